// Round 17
// baseline (4651.526 us; speedup 1.0000x reference)
//
#include <hip/hip_runtime.h>

// ===== BDH forward on MI355X — R17: R16 with g3 split-K x3 range fix =====
// R16 failed: g3 k-range used (i+1) as total instead of 2*(i+1) -> half of K
// dropped. Fixed: k0=(ks*2*(i+1))/3, k1=((ks+1)*2*(i+1))/3. g2 8-wave (2
// waves/SIMD, 160KB dbuf, row-triple) unchanged from R16 (desk-checked clean).

typedef unsigned short u16;
typedef unsigned int   u32;
typedef __attribute__((ext_vector_type(8))) short bf8;
typedef __attribute__((ext_vector_type(4))) float f4;

#define T_  2048
#define D_  256
#define NH_ 4
#define NN_ 4096
#define NLAYER 6

// ---- workspace layout (bytes); per-b activation buffers ----
#define CSA_OFF  ((size_t)0)                    // float2 [16][2048]  coarse-t trig
#define CSB_OFF  (CSA_OFF  + 262144)            // float2 [128][2048] fine-t trig
#define ETH_OFF  (CSB_OFF  + 2097152)           // bf16 [4][4096][256] enc^T hi
#define ETL_OFF  (ETH_OFF  + 8388608)
#define EVH_OFF  (ETL_OFF  + 8388608)
#define EVL_OFF  (EVH_OFF  + 8388608)
#define DTH_OFF  (EVL_OFF  + 8388608)           // bf16 [4][256][4096] dec^T hi
#define DTL_OFF  (DTH_OFF  + 8388608)
#define LMH_OFF  (DTL_OFF  + 8388608)           // bf16 [256][256] lm^T
#define LML_OFF  (LMH_OFF  + 131072)
#define X_OFF    (LML_OFF  + 131072)            // f32  [2048][256] x (per-b)
#define XBH_OFF  (X_OFF    + 2097152)           // bf16 [2048][256] (per-b)
#define XBL_OFF  (XBH_OFF  + 1048576)
#define XBTH_OFF (XBL_OFF  + 1048576)           // bf16 [256][2048] (per-b)
#define XBTL_OFF (XBTH_OFF + 1048576)
#define QRH_OFF  (XBTL_OFF + 1048576)           // bf16 [4][2048][4096] QR/xy hi (per-b)
#define QRL_OFF  (QRH_OFF  + 67108864)
#define SH_OFF   (QRL_OFF  + 67108864)          // bf16 [4][136][16384] S hi (per-b); part f32 overlays
#define SL_OFF   (SH_OFF   + 17825792)          // FREED -> f32 yKV partials 1,2 (2x8MB <= 17.8MB)
#define YKV_OFF  (SL_OFF   + 17825792)          // f32  [4][2048][256] yKV partial-0 (per-b)
#define YKBH_OFF (YKV_OFF  + 8388608)           // bf16 ln(yKV) hi (per-b)
#define YKBL_OFF (YKBH_OFF + 4194304)
#define IDX_END  (YKBL_OFF + 4194304)
#define WS_NEED  (IDX_END  + 16384)             // = 245,907,456 < 253,902,848 proven

// ---------- helpers ----------
__device__ __forceinline__ u16 f2b(float f) {               // RTNE f32->bf16
  u32 u = __builtin_bit_cast(u32, f);
  u32 r = u + 0x7fffu + ((u >> 16) & 1u);
  return (u16)(r >> 16);
}
__device__ __forceinline__ float b2f(u16 h) {
  u32 u = ((u32)h) << 16;
  return __builtin_bit_cast(float, u);
}
__device__ __forceinline__ void split2(float q0, float q1, u32& hi, u32& lo) {
  u16 h0 = f2b(q0), h1 = f2b(q1);
  u16 l0 = f2b(q0 - b2f(h0)), l1 = f2b(q1 - b2f(h1));
  hi = (u32)h0 | ((u32)h1 << 16);
  lo = (u32)l0 | ((u32)l1 << 16);
}
__device__ __forceinline__ float wsum(float v) {
#pragma unroll
  for (int o = 32; o; o >>= 1) v += __shfl_xor(v, o, 64);
  return v;
}
// trig from factored tables: pp = pair index [0,2048), t = time [0,2048)
__device__ __forceinline__ float2 trig_ct(const float2* csA, const float2* csB, int t, int pp) {
  float2 a = csA[(t >> 7) * 2048 + pp];
  float2 b = csB[(t & 127) * 2048 + pp];
  return make_float2(a.x * b.x - a.y * b.y, a.x * b.y + a.y * b.x);
}
__device__ __forceinline__ void gld16(const u16* g, short* l) {
  __builtin_amdgcn_global_load_lds(
      (const __attribute__((address_space(1))) u32*)g,
      (__attribute__((address_space(3))) u32*)l, 16, 0, 0);
}
// stage 128x64 bf16 tile into LDS [128][64], XOR-swizzled; 256-thread (4-wave) form
__device__ __forceinline__ void stage_t(const u16* g, int lda, short* s, int wid, int lane) {
  int r8 = lane >> 3;
  int c8 = ((lane & 7) ^ r8) * 8;
#pragma unroll
  for (int j = 0; j < 4; ++j) {
    int row = wid * 32 + j * 8;
    gld16(g + (size_t)(row + r8) * lda + c8, s + row * 64);
  }
}
// 512-thread (8-wave) stage: each wave covers 16 rows
__device__ __forceinline__ void stage_t8(const u16* g, int lda, short* s, int wid, int lane) {
  int r8 = lane >> 3;
  int c8 = ((lane & 7) ^ r8) * 8;
#pragma unroll
  for (int j = 0; j < 2; ++j) {
    int row = wid * 16 + j * 8;
    gld16(g + (size_t)(row + r8) * lda + c8, s + row * 64);
  }
}
// BK=64 step, 3-term split: 96 MFMA — g5 only
__device__ __forceinline__ void mma64x3(const short* AsH, const short* AsL, const short* BsH,
                                        const short* BsL, int wr, int wc, int lane,
                                        f4 acc[4][4]) {
  int r15 = lane & 15, hi = lane >> 4;
  int sw = (r15 & 7) << 3;
#pragma unroll
  for (int kk = 0; kk < 2; ++kk) {
    int ko = (kk * 32 + hi * 8) ^ sw;
    bf8 ah[4], al[4], bh[4], bl[4];
#pragma unroll
    for (int m = 0; m < 4; ++m) {
      int off = (wr * 64 + m * 16 + r15) * 64 + ko;
      ah[m] = *(const bf8*)(AsH + off);
      al[m] = *(const bf8*)(AsL + off);
    }
#pragma unroll
    for (int n = 0; n < 4; ++n) {
      int off = (wc * 64 + n * 16 + r15) * 64 + ko;
      bh[n] = *(const bf8*)(BsH + off);
      bl[n] = *(const bf8*)(BsL + off);
    }
#pragma unroll
    for (int m = 0; m < 4; ++m)
#pragma unroll
      for (int n = 0; n < 4; ++n) {
        acc[m][n] = __builtin_amdgcn_mfma_f32_16x16x32_bf16(ah[m], bh[n], acc[m][n], 0, 0, 0);
        acc[m][n] = __builtin_amdgcn_mfma_f32_16x16x32_bf16(al[m], bh[n], acc[m][n], 0, 0, 0);
        acc[m][n] = __builtin_amdgcn_mfma_f32_16x16x32_bf16(ah[m], bl[n], acc[m][n], 0, 0, 0);
      }
  }
}
// BK=64 step, 2-term A-split: acc += (Ah+Al)*Bh^T — g1/g4a/g4b
__device__ __forceinline__ void mma64x2(const short* AsH, const short* AsL, const short* BsH,
                                        int wr, int wc, int lane, f4 acc[4][4]) {
  int r15 = lane & 15, hi = lane >> 4;
  int sw = (r15 & 7) << 3;
#pragma unroll
  for (int kk = 0; kk < 2; ++kk) {
    int ko = (kk * 32 + hi * 8) ^ sw;
    bf8 ah[4], al[4], bh[4];
#pragma unroll
    for (int m = 0; m < 4; ++m) {
      int off = (wr * 64 + m * 16 + r15) * 64 + ko;
      ah[m] = *(const bf8*)(AsH + off);
      al[m] = *(const bf8*)(AsL + off);
    }
#pragma unroll
    for (int n = 0; n < 4; ++n)
      bh[n] = *(const bf8*)(BsH + (wc * 64 + n * 16 + r15) * 64 + ko);
#pragma unroll
    for (int m = 0; m < 4; ++m)
#pragma unroll
      for (int n = 0; n < 4; ++n) {
        acc[m][n] = __builtin_amdgcn_mfma_f32_16x16x32_bf16(ah[m], bh[n], acc[m][n], 0, 0, 0);
        acc[m][n] = __builtin_amdgcn_mfma_f32_16x16x32_bf16(al[m], bh[n], acc[m][n], 0, 0, 0);
      }
  }
}
// BK=64 step, 2-term B-split: acc += Ah*(Bh+Bl)^T — g3
__device__ __forceinline__ void mma64x2b(const short* AsH, const short* BsH, const short* BsL,
                                         int wr, int wc, int lane, f4 acc[4][4]) {
  int r15 = lane & 15, hi = lane >> 4;
  int sw = (r15 & 7) << 3;
#pragma unroll
  for (int kk = 0; kk < 2; ++kk) {
    int ko = (kk * 32 + hi * 8) ^ sw;
    bf8 ah[4], bh[4], bl[4];
#pragma unroll
    for (int m = 0; m < 4; ++m)
      ah[m] = *(const bf8*)(AsH + (wr * 64 + m * 16 + r15) * 64 + ko);
#pragma unroll
    for (int n = 0; n < 4; ++n) {
      int off = (wc * 64 + n * 16 + r15) * 64 + ko;
      bh[n] = *(const bf8*)(BsH + off);
      bl[n] = *(const bf8*)(BsL + off);
    }
#pragma unroll
    for (int m = 0; m < 4; ++m)
#pragma unroll
      for (int n = 0; n < 4; ++n) {
        acc[m][n] = __builtin_amdgcn_mfma_f32_16x16x32_bf16(ah[m], bh[n], acc[m][n], 0, 0, 0);
        acc[m][n] = __builtin_amdgcn_mfma_f32_16x16x32_bf16(ah[m], bl[n], acc[m][n], 0, 0, 0);
      }
  }
}
__device__ __forceinline__ void acc_zero(f4 acc[4][4]) {
#pragma unroll
  for (int m = 0; m < 4; ++m)
#pragma unroll
    for (int n = 0; n < 4; ++n)
#pragma unroll
      for (int j = 0; j < 4; ++j) acc[m][n][j] = 0.0f;
}
// C frag -> f32 LDS bounce [128][128] (g5)
__device__ __forceinline__ void acc_store_f32(float* F, f4 acc[4][4], int wr, int wc, int lane,
                                              bool relu) {
  int r15 = lane & 15, q = lane >> 4;
#pragma unroll
  for (int m = 0; m < 4; ++m)
#pragma unroll
    for (int n = 0; n < 4; ++n)
#pragma unroll
      for (int j = 0; j < 4; ++j) {
        float v = acc[m][n][j];
        if (relu) v = fmaxf(v, 0.0f);
        F[(wr * 64 + m * 16 + q * 4 + j) * 128 + wc * 64 + n * 16 + r15] = v;
      }
}
// half-store (pass p writes waves wr==p) into [64][128] f32 bounce
__device__ __forceinline__ void acc_store_half(float* F, f4 acc[4][4], int pass, int wr, int wc,
                                               int lane, bool relu) {
  if (wr != pass) return;
  int r15 = lane & 15, q = lane >> 4;
#pragma unroll
  for (int m = 0; m < 4; ++m)
#pragma unroll
    for (int n = 0; n < 4; ++n)
#pragma unroll
      for (int j = 0; j < 4; ++j) {
        float v = acc[m][n][j];
        if (relu) v = fmaxf(v, 0.0f);
        F[(m * 16 + q * 4 + j) * 128 + wc * 64 + n * 16 + r15] = v;
      }
}

// ---------- prep kernels ----------
__global__ __launch_bounds__(256) void k_costab(float2* csA, float2* csB) {
  int id = blockIdx.x * 256 + threadIdx.x;
  int r = id >> 11, p = id & 2047;
  double freq = exp2(-(double)p / 128.0) * 0.15915494309189533577;
  int t = (r < 16) ? (r * 128) : (r - 16);
  double ph = fmod((double)t * freq, 1.0);
  double ang = ph * 6.2831853071795864769;
  float2 v = make_float2((float)cos(ang), (float)sin(ang));
  if (r < 16) csA[r * 2048 + p] = v;
  else        csB[(r - 16) * 2048 + p] = v;
}

__global__ __launch_bounds__(256) void k_tcast2(const float* __restrict__ in,
                                                u16* __restrict__ outH, u16* __restrict__ outL,
                                                int R, int C) {
  __shared__ float tl[32][33];
  size_t bo = (size_t)blockIdx.z * R * C;
  int tx = threadIdx.x, ty = threadIdx.y;
  int c = blockIdx.x * 32 + tx, r0 = blockIdx.y * 32 + ty;
#pragma unroll
  for (int k = 0; k < 32; k += 8) tl[ty + k][tx] = in[bo + (size_t)(r0 + k) * C + c];
  __syncthreads();
  int rr = blockIdx.y * 32 + tx, cc0 = blockIdx.x * 32 + ty;
#pragma unroll
  for (int k = 0; k < 32; k += 8) {
    float v = tl[tx][ty + k];
    u16 h = f2b(v);
    outH[bo + (size_t)(cc0 + k) * R + rr] = h;
    outL[bo + (size_t)(cc0 + k) * R + rr] = f2b(v - b2f(h));
  }
}

__global__ __launch_bounds__(256) void k_ln_embed(const int* __restrict__ idx,
                                                  const float* __restrict__ embed, int b,
                                                  float* __restrict__ x, u16* __restrict__ xbH,
                                                  u16* __restrict__ xbL) {
  int lane = threadIdx.x & 63, wid = threadIdx.x >> 6;
  int r = blockIdx.x * 4 + wid;
  int id = idx[b * T_ + r] & 255;
  float4 v = ((const float4*)(embed + (size_t)id * 256))[lane];
  float m = wsum(v.x + v.y + v.z + v.w) * (1.0f / 256.0f);
  float d0 = v.x - m, d1 = v.y - m, d2 = v.z - m, d3 = v.w - m;
  float var = wsum(d0 * d0 + d1 * d1 + d2 * d2 + d3 * d3) * (1.0f / 256.0f);
  float rs = 1.0f / sqrtf(var + 1e-5f);
  float y0 = d0 * rs, y1 = d1 * rs, y2 = d2 * rs, y3 = d3 * rs;
  ((float4*)(x + (size_t)r * 256))[lane] = make_float4(y0, y1, y2, y3);
  ushort4 oh, ol;
  oh.x = f2b(y0); ol.x = f2b(y0 - b2f(oh.x));
  oh.y = f2b(y1); ol.y = f2b(y1 - b2f(oh.y));
  oh.z = f2b(y2); ol.z = f2b(y2 - b2f(oh.z));
  oh.w = f2b(y3); ol.w = f2b(y3 - b2f(oh.w));
  ((ushort4*)(xbH + (size_t)r * 256))[lane] = oh;
  ((ushort4*)(xbL + (size_t)r * 256))[lane] = ol;
}

__global__ __launch_bounds__(256) void k_xbt(const u16* __restrict__ xbH,
                                             const u16* __restrict__ xbL,
                                             u16* __restrict__ xbTH, u16* __restrict__ xbTL) {
  int id = blockIdx.x * 256 + threadIdx.x;
  int t = id & 2047, d = id >> 11;
  size_t src = (size_t)t * 256 + d;
  xbTH[id] = xbH[src];
  xbTL[id] = xbL[src];
}

// ---------- GEMM kernels ----------
#define GEMM_PRE2                                                       \
  __shared__ short sm2[24576];                                          \
  short* T0 = sm2;                                                      \
  short* T1 = sm2 + 8192;                                               \
  short* T2 = sm2 + 16384;                                              \
  float* bounce = (float*)sm2;                                          \
  int tid = threadIdx.x;                                                \
  int lane = tid & 63, wid = tid >> 6;                                  \
  int wr = wid >> 1, wc = wid & 1;                                      \
  f4 acc[4][4];                                                         \
  acc_zero(acc);

#define GEMM_PRE2D                                                      \
  __shared__ short smd[49152];                                          \
  float* bounce = (float*)smd;                                          \
  int tid = threadIdx.x;                                                \
  int lane = tid & 63, wid = tid >> 6;                                  \
  int wr = wid >> 1, wc = wid & 1;                                      \
  f4 acc[4][4];                                                         \
  acc_zero(acc);

// G1: x_sparse=relu(xb@enc_hi[h]) -> rope -> QR hi/lo.  2-term. grid(16,32,4), per-b.
__global__ __launch_bounds__(256) void k_g1(const u16* __restrict__ xbH, const u16* __restrict__ xbL,
                                            const u16* __restrict__ etH,
                                            const float2* __restrict__ csA,
                                            const float2* __restrict__ csB,
                                            u16* __restrict__ QRH, u16* __restrict__ QRL) {
  GEMM_PRE2
  int it = blockIdx.x, jt = blockIdx.y, h = blockIdx.z;
  size_t ao = (size_t)it * 128 * 256;
  size_t bo = (size_t)h * NN_ * 256 + (size_t)jt * 128 * 256;
  for (int kb = 0; kb < 4; ++kb) {
    stage_t(xbH + ao + kb * 64, 256, T0, wid, lane);
    stage_t(xbL + ao + kb * 64, 256, T1, wid, lane);
    stage_t(etH + bo + kb * 64, 256, T2, wid, lane);
    __syncthreads();
    mma64x2(T0, T1, T2, wr, wc, lane, acc);
    __syncthreads();
  }
#pragma unroll
  for (int pass = 0; pass < 2; ++pass) {
    acc_store_half(bounce, acc, pass, wr, wc, lane, true);
    __syncthreads();
    for (int w = 0; w < 16; ++w) {
      int e = w * 256 + tid;
      int rrel = e >> 6, p = e & 63;
      float v0 = bounce[rrel * 128 + 2 * p], v1 = bounce[rrel * 128 + 2 * p + 1];
      int t = it * 128 + pass * 64 + rrel, pp = jt * 64 + p;
      float2 c = trig_ct(csA, csB, t, pp);
      float q0 = v0 * c.x - v1 * c.y;
      float q1 = v1 * c.x + v0 * c.y;
      u32 hi, lo;
      split2(q0, q1, hi, lo);
      size_t u32b = (size_t)(h * T_ + t) * 2048 + pp;
      ((u32*)QRH)[u32b] = hi;
      ((u32*)QRL)[u32b] = lo;
    }
    __syncthreads();
  }
}

// G2: S = mask((Qh+Ql)@Qh^T), lower-tri, row-triple, 512 threads (8 waves: 2r x 4c
// of 64x96), 160KB dbuf, A-hoisted. grid 204 per b, bijective XCD chunk.
__global__ __launch_bounds__(512) void k_g2(const u16* __restrict__ QRH,
                                            const u16* __restrict__ QRL,
                                            u16* __restrict__ SpH) {
  __shared__ short smp[81920];             // 160KB: 2 x (AsH|AsL|B0|B1|B2)
  float* bounce = (float*)smp;             // 32KB [64][128] f32 (epilogue)
  int tid = threadIdx.x;
  int lane = tid & 63, wid = tid >> 6;     // wid 0..7
  int wr = wid >> 2, wc = wid & 3;         // 2 row-halves x 4 col-waves (64x96 each)
  f4 acc[4][6];
#pragma unroll
  for (int m = 0; m < 4; ++m)
#pragma unroll
    for (int n = 0; n < 6; ++n)
#pragma unroll
      for (int j = 0; j < 4; ++j) acc[m][n][j] = 0.0f;
  // bijective XCD chunking for N=204: q=25, r=4
  int orig = blockIdx.x;
  int xcd = orig & 7, sub = orig >> 3;
  int lb = (xcd < 4 ? xcd * 26 : 104 + (xcd - 4) * 25) + sub;
  int h = lb / 51;
  int rem = lb % 51, i = 0;
  while (rem >= (i + 3) / 3) { rem -= (i + 3) / 3; ++i; }
  int j0 = rem * 3, j1 = j0 + 1, j2 = j0 + 2;
  bool has1 = (j1 <= i), has2 = (j2 <= i);
  size_t base = (size_t)h * T_ * NN_;
  size_t ao = base + (size_t)i * 128 * NN_;
  size_t bo0 = base + (size_t)j0 * 128 * NN_;
  size_t bo1 = base + (size_t)j1 * 128 * NN_;
  size_t bo2 = base + (size_t)j2 * 128 * NN_;
  {  // prologue: stage k=0 into buf0
    stage_t8(QRH + ao, NN_, smp, wid, lane);
    stage_t8(QRL + ao, NN_, smp + 8192, wid, lane);
    stage_t8(QRH + bo0, NN_, smp + 16384, wid, lane);
    if (has1) stage_t8(QRH + bo1, NN_, smp + 24576, wid, lane);
    if (has2) stage_t8(QRH + bo2, NN_, smp + 32768, wid, lane);
  }
  int r15 = lane & 15, hi4 = lane >> 4;
  int sw = (r15 & 7) << 3;
  for (int kb = 0; kb < 64; ++kb) {
    short* cur = smp + (kb & 1) * 40960;
    __syncthreads();
    if (kb + 1 < 64) {
      short* nxt = smp + ((kb + 1) & 1) * 40960;
      stage_t8(QRH + ao + (kb + 1) * 64, NN_, nxt, wid, lane);
      stage_t8(QRL + ao + (kb + 1) * 64, NN_, nxt + 8192, wid, lane);
      stage_t8(QRH + bo0 + (kb + 1) * 64, NN_, nxt + 16384, wid, lane);
      if (has1) stage_t8(QRH + bo1 + (kb + 1) * 64, NN_, nxt + 24576, wid, lane);
      if (has2) stage_t8(QRH + bo2 + (kb + 1) * 64, NN_, nxt + 32768, wid, lane);
    }
#pragma unroll
    for (int kk = 0; kk < 2; ++kk) {
      int ko = (kk * 32 + hi4 * 8) ^ sw;
      bf8 ah[4], al[4];
#pragma unroll
      for (int m = 0; m < 4; ++m) {
        int off = (wr * 64 + m * 16 + r15) * 64 + ko;
        ah[m] = *(const bf8*)(cur + off);
        al[m] = *(const bf8*)(cur + 8192 + off);
      }
#pragma unroll
      for (int n = 0; n < 6; ++n) {
        int cn = wc * 96 + n * 16;
        int bp = cn >> 7;
        if (bp == 1 && !has1) continue;
        if (bp == 2 && !has2) continue;
        bf8 bh = *(const bf8*)(cur + 16384 + bp * 8192 + ((cn & 127) + r15) * 64 + ko);
#pragma unroll
        for (int m = 0; m < 4; ++m) {
          acc[m][n] = __builtin_amdgcn_mfma_f32_16x16x32_bf16(ah[m], bh, acc[m][n], 0, 0, 0);
          acc[m][n] = __builtin_amdgcn_mfma_f32_16x16x32_bf16(al[m], bh, acc[m][n], 0, 0, 0);
        }
      }
    }
  }
  __syncthreads();
  // epilogue: per present panel, 2 row-passes through 32KB bounce
  int q4 = lane >> 4;
#pragma unroll
  for (int jb = 0; jb < 3; ++jb) {
    if (jb == 1 && !has1) break;
    if (jb == 2 && !has2) break;
    int j = j0 + jb;
    size_t dblk = ((size_t)h * 136 + (size_t)i * (i + 1) / 2 + j) * 16384;
    bool diag = (i == j);
#pragma unroll
    for (int pass = 0; pass < 2; ++pass) {
      if (wr == pass) {
#pragma unroll
        for (int m = 0; m < 4; ++m)
#pragma unroll
          for (int n = 0; n < 6; ++n) {
            int cn = wc * 96 + n * 16;
            if ((cn >> 7) != jb) continue;
#pragma unroll
            for (int jj = 0; jj < 4; ++jj)
              bounce[(m * 16 + q4 * 4 + jj) * 128 + (cn & 127) + r15] = acc[m][n][jj];
          }
      }
      __syncthreads();
      for (int w = 0; w < 8; ++w) {
        int e = w * 512 + tid;
        int rrel = e >> 6, p = e & 63;
        int row = pass * 64 + rrel;
        float s0 = bounce[rrel * 128 + 2 * p], s1 = bounce[rrel * 128 + 2 * p + 1];
        if (diag) {  // strictly lower: col < row
          if (2 * p >= row) s0 = 0.0f;
          if (2 * p + 1 >= row) s1 = 0.0f;
        }
        u32 hi = (u32)f2b(s0) | ((u32)f2b(s1) << 16);
        ((u32*)SpH)[(dblk >> 1) + row * 64 + p] = hi;
      }
      __syncthreads();
    }
  }
}

// G3: yKV_partial = S_hi @ (xh+xl), split-K x3 over nk=2*(i+1) half-steps, dbuf.
// grid(16,2,12): z = h + 4*ks, ks in {0,1,2}.  per-b.
__global__ __launch_bounds__(256) void k_g3(const u16* __restrict__ SpH,
                                            const u16* __restrict__ xbTH,
                                            const u16* __restrict__ xbTL,
                                            float* __restrict__ yKV0,
                                            float* __restrict__ yKV1,
                                            float* __restrict__ yKV2) {
  GEMM_PRE2D
  int i = blockIdx.x, jt = blockIdx.y;
  int h = blockIdx.z & 3, ks = blockIdx.z >> 2;
  size_t tri = (size_t)h * 136 + (size_t)i * (i + 1) / 2;
  size_t bo = (size_t)jt * 128 * T_;
  int nk = 2 * (i + 1);                           // total half-steps (R16 BUG: used i+1)
  int k0 = (ks * nk) / 3, k1 = ((ks + 1) * nk) / 3;
  if (k0 < k1) {  // prologue
    size_t aoff = (tri + (k0 >> 1)) * 16384 + (k0 & 1) * 64;
    stage_t(SpH + aoff, 128, smd, wid, lane);
    stage_t(xbTH + bo + k0 * 64, T_, smd + 8192, wid, lane);
    stage_t(xbTL + bo + k0 * 64, T_, smd + 16384, wid, lane);
  }
  for (int kb = k0; kb < k1; ++kb) {
    short* cur = smd + ((kb - k0) & 1) * 24576;
    __syncthreads();
    if (kb + 1 < k1) {
      short* nxt = smd + ((kb + 1 - k0) & 1) * 24576;
      size_t aoff = (tri + ((kb + 1) >> 1)) * 16384 + ((kb + 1) & 1) * 64;
      stage_t(SpH + aoff, 128, nxt, wid, lane);
      stage_t(xbTH + bo + (kb + 1) * 64, T_, nxt + 8192, wid, lane);
      stage_t(xbTL + bo + (kb + 1) * 64, T_, nxt + 16384, wid, lane);
    }
    mma64x2b(cur, cur + 8192, cur + 16384, wr, wc, lane, acc);
  }
  __syncthreads();
  float* yout = (ks == 0) ? yKV0 : (ks == 1) ? yKV1 : yKV2;
#pragma unroll
  for (int pass = 0; pass < 2; ++pass) {
    acc_store_half(bounce, acc, pass, wr, wc, lane, false);
    __syncthreads();
    for (int w = 0; w < 32; ++w) {
      int e = w * 256 + tid;
      int row = e >> 7, col = e & 127;
      yout[((size_t)h * T_ + i * 128 + pass * 64 + row) * 256 + jt * 128 + col] =
          bounce[row * 128 + col];
    }
    __syncthreads();
  }
}

// LN over f32 rows of 256 (sum of 3 partials) -> hi/lo bf16.  2048 blocks, per-b.
__global__ __launch_bounds__(256) void k_ln_f32(const float* __restrict__ in0,
                                                const float* __restrict__ in1,
                                                const float* __restrict__ in2,
                                                u16* __restrict__ outH, u16* __restrict__ outL) {
  int lane = threadIdx.x & 63, wid = threadIdx.x >> 6;
  int r = blockIdx.x * 4 + wid;
  float4 a = ((const float4*)(in0 + (size_t)r * 256))[lane];
  float4 b = ((const float4*)(in1 + (size_t)r * 256))[lane];
  float4 c = ((const float4*)(in2 + (size_t)r * 256))[lane];
  float v0 = a.x + b.x + c.x, v1 = a.y + b.y + c.y;
  float v2 = a.z + b.z + c.z, v3 = a.w + b.w + c.w;
  float m = wsum(v0 + v1 + v2 + v3) * (1.0f / 256.0f);
  float d0 = v0 - m, d1 = v1 - m, d2 = v2 - m, d3 = v3 - m;
  float var = wsum(d0 * d0 + d1 * d1 + d2 * d2 + d3 * d3) * (1.0f / 256.0f);
  float rs = 1.0f / sqrtf(var + 1e-5f);
  float y0 = d0 * rs, y1 = d1 * rs, y2 = d2 * rs, y3 = d3 * rs;
  ushort4 oh, ol;
  oh.x = f2b(y0); ol.x = f2b(y0 - b2f(oh.x));
  oh.y = f2b(y1); ol.y = f2b(y1 - b2f(oh.y));
  oh.z = f2b(y2); ol.z = f2b(y2 - b2f(oh.z));
  oh.w = f2b(y3); ol.w = f2b(y3 - b2f(oh.w));
  ((ushort4*)(outH + (size_t)r * 256))[lane] = oh;
  ((ushort4*)(outL + (size_t)r * 256))[lane] = ol;
}

// G4a: y_sparse=relu((ykh+ykl)@encv_hi[h]); gate by invrope(QR h+l); xy -> QR hi/lo.
// 2-term. grid(16,32,4), per-b.
__global__ __launch_bounds__(256) void k_g4a(const u16* __restrict__ ykH,
                                             const u16* __restrict__ ykL,
                                             const u16* __restrict__ evH,
                                             const float2* __restrict__ csA,
                                             const float2* __restrict__ csB,
                                             u16* __restrict__ QRH, u16* __restrict__ QRL) {
  GEMM_PRE2
  int it = blockIdx.x, jt = blockIdx.y, h = blockIdx.z;
  int t0 = it * 128;
  size_t ao = (size_t)(h * T_ + t0) * 256;
  size_t bo = (size_t)h * NN_ * 256 + (size_t)jt * 128 * 256;
  for (int kb = 0; kb < 4; ++kb) {
    stage_t(ykH + ao + kb * 64, 256, T0, wid, lane);
    stage_t(ykL + ao + kb * 64, 256, T1, wid, lane);
    stage_t(evH + bo + kb * 64, 256, T2, wid, lane);
    __syncthreads();
    mma64x2(T0, T1, T2, wr, wc, lane, acc);
    __syncthreads();
  }
#pragma unroll
  for (int pass = 0; pass < 2; ++pass) {
    acc_store_half(bounce, acc, pass, wr, wc, lane, true);
    __syncthreads();
    for (int w = 0; w < 16; ++w) {
      int e = w * 256 + tid;
      int rrel = e >> 6, p = e & 63;
      float ys0 = bounce[rrel * 128 + 2 * p], ys1 = bounce[rrel * 128 + 2 * p + 1];
      int t = t0 + pass * 64 + rrel, pp = jt * 64 + p;
      size_t u32b = (size_t)(h * T_ + t) * 2048 + pp;
      u32 qh = ((const u32*)QRH)[u32b], ql = ((const u32*)QRL)[u32b];
      float qe = b2f((u16)(qh & 0xffff)) + b2f((u16)(ql & 0xffff));
      float qo = b2f((u16)(qh >> 16)) + b2f((u16)(ql >> 16));
      float2 c = trig_ct(csA, csB, t, pp);
      float xe = fmaxf(qe * c.x + qo * c.y, 0.0f);
      float xo = fmaxf(qo * c.x - qe * c.y, 0.0f);
      u32 hi, lo;
      split2(ys0 * xe, ys1 * xo, hi, lo);
      ((u32*)QRH)[u32b] = hi;
      ((u32*)QRL)[u32b] = lo;
    }
    __syncthreads();
  }
}

// G4b: part[ks*4+h] = (xyh+xyl)[ks-half] @ dec_hi[h][ks-half].  2-term, dbuf.
// grid(16,2,8): z = h + 4*ks.  per-b.
__global__ __launch_bounds__(256) void k_g4b(const u16* __restrict__ xyH,
                                             const u16* __restrict__ xyL,
                                             const u16* __restrict__ dtH,
                                             float* __restrict__ part) {
  GEMM_PRE2D
  int it = blockIdx.x, jt = blockIdx.y;
  int h = blockIdx.z & 3, ks = blockIdx.z >> 2;
  int t0 = it * 128;
  size_t ao = (size_t)(h * T_ + t0) * NN_;
  size_t bo = (size_t)h * D_ * NN_ + (size_t)jt * 128 * NN_;
  int k0 = ks * 32, k1 = ks * 32 + 32;
  {  // prologue
    stage_t(xyH + ao + k0 * 64, NN_, smd, wid, lane);
    stage_t(xyL + ao + k0 * 64, NN_, smd + 8192, wid, lane);
    stage_t(dtH + bo + k0 * 64, NN_, smd + 16384, wid, lane);
  }
  for (int kb = k0; kb < k1; ++kb) {
    short* cur = smd + ((kb - k0) & 1) * 24576;
    __syncthreads();
    if (kb + 1 < k1) {
      short* nxt = smd + ((kb + 1 - k0) & 1) * 24576;
      stage_t(xyH + ao + (kb + 1) * 64, NN_, nxt, wid, lane);
      stage_t(xyL + ao + (kb + 1) * 64, NN_, nxt + 8192, wid, lane);
      stage_t(dtH + bo + (kb + 1) * 64, NN_, nxt + 16384, wid, lane);
    }
    mma64x2(cur, cur + 8192, cur + 16384, wr, wc, lane, acc);
  }
  __syncthreads();
#pragma unroll
  for (int pass = 0; pass < 2; ++pass) {
    acc_store_half(bounce, acc, pass, wr, wc, lane, false);
    __syncthreads();
    for (int w = 0; w < 32; ++w) {
      int e = w * 256 + tid;
      int row = e >> 7, col = e & 127;
      part[((size_t)blockIdx.z * T_ + t0 + pass * 64 + row) * 256 + jt * 128 + col] =
          bounce[row * 128 + col];
    }
    __syncthreads();
  }
}

// LN3: yMLP = sum of 8 part slabs; x = ln(x + ln(yMLP)); refresh x, xb hi/lo. 512 blocks.
__global__ __launch_bounds__(256) void k_ln3(const float* __restrict__ part, float* __restrict__ x,
                                             u16* __restrict__ xbH, u16* __restrict__ xbL) {
  int lane = threadIdx.x & 63, wid = threadIdx.x >> 6;
  int r = blockIdx.x * 4 + wid;
  float a0 = 0, a1 = 0, a2 = 0, a3 = 0;
#pragma unroll
  for (int h = 0; h < 8; ++h) {
    float4 u = ((const float4*)(part + ((size_t)h * T_ + r) * 256))[lane];
    a0 += u.x; a1 += u.y; a2 += u.z; a3 += u.w;
  }
  float m = wsum(a0 + a1 + a2 + a3) * (1.0f / 256.0f);
  float d0 = a0 - m, d1 = a1 - m, d2 = a2 - m, d3 = a3 - m;
  float var = wsum(d0 * d0 + d1 * d1 + d2 * d2 + d3 * d3) * (1.0f / 256.0f);
  float rs = 1.0f / sqrtf(var + 1e-5f);
  float4 xv = ((const float4*)(x + (size_t)r * 256))[lane];
  float s0 = xv.x + d0 * rs, s1 = xv.y + d1 * rs, s2 = xv.z + d2 * rs, s3 = xv.w + d3 * rs;
  float m2 = wsum(s0 + s1 + s2 + s3) * (1.0f / 256.0f);
  float e0 = s0 - m2, e1 = s1 - m2, e2 = s2 - m2, e3 = s3 - m2;
  float var2 = wsum(e0 * e0 + e1 * e1 + e2 * e2 + e3 * e3) * (1.0f / 256.0f);
  float rs2 = 1.0f / sqrtf(var2 + 1e-5f);
  float y0 = e0 * rs2, y1 = e1 * rs2, y2 = e2 * rs2, y3 = e3 * rs2;
  ((float4*)(x + (size_t)r * 256))[lane] = make_float4(y0, y1, y2, y3);
  ushort4 oh, ol;
  oh.x = f2b(y0); ol.x = f2b(y0 - b2f(oh.x));
  oh.y = f2b(y1); ol.y = f2b(y1 - b2f(oh.y));
  oh.z = f2b(y2); ol.z = f2b(y2 - b2f(oh.z));
  oh.w = f2b(y3); ol.w = f2b(y3 - b2f(oh.w));
  ((ushort4*)(xbH + (size_t)r * 256))[lane] = oh;
  ((ushort4*)(xbL + (size_t)r * 256))[lane] = ol;
}

// G5: logits = xb @ lm_head (3-term) -> f32 out.  grid(16,2), per-b.
__global__ __launch_bounds__(256) void k_g5(const u16* __restrict__ xbH,
                                            const u16* __restrict__ xbL,
                                            const u16* __restrict__ lmH,
                                            const u16* __restrict__ lmL,
                                            float* __restrict__ out) {
  __shared__ float smf[16384];
  short* AsH = (short*)smf;
  short* AsL = AsH + 8192;
  short* BsH = AsH + 16384;
  short* BsL = AsH + 24576;
  int tid = threadIdx.x;
  int lane = tid & 63, wid = tid >> 6;
  int wr = wid >> 1, wc = wid & 1;
  f4 acc[4][4];
  acc_zero(acc);
  int it = blockIdx.x, jt = blockIdx.y;
  size_t ao = (size_t)it * 128 * 256;
  size_t bo = (size_t)jt * 128 * 256;
  for (int kb = 0; kb < 4; ++kb) {
    stage_t(xbH + ao + kb * 64, 256, AsH, wid, lane);
    stage_t(xbL + ao + kb * 64, 256, AsL, wid, lane);
    stage_t(lmH + bo + kb * 64, 256, BsH, wid, lane);
    stage_t(lmL + bo + kb * 64, 256, BsL, wid, lane);
    __syncthreads();
    mma64x3(AsH, AsL, BsH, BsL, wr, wc, lane, acc);
    __syncthreads();
  }
  acc_store_f32(smf, acc, wr, wc, lane, false);
  __syncthreads();
  for (int w = 0; w < 64; ++w) {
    int e = w * 256 + tid;
    int row = e >> 7, col = e & 127;
    out[(size_t)(it * 128 + row) * 256 + jt * 128 + col] = smf[row * 128 + col];
  }
}

extern "C" void kernel_launch(void* const* d_in, const int* in_sizes, int n_in, void* d_out,
                              int out_size, void* d_ws, size_t ws_size, hipStream_t stream) {
  const int*   idx   = (const int*)d_in[0];
  const float* embed = (const float*)d_in[1];
  const float* enc   = (const float*)d_in[2];
  const float* encv  = (const float*)d_in[3];
  const float* dec   = (const float*)d_in[4];
  const float* lm    = (const float*)d_in[5];

  if (ws_size < WS_NEED) {
    hipMemsetAsync(d_out, 0x46, (size_t)out_size * 4, stream);
    return;
  }

  char* w = (char*)d_ws;
  float2* csA  = (float2*)(w + CSA_OFF);
  float2* csB  = (float2*)(w + CSB_OFF);
  u16*    etH  = (u16*)(w + ETH_OFF);
  u16*    etL  = (u16*)(w + ETL_OFF);
  u16*    evH  = (u16*)(w + EVH_OFF);
  u16*    evL  = (u16*)(w + EVL_OFF);
  u16*    dtH  = (u16*)(w + DTH_OFF);
  u16*    dtL  = (u16*)(w + DTL_OFF);
  u16*    lmH  = (u16*)(w + LMH_OFF);
  u16*    lmL  = (u16*)(w + LML_OFF);
  float*  x    = (float*)(w + X_OFF);
  u16*    xbH  = (u16*)(w + XBH_OFF);
  u16*    xbL  = (u16*)(w + XBL_OFF);
  u16*    xbTH = (u16*)(w + XBTH_OFF);
  u16*    xbTL = (u16*)(w + XBTL_OFF);
  u16*    QRH  = (u16*)(w + QRH_OFF);
  u16*    QRL  = (u16*)(w + QRL_OFF);
  u16*    SpH  = (u16*)(w + SH_OFF);
  float*  part = (float*)(w + SH_OFF);   // overlays S-hi (S dead after G3)
  float*  yKV1 = (float*)(w + SL_OFF);   // freed S-lo region -> partials 1,2
  float*  yKV2 = (float*)(w + SL_OFF + 8388608);
  float*  yKV0 = (float*)(w + YKV_OFF);
  u16*    ykH  = (u16*)(w + YKBH_OFF);
  u16*    ykL  = (u16*)(w + YKBL_OFF);

  k_costab<<<1152, 256, 0, stream>>>(csA, csB);
  k_tcast2<<<dim3(128, 8, 4), dim3(32, 8), 0, stream>>>(enc, etH, etL, 256, 4096);
  k_tcast2<<<dim3(128, 8, 4), dim3(32, 8), 0, stream>>>(encv, evH, evL, 256, 4096);
  k_tcast2<<<dim3(8, 128, 4), dim3(32, 8), 0, stream>>>(dec, dtH, dtL, 4096, 256);
  k_tcast2<<<dim3(8, 8, 1), dim3(32, 8), 0, stream>>>(lm, lmH, lmL, 256, 256);

  for (int b = 0; b < 2; ++b) {
    k_ln_embed<<<512, 256, 0, stream>>>(idx, embed, b, x, xbH, xbL);
    k_xbt<<<2048, 256, 0, stream>>>(xbH, xbL, xbTH, xbTL);
    for (int l = 0; l < NLAYER; ++l) {
      k_g1<<<dim3(16, 32, 4), 256, 0, stream>>>(xbH, xbL, etH, csA, csB, QRH, QRL);
      k_g2<<<204, 512, 0, stream>>>(QRH, QRL, SpH);
      k_g3<<<dim3(16, 2, 12), 256, 0, stream>>>(SpH, xbTH, xbTL, yKV0, yKV1, yKV2);
      k_ln_f32<<<2048, 256, 0, stream>>>(yKV0, yKV1, yKV2, ykH, ykL);
      k_g4a<<<dim3(16, 32, 4), 256, 0, stream>>>(ykH, ykL, evH, csA, csB, QRH, QRL);
      k_g4b<<<dim3(16, 2, 8), 256, 0, stream>>>(QRH, QRL, dtH, part);
      k_ln3<<<512, 256, 0, stream>>>(part, x, xbH, xbL);
      k_xbt<<<2048, 256, 0, stream>>>(xbH, xbL, xbTH, xbTL);
    }
    k_g5<<<dim3(16, 2), 256, 0, stream>>>(xbH, xbL, lmH, lmL, (float*)d_out + (size_t)b * T_ * 256);
  }
}

// Round 18
// 3879.823 us; speedup vs baseline: 1.1989x; 1.1989x over previous
//
#include <hip/hip_runtime.h>

// ===== BDH forward on MI355X — R18: g2 1-term (S = Qh@Qh^T) + g3 revert to x2 =====
// R17 (4651us, absmax 0.01367): g2 residual = LDS-read amplification; scheduling
// levers exhausted. R18: halve g2's arithmetic — S = Qh·Qh^T (1-term, quadrature
// model predicts absmax ~0.0153 < 0.0298). 128KB dbuf, 4 tiles. g3 back to
// split-K x2 (R15 exact; x3 regressed).

typedef unsigned short u16;
typedef unsigned int   u32;
typedef __attribute__((ext_vector_type(8))) short bf8;
typedef __attribute__((ext_vector_type(4))) float f4;

#define T_  2048
#define D_  256
#define NH_ 4
#define NN_ 4096
#define NLAYER 6

// ---- workspace layout (bytes); per-b activation buffers ----
#define CSA_OFF  ((size_t)0)                    // float2 [16][2048]  coarse-t trig
#define CSB_OFF  (CSA_OFF  + 262144)            // float2 [128][2048] fine-t trig
#define ETH_OFF  (CSB_OFF  + 2097152)           // bf16 [4][4096][256] enc^T hi
#define ETL_OFF  (ETH_OFF  + 8388608)
#define EVH_OFF  (ETL_OFF  + 8388608)
#define EVL_OFF  (EVH_OFF  + 8388608)
#define DTH_OFF  (EVL_OFF  + 8388608)           // bf16 [4][256][4096] dec^T hi
#define DTL_OFF  (DTH_OFF  + 8388608)
#define LMH_OFF  (DTL_OFF  + 8388608)           // bf16 [256][256] lm^T
#define LML_OFF  (LMH_OFF  + 131072)
#define X_OFF    (LML_OFF  + 131072)            // f32  [2048][256] x (per-b)
#define XBH_OFF  (X_OFF    + 2097152)           // bf16 [2048][256] (per-b)
#define XBL_OFF  (XBH_OFF  + 1048576)
#define XBTH_OFF (XBL_OFF  + 1048576)           // bf16 [256][2048] (per-b)
#define XBTL_OFF (XBTH_OFF + 1048576)
#define QRH_OFF  (XBTL_OFF + 1048576)           // bf16 [4][2048][4096] QR/xy hi (per-b)
#define QRL_OFF  (QRH_OFF  + 67108864)
#define SH_OFF   (QRL_OFF  + 67108864)          // bf16 [4][136][16384] S hi (per-b); part f32 overlays
#define SL_OFF   (SH_OFF   + 17825792)          // FREED -> f32 yKV partial-1
#define YKV_OFF  (SL_OFF   + 17825792)          // f32  [4][2048][256] yKV partial-0 (per-b)
#define YKBH_OFF (YKV_OFF  + 8388608)           // bf16 ln(yKV) hi (per-b)
#define YKBL_OFF (YKBH_OFF + 4194304)
#define IDX_END  (YKBL_OFF + 4194304)
#define WS_NEED  (IDX_END  + 16384)             // = 245,907,456 < 253,902,848 proven

// ---------- helpers ----------
__device__ __forceinline__ u16 f2b(float f) {               // RTNE f32->bf16
  u32 u = __builtin_bit_cast(u32, f);
  u32 r = u + 0x7fffu + ((u >> 16) & 1u);
  return (u16)(r >> 16);
}
__device__ __forceinline__ float b2f(u16 h) {
  u32 u = ((u32)h) << 16;
  return __builtin_bit_cast(float, u);
}
__device__ __forceinline__ void split2(float q0, float q1, u32& hi, u32& lo) {
  u16 h0 = f2b(q0), h1 = f2b(q1);
  u16 l0 = f2b(q0 - b2f(h0)), l1 = f2b(q1 - b2f(h1));
  hi = (u32)h0 | ((u32)h1 << 16);
  lo = (u32)l0 | ((u32)l1 << 16);
}
__device__ __forceinline__ float wsum(float v) {
#pragma unroll
  for (int o = 32; o; o >>= 1) v += __shfl_xor(v, o, 64);
  return v;
}
// trig from factored tables: pp = pair index [0,2048), t = time [0,2048)
__device__ __forceinline__ float2 trig_ct(const float2* csA, const float2* csB, int t, int pp) {
  float2 a = csA[(t >> 7) * 2048 + pp];
  float2 b = csB[(t & 127) * 2048 + pp];
  return make_float2(a.x * b.x - a.y * b.y, a.x * b.y + a.y * b.x);
}
__device__ __forceinline__ void gld16(const u16* g, short* l) {
  __builtin_amdgcn_global_load_lds(
      (const __attribute__((address_space(1))) u32*)g,
      (__attribute__((address_space(3))) u32*)l, 16, 0, 0);
}
// stage 128x64 bf16 tile into LDS [128][64], XOR-swizzled; 256-thread (4-wave) form
__device__ __forceinline__ void stage_t(const u16* g, int lda, short* s, int wid, int lane) {
  int r8 = lane >> 3;
  int c8 = ((lane & 7) ^ r8) * 8;
#pragma unroll
  for (int j = 0; j < 4; ++j) {
    int row = wid * 32 + j * 8;
    gld16(g + (size_t)(row + r8) * lda + c8, s + row * 64);
  }
}
// 512-thread (8-wave) stage: each wave covers 16 rows
__device__ __forceinline__ void stage_t8(const u16* g, int lda, short* s, int wid, int lane) {
  int r8 = lane >> 3;
  int c8 = ((lane & 7) ^ r8) * 8;
#pragma unroll
  for (int j = 0; j < 2; ++j) {
    int row = wid * 16 + j * 8;
    gld16(g + (size_t)(row + r8) * lda + c8, s + row * 64);
  }
}
// BK=64 step, 3-term split: 96 MFMA — g5 only
__device__ __forceinline__ void mma64x3(const short* AsH, const short* AsL, const short* BsH,
                                        const short* BsL, int wr, int wc, int lane,
                                        f4 acc[4][4]) {
  int r15 = lane & 15, hi = lane >> 4;
  int sw = (r15 & 7) << 3;
#pragma unroll
  for (int kk = 0; kk < 2; ++kk) {
    int ko = (kk * 32 + hi * 8) ^ sw;
    bf8 ah[4], al[4], bh[4], bl[4];
#pragma unroll
    for (int m = 0; m < 4; ++m) {
      int off = (wr * 64 + m * 16 + r15) * 64 + ko;
      ah[m] = *(const bf8*)(AsH + off);
      al[m] = *(const bf8*)(AsL + off);
    }
#pragma unroll
    for (int n = 0; n < 4; ++n) {
      int off = (wc * 64 + n * 16 + r15) * 64 + ko;
      bh[n] = *(const bf8*)(BsH + off);
      bl[n] = *(const bf8*)(BsL + off);
    }
#pragma unroll
    for (int m = 0; m < 4; ++m)
#pragma unroll
      for (int n = 0; n < 4; ++n) {
        acc[m][n] = __builtin_amdgcn_mfma_f32_16x16x32_bf16(ah[m], bh[n], acc[m][n], 0, 0, 0);
        acc[m][n] = __builtin_amdgcn_mfma_f32_16x16x32_bf16(al[m], bh[n], acc[m][n], 0, 0, 0);
        acc[m][n] = __builtin_amdgcn_mfma_f32_16x16x32_bf16(ah[m], bl[n], acc[m][n], 0, 0, 0);
      }
  }
}
// BK=64 step, 2-term A-split: acc += (Ah+Al)*Bh^T — g1/g4a/g4b
__device__ __forceinline__ void mma64x2(const short* AsH, const short* AsL, const short* BsH,
                                        int wr, int wc, int lane, f4 acc[4][4]) {
  int r15 = lane & 15, hi = lane >> 4;
  int sw = (r15 & 7) << 3;
#pragma unroll
  for (int kk = 0; kk < 2; ++kk) {
    int ko = (kk * 32 + hi * 8) ^ sw;
    bf8 ah[4], al[4], bh[4];
#pragma unroll
    for (int m = 0; m < 4; ++m) {
      int off = (wr * 64 + m * 16 + r15) * 64 + ko;
      ah[m] = *(const bf8*)(AsH + off);
      al[m] = *(const bf8*)(AsL + off);
    }
#pragma unroll
    for (int n = 0; n < 4; ++n)
      bh[n] = *(const bf8*)(BsH + (wc * 64 + n * 16 + r15) * 64 + ko);
#pragma unroll
    for (int m = 0; m < 4; ++m)
#pragma unroll
      for (int n = 0; n < 4; ++n) {
        acc[m][n] = __builtin_amdgcn_mfma_f32_16x16x32_bf16(ah[m], bh[n], acc[m][n], 0, 0, 0);
        acc[m][n] = __builtin_amdgcn_mfma_f32_16x16x32_bf16(al[m], bh[n], acc[m][n], 0, 0, 0);
      }
  }
}
// BK=64 step, 2-term B-split: acc += Ah*(Bh+Bl)^T — g3
__device__ __forceinline__ void mma64x2b(const short* AsH, const short* BsH, const short* BsL,
                                         int wr, int wc, int lane, f4 acc[4][4]) {
  int r15 = lane & 15, hi = lane >> 4;
  int sw = (r15 & 7) << 3;
#pragma unroll
  for (int kk = 0; kk < 2; ++kk) {
    int ko = (kk * 32 + hi * 8) ^ sw;
    bf8 ah[4], bh[4], bl[4];
#pragma unroll
    for (int m = 0; m < 4; ++m)
      ah[m] = *(const bf8*)(AsH + (wr * 64 + m * 16 + r15) * 64 + ko);
#pragma unroll
    for (int n = 0; n < 4; ++n) {
      int off = (wc * 64 + n * 16 + r15) * 64 + ko;
      bh[n] = *(const bf8*)(BsH + off);
      bl[n] = *(const bf8*)(BsL + off);
    }
#pragma unroll
    for (int m = 0; m < 4; ++m)
#pragma unroll
      for (int n = 0; n < 4; ++n) {
        acc[m][n] = __builtin_amdgcn_mfma_f32_16x16x32_bf16(ah[m], bh[n], acc[m][n], 0, 0, 0);
        acc[m][n] = __builtin_amdgcn_mfma_f32_16x16x32_bf16(ah[m], bl[n], acc[m][n], 0, 0, 0);
      }
  }
}
__device__ __forceinline__ void acc_zero(f4 acc[4][4]) {
#pragma unroll
  for (int m = 0; m < 4; ++m)
#pragma unroll
    for (int n = 0; n < 4; ++n)
#pragma unroll
      for (int j = 0; j < 4; ++j) acc[m][n][j] = 0.0f;
}
// C frag -> f32 LDS bounce [128][128] (g5)
__device__ __forceinline__ void acc_store_f32(float* F, f4 acc[4][4], int wr, int wc, int lane,
                                              bool relu) {
  int r15 = lane & 15, q = lane >> 4;
#pragma unroll
  for (int m = 0; m < 4; ++m)
#pragma unroll
    for (int n = 0; n < 4; ++n)
#pragma unroll
      for (int j = 0; j < 4; ++j) {
        float v = acc[m][n][j];
        if (relu) v = fmaxf(v, 0.0f);
        F[(wr * 64 + m * 16 + q * 4 + j) * 128 + wc * 64 + n * 16 + r15] = v;
      }
}
// half-store (pass p writes waves wr==p) into [64][128] f32 bounce
__device__ __forceinline__ void acc_store_half(float* F, f4 acc[4][4], int pass, int wr, int wc,
                                               int lane, bool relu) {
  if (wr != pass) return;
  int r15 = lane & 15, q = lane >> 4;
#pragma unroll
  for (int m = 0; m < 4; ++m)
#pragma unroll
    for (int n = 0; n < 4; ++n)
#pragma unroll
      for (int j = 0; j < 4; ++j) {
        float v = acc[m][n][j];
        if (relu) v = fmaxf(v, 0.0f);
        F[(m * 16 + q * 4 + j) * 128 + wc * 64 + n * 16 + r15] = v;
      }
}

// ---------- prep kernels ----------
__global__ __launch_bounds__(256) void k_costab(float2* csA, float2* csB) {
  int id = blockIdx.x * 256 + threadIdx.x;
  int r = id >> 11, p = id & 2047;
  double freq = exp2(-(double)p / 128.0) * 0.15915494309189533577;
  int t = (r < 16) ? (r * 128) : (r - 16);
  double ph = fmod((double)t * freq, 1.0);
  double ang = ph * 6.2831853071795864769;
  float2 v = make_float2((float)cos(ang), (float)sin(ang));
  if (r < 16) csA[r * 2048 + p] = v;
  else        csB[(r - 16) * 2048 + p] = v;
}

__global__ __launch_bounds__(256) void k_tcast2(const float* __restrict__ in,
                                                u16* __restrict__ outH, u16* __restrict__ outL,
                                                int R, int C) {
  __shared__ float tl[32][33];
  size_t bo = (size_t)blockIdx.z * R * C;
  int tx = threadIdx.x, ty = threadIdx.y;
  int c = blockIdx.x * 32 + tx, r0 = blockIdx.y * 32 + ty;
#pragma unroll
  for (int k = 0; k < 32; k += 8) tl[ty + k][tx] = in[bo + (size_t)(r0 + k) * C + c];
  __syncthreads();
  int rr = blockIdx.y * 32 + tx, cc0 = blockIdx.x * 32 + ty;
#pragma unroll
  for (int k = 0; k < 32; k += 8) {
    float v = tl[tx][ty + k];
    u16 h = f2b(v);
    outH[bo + (size_t)(cc0 + k) * R + rr] = h;
    outL[bo + (size_t)(cc0 + k) * R + rr] = f2b(v - b2f(h));
  }
}

__global__ __launch_bounds__(256) void k_ln_embed(const int* __restrict__ idx,
                                                  const float* __restrict__ embed, int b,
                                                  float* __restrict__ x, u16* __restrict__ xbH,
                                                  u16* __restrict__ xbL) {
  int lane = threadIdx.x & 63, wid = threadIdx.x >> 6;
  int r = blockIdx.x * 4 + wid;
  int id = idx[b * T_ + r] & 255;
  float4 v = ((const float4*)(embed + (size_t)id * 256))[lane];
  float m = wsum(v.x + v.y + v.z + v.w) * (1.0f / 256.0f);
  float d0 = v.x - m, d1 = v.y - m, d2 = v.z - m, d3 = v.w - m;
  float var = wsum(d0 * d0 + d1 * d1 + d2 * d2 + d3 * d3) * (1.0f / 256.0f);
  float rs = 1.0f / sqrtf(var + 1e-5f);
  float y0 = d0 * rs, y1 = d1 * rs, y2 = d2 * rs, y3 = d3 * rs;
  ((float4*)(x + (size_t)r * 256))[lane] = make_float4(y0, y1, y2, y3);
  ushort4 oh, ol;
  oh.x = f2b(y0); ol.x = f2b(y0 - b2f(oh.x));
  oh.y = f2b(y1); ol.y = f2b(y1 - b2f(oh.y));
  oh.z = f2b(y2); ol.z = f2b(y2 - b2f(oh.z));
  oh.w = f2b(y3); ol.w = f2b(y3 - b2f(oh.w));
  ((ushort4*)(xbH + (size_t)r * 256))[lane] = oh;
  ((ushort4*)(xbL + (size_t)r * 256))[lane] = ol;
}

__global__ __launch_bounds__(256) void k_xbt(const u16* __restrict__ xbH,
                                             const u16* __restrict__ xbL,
                                             u16* __restrict__ xbTH, u16* __restrict__ xbTL) {
  int id = blockIdx.x * 256 + threadIdx.x;
  int t = id & 2047, d = id >> 11;
  size_t src = (size_t)t * 256 + d;
  xbTH[id] = xbH[src];
  xbTL[id] = xbL[src];
}

// ---------- GEMM kernels ----------
#define GEMM_PRE2                                                       \
  __shared__ short sm2[24576];                                          \
  short* T0 = sm2;                                                      \
  short* T1 = sm2 + 8192;                                               \
  short* T2 = sm2 + 16384;                                              \
  float* bounce = (float*)sm2;                                          \
  int tid = threadIdx.x;                                                \
  int lane = tid & 63, wid = tid >> 6;                                  \
  int wr = wid >> 1, wc = wid & 1;                                      \
  f4 acc[4][4];                                                         \
  acc_zero(acc);

#define GEMM_PRE2D                                                      \
  __shared__ short smd[49152];                                          \
  float* bounce = (float*)smd;                                          \
  int tid = threadIdx.x;                                                \
  int lane = tid & 63, wid = tid >> 6;                                  \
  int wr = wid >> 1, wc = wid & 1;                                      \
  f4 acc[4][4];                                                         \
  acc_zero(acc);

// G1: x_sparse=relu(xb@enc_hi[h]) -> rope -> QR hi/lo.  2-term. grid(16,32,4), per-b.
__global__ __launch_bounds__(256) void k_g1(const u16* __restrict__ xbH, const u16* __restrict__ xbL,
                                            const u16* __restrict__ etH,
                                            const float2* __restrict__ csA,
                                            const float2* __restrict__ csB,
                                            u16* __restrict__ QRH, u16* __restrict__ QRL) {
  GEMM_PRE2
  int it = blockIdx.x, jt = blockIdx.y, h = blockIdx.z;
  size_t ao = (size_t)it * 128 * 256;
  size_t bo = (size_t)h * NN_ * 256 + (size_t)jt * 128 * 256;
  for (int kb = 0; kb < 4; ++kb) {
    stage_t(xbH + ao + kb * 64, 256, T0, wid, lane);
    stage_t(xbL + ao + kb * 64, 256, T1, wid, lane);
    stage_t(etH + bo + kb * 64, 256, T2, wid, lane);
    __syncthreads();
    mma64x2(T0, T1, T2, wr, wc, lane, acc);
    __syncthreads();
  }
#pragma unroll
  for (int pass = 0; pass < 2; ++pass) {
    acc_store_half(bounce, acc, pass, wr, wc, lane, true);
    __syncthreads();
    for (int w = 0; w < 16; ++w) {
      int e = w * 256 + tid;
      int rrel = e >> 6, p = e & 63;
      float v0 = bounce[rrel * 128 + 2 * p], v1 = bounce[rrel * 128 + 2 * p + 1];
      int t = it * 128 + pass * 64 + rrel, pp = jt * 64 + p;
      float2 c = trig_ct(csA, csB, t, pp);
      float q0 = v0 * c.x - v1 * c.y;
      float q1 = v1 * c.x + v0 * c.y;
      u32 hi, lo;
      split2(q0, q1, hi, lo);
      size_t u32b = (size_t)(h * T_ + t) * 2048 + pp;
      ((u32*)QRH)[u32b] = hi;
      ((u32*)QRL)[u32b] = lo;
    }
    __syncthreads();
  }
}

// G2: S = mask(Qh@Qh^T), 1-term, lower-tri, row-triple, 512 threads (8 waves:
// 2r x 4c of 64x96), 128KB dbuf (2 x AsH|B0|B1|B2). grid 204 per b, XCD chunk.
__global__ __launch_bounds__(512) void k_g2(const u16* __restrict__ QRH,
                                            u16* __restrict__ SpH) {
  __shared__ short smp[65536];             // 128KB: 2 x (AsH|B0|B1|B2)
  float* bounce = (float*)smp;             // 32KB [64][128] f32 (epilogue)
  int tid = threadIdx.x;
  int lane = tid & 63, wid = tid >> 6;     // wid 0..7
  int wr = wid >> 2, wc = wid & 3;         // 2 row-halves x 4 col-waves (64x96 each)
  f4 acc[4][6];
#pragma unroll
  for (int m = 0; m < 4; ++m)
#pragma unroll
    for (int n = 0; n < 6; ++n)
#pragma unroll
      for (int j = 0; j < 4; ++j) acc[m][n][j] = 0.0f;
  // bijective XCD chunking for N=204: q=25, r=4
  int orig = blockIdx.x;
  int xcd = orig & 7, sub = orig >> 3;
  int lb = (xcd < 4 ? xcd * 26 : 104 + (xcd - 4) * 25) + sub;
  int h = lb / 51;
  int rem = lb % 51, i = 0;
  while (rem >= (i + 3) / 3) { rem -= (i + 3) / 3; ++i; }
  int j0 = rem * 3, j1 = j0 + 1, j2 = j0 + 2;
  bool has1 = (j1 <= i), has2 = (j2 <= i);
  size_t base = (size_t)h * T_ * NN_;
  size_t ao = base + (size_t)i * 128 * NN_;
  size_t bo0 = base + (size_t)j0 * 128 * NN_;
  size_t bo1 = base + (size_t)j1 * 128 * NN_;
  size_t bo2 = base + (size_t)j2 * 128 * NN_;
  {  // prologue: stage k=0 into buf0
    stage_t8(QRH + ao, NN_, smp, wid, lane);
    stage_t8(QRH + bo0, NN_, smp + 8192, wid, lane);
    if (has1) stage_t8(QRH + bo1, NN_, smp + 16384, wid, lane);
    if (has2) stage_t8(QRH + bo2, NN_, smp + 24576, wid, lane);
  }
  int r15 = lane & 15, hi4 = lane >> 4;
  int sw = (r15 & 7) << 3;
  for (int kb = 0; kb < 64; ++kb) {
    short* cur = smp + (kb & 1) * 32768;
    __syncthreads();
    if (kb + 1 < 64) {
      short* nxt = smp + ((kb + 1) & 1) * 32768;
      stage_t8(QRH + ao + (kb + 1) * 64, NN_, nxt, wid, lane);
      stage_t8(QRH + bo0 + (kb + 1) * 64, NN_, nxt + 8192, wid, lane);
      if (has1) stage_t8(QRH + bo1 + (kb + 1) * 64, NN_, nxt + 16384, wid, lane);
      if (has2) stage_t8(QRH + bo2 + (kb + 1) * 64, NN_, nxt + 24576, wid, lane);
    }
#pragma unroll
    for (int kk = 0; kk < 2; ++kk) {
      int ko = (kk * 32 + hi4 * 8) ^ sw;
      bf8 ah[4];
#pragma unroll
      for (int m = 0; m < 4; ++m)
        ah[m] = *(const bf8*)(cur + (wr * 64 + m * 16 + r15) * 64 + ko);
#pragma unroll
      for (int n = 0; n < 6; ++n) {
        int cn = wc * 96 + n * 16;
        int bp = cn >> 7;
        if (bp == 1 && !has1) continue;
        if (bp == 2 && !has2) continue;
        bf8 bh = *(const bf8*)(cur + 8192 + bp * 8192 + ((cn & 127) + r15) * 64 + ko);
#pragma unroll
        for (int m = 0; m < 4; ++m)
          acc[m][n] = __builtin_amdgcn_mfma_f32_16x16x32_bf16(ah[m], bh, acc[m][n], 0, 0, 0);
      }
    }
  }
  __syncthreads();
  // epilogue: per present panel, 2 row-passes through 32KB bounce
  int q4 = lane >> 4;
#pragma unroll
  for (int jb = 0; jb < 3; ++jb) {
    if (jb == 1 && !has1) break;
    if (jb == 2 && !has2) break;
    int j = j0 + jb;
    size_t dblk = ((size_t)h * 136 + (size_t)i * (i + 1) / 2 + j) * 16384;
    bool diag = (i == j);
#pragma unroll
    for (int pass = 0; pass < 2; ++pass) {
      if (wr == pass) {
#pragma unroll
        for (int m = 0; m < 4; ++m)
#pragma unroll
          for (int n = 0; n < 6; ++n) {
            int cn = wc * 96 + n * 16;
            if ((cn >> 7) != jb) continue;
#pragma unroll
            for (int jj = 0; jj < 4; ++jj)
              bounce[(m * 16 + q4 * 4 + jj) * 128 + (cn & 127) + r15] = acc[m][n][jj];
          }
      }
      __syncthreads();
      for (int w = 0; w < 8; ++w) {
        int e = w * 512 + tid;
        int rrel = e >> 6, p = e & 63;
        int row = pass * 64 + rrel;
        float s0 = bounce[rrel * 128 + 2 * p], s1 = bounce[rrel * 128 + 2 * p + 1];
        if (diag) {  // strictly lower: col < row
          if (2 * p >= row) s0 = 0.0f;
          if (2 * p + 1 >= row) s1 = 0.0f;
        }
        u32 hi = (u32)f2b(s0) | ((u32)f2b(s1) << 16);
        ((u32*)SpH)[(dblk >> 1) + row * 64 + p] = hi;
      }
      __syncthreads();
    }
  }
}

// G3: yKV_partial = S_hi @ (xh+xl), split-K x2, double-buffered (R15 exact).
// grid(16,2,8): z = h + 4*ks.  per-b.
__global__ __launch_bounds__(256) void k_g3(const u16* __restrict__ SpH,
                                            const u16* __restrict__ xbTH,
                                            const u16* __restrict__ xbTL,
                                            float* __restrict__ yKV0,
                                            float* __restrict__ yKV1) {
  GEMM_PRE2D
  int i = blockIdx.x, jt = blockIdx.y;
  int h = blockIdx.z & 3, ks = blockIdx.z >> 2;
  size_t tri = (size_t)h * 136 + (size_t)i * (i + 1) / 2;
  size_t bo = (size_t)jt * 128 * T_;
  int k0 = ks * (i + 1), k1 = (ks + 1) * (i + 1);   // half-step range
  {  // prologue
    size_t aoff = (tri + (k0 >> 1)) * 16384 + (k0 & 1) * 64;
    stage_t(SpH + aoff, 128, smd, wid, lane);
    stage_t(xbTH + bo + k0 * 64, T_, smd + 8192, wid, lane);
    stage_t(xbTL + bo + k0 * 64, T_, smd + 16384, wid, lane);
  }
  for (int kb = k0; kb < k1; ++kb) {
    short* cur = smd + ((kb - k0) & 1) * 24576;
    __syncthreads();
    if (kb + 1 < k1) {
      short* nxt = smd + ((kb + 1 - k0) & 1) * 24576;
      size_t aoff = (tri + ((kb + 1) >> 1)) * 16384 + ((kb + 1) & 1) * 64;
      stage_t(SpH + aoff, 128, nxt, wid, lane);
      stage_t(xbTH + bo + (kb + 1) * 64, T_, nxt + 8192, wid, lane);
      stage_t(xbTL + bo + (kb + 1) * 64, T_, nxt + 16384, wid, lane);
    }
    mma64x2b(cur, cur + 8192, cur + 16384, wr, wc, lane, acc);
  }
  __syncthreads();
  float* yout = ks ? yKV1 : yKV0;
#pragma unroll
  for (int pass = 0; pass < 2; ++pass) {
    acc_store_half(bounce, acc, pass, wr, wc, lane, false);
    __syncthreads();
    for (int w = 0; w < 32; ++w) {
      int e = w * 256 + tid;
      int row = e >> 7, col = e & 127;
      yout[((size_t)h * T_ + i * 128 + pass * 64 + row) * 256 + jt * 128 + col] =
          bounce[row * 128 + col];
    }
    __syncthreads();
  }
}

// LN over f32 rows of 256 (sum of 2 partials) -> hi/lo bf16.  2048 blocks, per-b.
__global__ __launch_bounds__(256) void k_ln_f32(const float* __restrict__ in0,
                                                const float* __restrict__ in1,
                                                u16* __restrict__ outH, u16* __restrict__ outL) {
  int lane = threadIdx.x & 63, wid = threadIdx.x >> 6;
  int r = blockIdx.x * 4 + wid;
  float4 a = ((const float4*)(in0 + (size_t)r * 256))[lane];
  float4 b = ((const float4*)(in1 + (size_t)r * 256))[lane];
  float v0 = a.x + b.x, v1 = a.y + b.y, v2 = a.z + b.z, v3 = a.w + b.w;
  float m = wsum(v0 + v1 + v2 + v3) * (1.0f / 256.0f);
  float d0 = v0 - m, d1 = v1 - m, d2 = v2 - m, d3 = v3 - m;
  float var = wsum(d0 * d0 + d1 * d1 + d2 * d2 + d3 * d3) * (1.0f / 256.0f);
  float rs = 1.0f / sqrtf(var + 1e-5f);
  float y0 = d0 * rs, y1 = d1 * rs, y2 = d2 * rs, y3 = d3 * rs;
  ushort4 oh, ol;
  oh.x = f2b(y0); ol.x = f2b(y0 - b2f(oh.x));
  oh.y = f2b(y1); ol.y = f2b(y1 - b2f(oh.y));
  oh.z = f2b(y2); ol.z = f2b(y2 - b2f(oh.z));
  oh.w = f2b(y3); ol.w = f2b(y3 - b2f(oh.w));
  ((ushort4*)(outH + (size_t)r * 256))[lane] = oh;
  ((ushort4*)(outL + (size_t)r * 256))[lane] = ol;
}

// G4a: y_sparse=relu((ykh+ykl)@encv_hi[h]); gate by invrope(QR h+l); xy -> QR hi/lo.
// 2-term. grid(16,32,4), per-b.
__global__ __launch_bounds__(256) void k_g4a(const u16* __restrict__ ykH,
                                             const u16* __restrict__ ykL,
                                             const u16* __restrict__ evH,
                                             const float2* __restrict__ csA,
                                             const float2* __restrict__ csB,
                                             u16* __restrict__ QRH, u16* __restrict__ QRL) {
  GEMM_PRE2
  int it = blockIdx.x, jt = blockIdx.y, h = blockIdx.z;
  int t0 = it * 128;
  size_t ao = (size_t)(h * T_ + t0) * 256;
  size_t bo = (size_t)h * NN_ * 256 + (size_t)jt * 128 * 256;
  for (int kb = 0; kb < 4; ++kb) {
    stage_t(ykH + ao + kb * 64, 256, T0, wid, lane);
    stage_t(ykL + ao + kb * 64, 256, T1, wid, lane);
    stage_t(evH + bo + kb * 64, 256, T2, wid, lane);
    __syncthreads();
    mma64x2(T0, T1, T2, wr, wc, lane, acc);
    __syncthreads();
  }
#pragma unroll
  for (int pass = 0; pass < 2; ++pass) {
    acc_store_half(bounce, acc, pass, wr, wc, lane, true);
    __syncthreads();
    for (int w = 0; w < 16; ++w) {
      int e = w * 256 + tid;
      int rrel = e >> 6, p = e & 63;
      float ys0 = bounce[rrel * 128 + 2 * p], ys1 = bounce[rrel * 128 + 2 * p + 1];
      int t = t0 + pass * 64 + rrel, pp = jt * 64 + p;
      size_t u32b = (size_t)(h * T_ + t) * 2048 + pp;
      u32 qh = ((const u32*)QRH)[u32b], ql = ((const u32*)QRL)[u32b];
      float qe = b2f((u16)(qh & 0xffff)) + b2f((u16)(ql & 0xffff));
      float qo = b2f((u16)(qh >> 16)) + b2f((u16)(ql >> 16));
      float2 c = trig_ct(csA, csB, t, pp);
      float xe = fmaxf(qe * c.x + qo * c.y, 0.0f);
      float xo = fmaxf(qo * c.x - qe * c.y, 0.0f);
      u32 hi, lo;
      split2(ys0 * xe, ys1 * xo, hi, lo);
      ((u32*)QRH)[u32b] = hi;
      ((u32*)QRL)[u32b] = lo;
    }
    __syncthreads();
  }
}

// G4b: part[ks*4+h] = (xyh+xyl)[ks-half] @ dec_hi[h][ks-half].  2-term, dbuf.
// grid(16,2,8): z = h + 4*ks.  per-b.
__global__ __launch_bounds__(256) void k_g4b(const u16* __restrict__ xyH,
                                             const u16* __restrict__ xyL,
                                             const u16* __restrict__ dtH,
                                             float* __restrict__ part) {
  GEMM_PRE2D
  int it = blockIdx.x, jt = blockIdx.y;
  int h = blockIdx.z & 3, ks = blockIdx.z >> 2;
  int t0 = it * 128;
  size_t ao = (size_t)(h * T_ + t0) * NN_;
  size_t bo = (size_t)h * D_ * NN_ + (size_t)jt * 128 * NN_;
  int k0 = ks * 32, k1 = ks * 32 + 32;
  {  // prologue
    stage_t(xyH + ao + k0 * 64, NN_, smd, wid, lane);
    stage_t(xyL + ao + k0 * 64, NN_, smd + 8192, wid, lane);
    stage_t(dtH + bo + k0 * 64, NN_, smd + 16384, wid, lane);
  }
  for (int kb = k0; kb < k1; ++kb) {
    short* cur = smd + ((kb - k0) & 1) * 24576;
    __syncthreads();
    if (kb + 1 < k1) {
      short* nxt = smd + ((kb + 1 - k0) & 1) * 24576;
      stage_t(xyH + ao + (kb + 1) * 64, NN_, nxt, wid, lane);
      stage_t(xyL + ao + (kb + 1) * 64, NN_, nxt + 8192, wid, lane);
      stage_t(dtH + bo + (kb + 1) * 64, NN_, nxt + 16384, wid, lane);
    }
    mma64x2(cur, cur + 8192, cur + 16384, wr, wc, lane, acc);
  }
  __syncthreads();
#pragma unroll
  for (int pass = 0; pass < 2; ++pass) {
    acc_store_half(bounce, acc, pass, wr, wc, lane, false);
    __syncthreads();
    for (int w = 0; w < 32; ++w) {
      int e = w * 256 + tid;
      int row = e >> 7, col = e & 127;
      part[((size_t)blockIdx.z * T_ + t0 + pass * 64 + row) * 256 + jt * 128 + col] =
          bounce[row * 128 + col];
    }
    __syncthreads();
  }
}

// LN3: yMLP = sum of 8 part slabs; x = ln(x + ln(yMLP)); refresh x, xb hi/lo. 512 blocks.
__global__ __launch_bounds__(256) void k_ln3(const float* __restrict__ part, float* __restrict__ x,
                                             u16* __restrict__ xbH, u16* __restrict__ xbL) {
  int lane = threadIdx.x & 63, wid = threadIdx.x >> 6;
  int r = blockIdx.x * 4 + wid;
  float a0 = 0, a1 = 0, a2 = 0, a3 = 0;
#pragma unroll
  for (int h = 0; h < 8; ++h) {
    float4 u = ((const float4*)(part + ((size_t)h * T_ + r) * 256))[lane];
    a0 += u.x; a1 += u.y; a2 += u.z; a3 += u.w;
  }
  float m = wsum(a0 + a1 + a2 + a3) * (1.0f / 256.0f);
  float d0 = a0 - m, d1 = a1 - m, d2 = a2 - m, d3 = a3 - m;
  float var = wsum(d0 * d0 + d1 * d1 + d2 * d2 + d3 * d3) * (1.0f / 256.0f);
  float rs = 1.0f / sqrtf(var + 1e-5f);
  float4 xv = ((const float4*)(x + (size_t)r * 256))[lane];
  float s0 = xv.x + d0 * rs, s1 = xv.y + d1 * rs, s2 = xv.z + d2 * rs, s3 = xv.w + d3 * rs;
  float m2 = wsum(s0 + s1 + s2 + s3) * (1.0f / 256.0f);
  float e0 = s0 - m2, e1 = s1 - m2, e2 = s2 - m2, e3 = s3 - m2;
  float var2 = wsum(e0 * e0 + e1 * e1 + e2 * e2 + e3 * e3) * (1.0f / 256.0f);
  float rs2 = 1.0f / sqrtf(var2 + 1e-5f);
  float y0 = e0 * rs2, y1 = e1 * rs2, y2 = e2 * rs2, y3 = e3 * rs2;
  ((float4*)(x + (size_t)r * 256))[lane] = make_float4(y0, y1, y2, y3);
  ushort4 oh, ol;
  oh.x = f2b(y0); ol.x = f2b(y0 - b2f(oh.x));
  oh.y = f2b(y1); ol.y = f2b(y1 - b2f(oh.y));
  oh.z = f2b(y2); ol.z = f2b(y2 - b2f(oh.z));
  oh.w = f2b(y3); ol.w = f2b(y3 - b2f(oh.w));
  ((ushort4*)(xbH + (size_t)r * 256))[lane] = oh;
  ((ushort4*)(xbL + (size_t)r * 256))[lane] = ol;
}

// G5: logits = xb @ lm_head (3-term) -> f32 out.  grid(16,2), per-b.
__global__ __launch_bounds__(256) void k_g5(const u16* __restrict__ xbH,
                                            const u16* __restrict__ xbL,
                                            const u16* __restrict__ lmH,
                                            const u16* __restrict__ lmL,
                                            float* __restrict__ out) {
  __shared__ float smf[16384];
  short* AsH = (short*)smf;
  short* AsL = AsH + 8192;
  short* BsH = AsH + 16384;
  short* BsL = AsH + 24576;
  int tid = threadIdx.x;
  int lane = tid & 63, wid = tid >> 6;
  int wr = wid >> 1, wc = wid & 1;
  f4 acc[4][4];
  acc_zero(acc);
  int it = blockIdx.x, jt = blockIdx.y;
  size_t ao = (size_t)it * 128 * 256;
  size_t bo = (size_t)jt * 128 * 256;
  for (int kb = 0; kb < 4; ++kb) {
    stage_t(xbH + ao + kb * 64, 256, AsH, wid, lane);
    stage_t(xbL + ao + kb * 64, 256, AsL, wid, lane);
    stage_t(lmH + bo + kb * 64, 256, BsH, wid, lane);
    stage_t(lmL + bo + kb * 64, 256, BsL, wid, lane);
    __syncthreads();
    mma64x3(AsH, AsL, BsH, BsL, wr, wc, lane, acc);
    __syncthreads();
  }
  acc_store_f32(smf, acc, wr, wc, lane, false);
  __syncthreads();
  for (int w = 0; w < 64; ++w) {
    int e = w * 256 + tid;
    int row = e >> 7, col = e & 127;
    out[(size_t)(it * 128 + row) * 256 + jt * 128 + col] = smf[row * 128 + col];
  }
}

extern "C" void kernel_launch(void* const* d_in, const int* in_sizes, int n_in, void* d_out,
                              int out_size, void* d_ws, size_t ws_size, hipStream_t stream) {
  const int*   idx   = (const int*)d_in[0];
  const float* embed = (const float*)d_in[1];
  const float* enc   = (const float*)d_in[2];
  const float* encv  = (const float*)d_in[3];
  const float* dec   = (const float*)d_in[4];
  const float* lm    = (const float*)d_in[5];

  if (ws_size < WS_NEED) {
    hipMemsetAsync(d_out, 0x46, (size_t)out_size * 4, stream);
    return;
  }

  char* w = (char*)d_ws;
  float2* csA  = (float2*)(w + CSA_OFF);
  float2* csB  = (float2*)(w + CSB_OFF);
  u16*    etH  = (u16*)(w + ETH_OFF);
  u16*    etL  = (u16*)(w + ETL_OFF);
  u16*    evH  = (u16*)(w + EVH_OFF);
  u16*    evL  = (u16*)(w + EVL_OFF);
  u16*    dtH  = (u16*)(w + DTH_OFF);
  u16*    dtL  = (u16*)(w + DTL_OFF);
  u16*    lmH  = (u16*)(w + LMH_OFF);
  u16*    lmL  = (u16*)(w + LML_OFF);
  float*  x    = (float*)(w + X_OFF);
  u16*    xbH  = (u16*)(w + XBH_OFF);
  u16*    xbL  = (u16*)(w + XBL_OFF);
  u16*    xbTH = (u16*)(w + XBTH_OFF);
  u16*    xbTL = (u16*)(w + XBTL_OFF);
  u16*    QRH  = (u16*)(w + QRH_OFF);
  u16*    QRL  = (u16*)(w + QRL_OFF);
  u16*    SpH  = (u16*)(w + SH_OFF);
  float*  part = (float*)(w + SH_OFF);   // overlays S-hi (S dead after G3)
  float*  yKV1 = (float*)(w + SL_OFF);   // freed S-lo region -> g3 partial 1
  float*  yKV0 = (float*)(w + YKV_OFF);
  u16*    ykH  = (u16*)(w + YKBH_OFF);
  u16*    ykL  = (u16*)(w + YKBL_OFF);

  k_costab<<<1152, 256, 0, stream>>>(csA, csB);
  k_tcast2<<<dim3(128, 8, 4), dim3(32, 8), 0, stream>>>(enc, etH, etL, 256, 4096);
  k_tcast2<<<dim3(128, 8, 4), dim3(32, 8), 0, stream>>>(encv, evH, evL, 256, 4096);
  k_tcast2<<<dim3(8, 128, 4), dim3(32, 8), 0, stream>>>(dec, dtH, dtL, 4096, 256);
  k_tcast2<<<dim3(8, 8, 1), dim3(32, 8), 0, stream>>>(lm, lmH, lmL, 256, 256);

  for (int b = 0; b < 2; ++b) {
    k_ln_embed<<<512, 256, 0, stream>>>(idx, embed, b, x, xbH, xbL);
    k_xbt<<<2048, 256, 0, stream>>>(xbH, xbL, xbTH, xbTL);
    for (int l = 0; l < NLAYER; ++l) {
      k_g1<<<dim3(16, 32, 4), 256, 0, stream>>>(xbH, xbL, etH, csA, csB, QRH, QRL);
      k_g2<<<204, 512, 0, stream>>>(QRH, SpH);
      k_g3<<<dim3(16, 2, 8), 256, 0, stream>>>(SpH, xbTH, xbTL, yKV0, yKV1);
      k_ln_f32<<<2048, 256, 0, stream>>>(yKV0, yKV1, ykH, ykL);
      k_g4a<<<dim3(16, 32, 4), 256, 0, stream>>>(ykH, ykL, evH, csA, csB, QRH, QRL);
      k_g4b<<<dim3(16, 2, 8), 256, 0, stream>>>(QRH, QRL, dtH, part);
      k_ln3<<<512, 256, 0, stream>>>(part, x, xbH, xbL);
      k_xbt<<<2048, 256, 0, stream>>>(xbH, xbL, xbTH, xbTL);
    }
    k_g5<<<dim3(16, 2), 256, 0, stream>>>(xbH, xbL, lmH, lmL, (float*)d_out + (size_t)b * T_ * 256);
  }
}

// Round 19
// 3678.459 us; speedup vs baseline: 1.2645x; 1.0547x over previous
//
#include <hip/hip_runtime.h>

// ===== BDH forward on MI355X — R19: drop QR-lo stream + g4b 1-term =====
// R18 (3880us, absmax 0.01367 — unchanged by g2-lh drop => headroom).
// R19: QRL eliminated (g1 writes hi only; g4a gates from hi; xy stored hi only);
// g4b 1-term (xyH @ decH, 64KB dbuf). Everything else identical to R18.
// Quadrature model: +2 terms -> ~0.0166 predicted (threshold 0.0298).

typedef unsigned short u16;
typedef unsigned int   u32;
typedef __attribute__((ext_vector_type(8))) short bf8;
typedef __attribute__((ext_vector_type(4))) float f4;

#define T_  2048
#define D_  256
#define NH_ 4
#define NN_ 4096
#define NLAYER 6

// ---- workspace layout (bytes); per-b activation buffers ----
#define CSA_OFF  ((size_t)0)                    // float2 [16][2048]  coarse-t trig
#define CSB_OFF  (CSA_OFF  + 262144)            // float2 [128][2048] fine-t trig
#define ETH_OFF  (CSB_OFF  + 2097152)           // bf16 [4][4096][256] enc^T hi
#define ETL_OFF  (ETH_OFF  + 8388608)
#define EVH_OFF  (ETL_OFF  + 8388608)
#define EVL_OFF  (EVH_OFF  + 8388608)
#define DTH_OFF  (EVL_OFF  + 8388608)           // bf16 [4][256][4096] dec^T hi
#define DTL_OFF  (DTH_OFF  + 8388608)
#define LMH_OFF  (DTL_OFF  + 8388608)           // bf16 [256][256] lm^T
#define LML_OFF  (LMH_OFF  + 131072)
#define X_OFF    (LML_OFF  + 131072)            // f32  [2048][256] x (per-b)
#define XBH_OFF  (X_OFF    + 2097152)           // bf16 [2048][256] (per-b)
#define XBL_OFF  (XBH_OFF  + 1048576)
#define XBTH_OFF (XBL_OFF  + 1048576)           // bf16 [256][2048] (per-b)
#define XBTL_OFF (XBTH_OFF + 1048576)
#define QRH_OFF  (XBTL_OFF + 1048576)           // bf16 [4][2048][4096] QR/xy hi (per-b)
#define QRL_OFF  (QRH_OFF  + 67108864)          // UNUSED now (kept for layout stability)
#define SH_OFF   (QRL_OFF  + 67108864)          // bf16 [4][136][16384] S hi (per-b); part f32 overlays
#define SL_OFF   (SH_OFF   + 17825792)          // FREED -> f32 yKV partial-1
#define YKV_OFF  (SL_OFF   + 17825792)          // f32  [4][2048][256] yKV partial-0 (per-b)
#define YKBH_OFF (YKV_OFF  + 8388608)           // bf16 ln(yKV) hi (per-b)
#define YKBL_OFF (YKBH_OFF + 4194304)
#define IDX_END  (YKBL_OFF + 4194304)
#define WS_NEED  (IDX_END  + 16384)             // = 245,907,456 < 253,902,848 proven

// ---------- helpers ----------
__device__ __forceinline__ u16 f2b(float f) {               // RTNE f32->bf16
  u32 u = __builtin_bit_cast(u32, f);
  u32 r = u + 0x7fffu + ((u >> 16) & 1u);
  return (u16)(r >> 16);
}
__device__ __forceinline__ float b2f(u16 h) {
  u32 u = ((u32)h) << 16;
  return __builtin_bit_cast(float, u);
}
__device__ __forceinline__ void split2(float q0, float q1, u32& hi, u32& lo) {
  u16 h0 = f2b(q0), h1 = f2b(q1);
  u16 l0 = f2b(q0 - b2f(h0)), l1 = f2b(q1 - b2f(h1));
  hi = (u32)h0 | ((u32)h1 << 16);
  lo = (u32)l0 | ((u32)l1 << 16);
}
__device__ __forceinline__ float wsum(float v) {
#pragma unroll
  for (int o = 32; o; o >>= 1) v += __shfl_xor(v, o, 64);
  return v;
}
// trig from factored tables: pp = pair index [0,2048), t = time [0,2048)
__device__ __forceinline__ float2 trig_ct(const float2* csA, const float2* csB, int t, int pp) {
  float2 a = csA[(t >> 7) * 2048 + pp];
  float2 b = csB[(t & 127) * 2048 + pp];
  return make_float2(a.x * b.x - a.y * b.y, a.x * b.y + a.y * b.x);
}
__device__ __forceinline__ void gld16(const u16* g, short* l) {
  __builtin_amdgcn_global_load_lds(
      (const __attribute__((address_space(1))) u32*)g,
      (__attribute__((address_space(3))) u32*)l, 16, 0, 0);
}
// stage 128x64 bf16 tile into LDS [128][64], XOR-swizzled; 256-thread (4-wave) form
__device__ __forceinline__ void stage_t(const u16* g, int lda, short* s, int wid, int lane) {
  int r8 = lane >> 3;
  int c8 = ((lane & 7) ^ r8) * 8;
#pragma unroll
  for (int j = 0; j < 4; ++j) {
    int row = wid * 32 + j * 8;
    gld16(g + (size_t)(row + r8) * lda + c8, s + row * 64);
  }
}
// 512-thread (8-wave) stage: each wave covers 16 rows
__device__ __forceinline__ void stage_t8(const u16* g, int lda, short* s, int wid, int lane) {
  int r8 = lane >> 3;
  int c8 = ((lane & 7) ^ r8) * 8;
#pragma unroll
  for (int j = 0; j < 2; ++j) {
    int row = wid * 16 + j * 8;
    gld16(g + (size_t)(row + r8) * lda + c8, s + row * 64);
  }
}
// BK=64 step, 3-term split: 96 MFMA — g5 only
__device__ __forceinline__ void mma64x3(const short* AsH, const short* AsL, const short* BsH,
                                        const short* BsL, int wr, int wc, int lane,
                                        f4 acc[4][4]) {
  int r15 = lane & 15, hi = lane >> 4;
  int sw = (r15 & 7) << 3;
#pragma unroll
  for (int kk = 0; kk < 2; ++kk) {
    int ko = (kk * 32 + hi * 8) ^ sw;
    bf8 ah[4], al[4], bh[4], bl[4];
#pragma unroll
    for (int m = 0; m < 4; ++m) {
      int off = (wr * 64 + m * 16 + r15) * 64 + ko;
      ah[m] = *(const bf8*)(AsH + off);
      al[m] = *(const bf8*)(AsL + off);
    }
#pragma unroll
    for (int n = 0; n < 4; ++n) {
      int off = (wc * 64 + n * 16 + r15) * 64 + ko;
      bh[n] = *(const bf8*)(BsH + off);
      bl[n] = *(const bf8*)(BsL + off);
    }
#pragma unroll
    for (int m = 0; m < 4; ++m)
#pragma unroll
      for (int n = 0; n < 4; ++n) {
        acc[m][n] = __builtin_amdgcn_mfma_f32_16x16x32_bf16(ah[m], bh[n], acc[m][n], 0, 0, 0);
        acc[m][n] = __builtin_amdgcn_mfma_f32_16x16x32_bf16(al[m], bh[n], acc[m][n], 0, 0, 0);
        acc[m][n] = __builtin_amdgcn_mfma_f32_16x16x32_bf16(ah[m], bl[n], acc[m][n], 0, 0, 0);
      }
  }
}
// BK=64 step, 2-term A-split: acc += (Ah+Al)*Bh^T — g1/g4a
__device__ __forceinline__ void mma64x2(const short* AsH, const short* AsL, const short* BsH,
                                        int wr, int wc, int lane, f4 acc[4][4]) {
  int r15 = lane & 15, hi = lane >> 4;
  int sw = (r15 & 7) << 3;
#pragma unroll
  for (int kk = 0; kk < 2; ++kk) {
    int ko = (kk * 32 + hi * 8) ^ sw;
    bf8 ah[4], al[4], bh[4];
#pragma unroll
    for (int m = 0; m < 4; ++m) {
      int off = (wr * 64 + m * 16 + r15) * 64 + ko;
      ah[m] = *(const bf8*)(AsH + off);
      al[m] = *(const bf8*)(AsL + off);
    }
#pragma unroll
    for (int n = 0; n < 4; ++n)
      bh[n] = *(const bf8*)(BsH + (wc * 64 + n * 16 + r15) * 64 + ko);
#pragma unroll
    for (int m = 0; m < 4; ++m)
#pragma unroll
      for (int n = 0; n < 4; ++n) {
        acc[m][n] = __builtin_amdgcn_mfma_f32_16x16x32_bf16(ah[m], bh[n], acc[m][n], 0, 0, 0);
        acc[m][n] = __builtin_amdgcn_mfma_f32_16x16x32_bf16(al[m], bh[n], acc[m][n], 0, 0, 0);
      }
  }
}
// BK=64 step, 1-term: acc += Ah*Bh^T  (32 MFMA) — g4b
__device__ __forceinline__ void mma64x1(const short* AsH, const short* BsH,
                                        int wr, int wc, int lane, f4 acc[4][4]) {
  int r15 = lane & 15, hi = lane >> 4;
  int sw = (r15 & 7) << 3;
#pragma unroll
  for (int kk = 0; kk < 2; ++kk) {
    int ko = (kk * 32 + hi * 8) ^ sw;
    bf8 ah[4], bh[4];
#pragma unroll
    for (int m = 0; m < 4; ++m)
      ah[m] = *(const bf8*)(AsH + (wr * 64 + m * 16 + r15) * 64 + ko);
#pragma unroll
    for (int n = 0; n < 4; ++n)
      bh[n] = *(const bf8*)(BsH + (wc * 64 + n * 16 + r15) * 64 + ko);
#pragma unroll
    for (int m = 0; m < 4; ++m)
#pragma unroll
      for (int n = 0; n < 4; ++n)
        acc[m][n] = __builtin_amdgcn_mfma_f32_16x16x32_bf16(ah[m], bh[n], acc[m][n], 0, 0, 0);
  }
}
// BK=64 step, 2-term B-split: acc += Ah*(Bh+Bl)^T — g3
__device__ __forceinline__ void mma64x2b(const short* AsH, const short* BsH, const short* BsL,
                                         int wr, int wc, int lane, f4 acc[4][4]) {
  int r15 = lane & 15, hi = lane >> 4;
  int sw = (r15 & 7) << 3;
#pragma unroll
  for (int kk = 0; kk < 2; ++kk) {
    int ko = (kk * 32 + hi * 8) ^ sw;
    bf8 ah[4], bh[4], bl[4];
#pragma unroll
    for (int m = 0; m < 4; ++m)
      ah[m] = *(const bf8*)(AsH + (wr * 64 + m * 16 + r15) * 64 + ko);
#pragma unroll
    for (int n = 0; n < 4; ++n) {
      int off = (wc * 64 + n * 16 + r15) * 64 + ko;
      bh[n] = *(const bf8*)(BsH + off);
      bl[n] = *(const bf8*)(BsL + off);
    }
#pragma unroll
    for (int m = 0; m < 4; ++m)
#pragma unroll
      for (int n = 0; n < 4; ++n) {
        acc[m][n] = __builtin_amdgcn_mfma_f32_16x16x32_bf16(ah[m], bh[n], acc[m][n], 0, 0, 0);
        acc[m][n] = __builtin_amdgcn_mfma_f32_16x16x32_bf16(ah[m], bl[n], acc[m][n], 0, 0, 0);
      }
  }
}
__device__ __forceinline__ void acc_zero(f4 acc[4][4]) {
#pragma unroll
  for (int m = 0; m < 4; ++m)
#pragma unroll
    for (int n = 0; n < 4; ++n)
#pragma unroll
      for (int j = 0; j < 4; ++j) acc[m][n][j] = 0.0f;
}
// C frag -> f32 LDS bounce [128][128] (g5)
__device__ __forceinline__ void acc_store_f32(float* F, f4 acc[4][4], int wr, int wc, int lane,
                                              bool relu) {
  int r15 = lane & 15, q = lane >> 4;
#pragma unroll
  for (int m = 0; m < 4; ++m)
#pragma unroll
    for (int n = 0; n < 4; ++n)
#pragma unroll
      for (int j = 0; j < 4; ++j) {
        float v = acc[m][n][j];
        if (relu) v = fmaxf(v, 0.0f);
        F[(wr * 64 + m * 16 + q * 4 + j) * 128 + wc * 64 + n * 16 + r15] = v;
      }
}
// half-store (pass p writes waves wr==p) into [64][128] f32 bounce
__device__ __forceinline__ void acc_store_half(float* F, f4 acc[4][4], int pass, int wr, int wc,
                                               int lane, bool relu) {
  if (wr != pass) return;
  int r15 = lane & 15, q = lane >> 4;
#pragma unroll
  for (int m = 0; m < 4; ++m)
#pragma unroll
    for (int n = 0; n < 4; ++n)
#pragma unroll
      for (int j = 0; j < 4; ++j) {
        float v = acc[m][n][j];
        if (relu) v = fmaxf(v, 0.0f);
        F[(m * 16 + q * 4 + j) * 128 + wc * 64 + n * 16 + r15] = v;
      }
}

// ---------- prep kernels ----------
__global__ __launch_bounds__(256) void k_costab(float2* csA, float2* csB) {
  int id = blockIdx.x * 256 + threadIdx.x;
  int r = id >> 11, p = id & 2047;
  double freq = exp2(-(double)p / 128.0) * 0.15915494309189533577;
  int t = (r < 16) ? (r * 128) : (r - 16);
  double ph = fmod((double)t * freq, 1.0);
  double ang = ph * 6.2831853071795864769;
  float2 v = make_float2((float)cos(ang), (float)sin(ang));
  if (r < 16) csA[r * 2048 + p] = v;
  else        csB[(r - 16) * 2048 + p] = v;
}

__global__ __launch_bounds__(256) void k_tcast2(const float* __restrict__ in,
                                                u16* __restrict__ outH, u16* __restrict__ outL,
                                                int R, int C) {
  __shared__ float tl[32][33];
  size_t bo = (size_t)blockIdx.z * R * C;
  int tx = threadIdx.x, ty = threadIdx.y;
  int c = blockIdx.x * 32 + tx, r0 = blockIdx.y * 32 + ty;
#pragma unroll
  for (int k = 0; k < 32; k += 8) tl[ty + k][tx] = in[bo + (size_t)(r0 + k) * C + c];
  __syncthreads();
  int rr = blockIdx.y * 32 + tx, cc0 = blockIdx.x * 32 + ty;
#pragma unroll
  for (int k = 0; k < 32; k += 8) {
    float v = tl[tx][ty + k];
    u16 h = f2b(v);
    outH[bo + (size_t)(cc0 + k) * R + rr] = h;
    outL[bo + (size_t)(cc0 + k) * R + rr] = f2b(v - b2f(h));
  }
}

__global__ __launch_bounds__(256) void k_ln_embed(const int* __restrict__ idx,
                                                  const float* __restrict__ embed, int b,
                                                  float* __restrict__ x, u16* __restrict__ xbH,
                                                  u16* __restrict__ xbL) {
  int lane = threadIdx.x & 63, wid = threadIdx.x >> 6;
  int r = blockIdx.x * 4 + wid;
  int id = idx[b * T_ + r] & 255;
  float4 v = ((const float4*)(embed + (size_t)id * 256))[lane];
  float m = wsum(v.x + v.y + v.z + v.w) * (1.0f / 256.0f);
  float d0 = v.x - m, d1 = v.y - m, d2 = v.z - m, d3 = v.w - m;
  float var = wsum(d0 * d0 + d1 * d1 + d2 * d2 + d3 * d3) * (1.0f / 256.0f);
  float rs = 1.0f / sqrtf(var + 1e-5f);
  float y0 = d0 * rs, y1 = d1 * rs, y2 = d2 * rs, y3 = d3 * rs;
  ((float4*)(x + (size_t)r * 256))[lane] = make_float4(y0, y1, y2, y3);
  ushort4 oh, ol;
  oh.x = f2b(y0); ol.x = f2b(y0 - b2f(oh.x));
  oh.y = f2b(y1); ol.y = f2b(y1 - b2f(oh.y));
  oh.z = f2b(y2); ol.z = f2b(y2 - b2f(oh.z));
  oh.w = f2b(y3); ol.w = f2b(y3 - b2f(oh.w));
  ((ushort4*)(xbH + (size_t)r * 256))[lane] = oh;
  ((ushort4*)(xbL + (size_t)r * 256))[lane] = ol;
}

__global__ __launch_bounds__(256) void k_xbt(const u16* __restrict__ xbH,
                                             const u16* __restrict__ xbL,
                                             u16* __restrict__ xbTH, u16* __restrict__ xbTL) {
  int id = blockIdx.x * 256 + threadIdx.x;
  int t = id & 2047, d = id >> 11;
  size_t src = (size_t)t * 256 + d;
  xbTH[id] = xbH[src];
  xbTL[id] = xbL[src];
}

// ---------- GEMM kernels ----------
#define GEMM_PRE2                                                       \
  __shared__ short sm2[24576];                                          \
  short* T0 = sm2;                                                      \
  short* T1 = sm2 + 8192;                                               \
  short* T2 = sm2 + 16384;                                              \
  float* bounce = (float*)sm2;                                          \
  int tid = threadIdx.x;                                                \
  int lane = tid & 63, wid = tid >> 6;                                  \
  int wr = wid >> 1, wc = wid & 1;                                      \
  f4 acc[4][4];                                                         \
  acc_zero(acc);

#define GEMM_PRE2D                                                      \
  __shared__ short smd[49152];                                          \
  float* bounce = (float*)smd;                                          \
  int tid = threadIdx.x;                                                \
  int lane = tid & 63, wid = tid >> 6;                                  \
  int wr = wid >> 1, wc = wid & 1;                                      \
  f4 acc[4][4];                                                         \
  acc_zero(acc);

#define GEMM_PRE1D                                                      \
  __shared__ short smd1[32768];                                         \
  float* bounce = (float*)smd1;                                         \
  int tid = threadIdx.x;                                                \
  int lane = tid & 63, wid = tid >> 6;                                  \
  int wr = wid >> 1, wc = wid & 1;                                      \
  f4 acc[4][4];                                                         \
  acc_zero(acc);

// G1: x_sparse=relu(xb@enc_hi[h]) -> rope -> QR hi ONLY.  2-term. grid(16,32,4), per-b.
__global__ __launch_bounds__(256) void k_g1(const u16* __restrict__ xbH, const u16* __restrict__ xbL,
                                            const u16* __restrict__ etH,
                                            const float2* __restrict__ csA,
                                            const float2* __restrict__ csB,
                                            u16* __restrict__ QRH) {
  GEMM_PRE2
  int it = blockIdx.x, jt = blockIdx.y, h = blockIdx.z;
  size_t ao = (size_t)it * 128 * 256;
  size_t bo = (size_t)h * NN_ * 256 + (size_t)jt * 128 * 256;
  for (int kb = 0; kb < 4; ++kb) {
    stage_t(xbH + ao + kb * 64, 256, T0, wid, lane);
    stage_t(xbL + ao + kb * 64, 256, T1, wid, lane);
    stage_t(etH + bo + kb * 64, 256, T2, wid, lane);
    __syncthreads();
    mma64x2(T0, T1, T2, wr, wc, lane, acc);
    __syncthreads();
  }
#pragma unroll
  for (int pass = 0; pass < 2; ++pass) {
    acc_store_half(bounce, acc, pass, wr, wc, lane, true);
    __syncthreads();
    for (int w = 0; w < 16; ++w) {
      int e = w * 256 + tid;
      int rrel = e >> 6, p = e & 63;
      float v0 = bounce[rrel * 128 + 2 * p], v1 = bounce[rrel * 128 + 2 * p + 1];
      int t = it * 128 + pass * 64 + rrel, pp = jt * 64 + p;
      float2 c = trig_ct(csA, csB, t, pp);
      float q0 = v0 * c.x - v1 * c.y;
      float q1 = v1 * c.x + v0 * c.y;
      u32 hi = (u32)f2b(q0) | ((u32)f2b(q1) << 16);
      ((u32*)QRH)[(size_t)(h * T_ + t) * 2048 + pp] = hi;
    }
    __syncthreads();
  }
}

// G2: S = mask(Qh@Qh^T), 1-term, lower-tri, row-triple, 512 threads (8 waves:
// 2r x 4c of 64x96), 128KB dbuf (2 x AsH|B0|B1|B2). grid 204 per b, XCD chunk.
__global__ __launch_bounds__(512) void k_g2(const u16* __restrict__ QRH,
                                            u16* __restrict__ SpH) {
  __shared__ short smp[65536];             // 128KB: 2 x (AsH|B0|B1|B2)
  float* bounce = (float*)smp;             // 32KB [64][128] f32 (epilogue)
  int tid = threadIdx.x;
  int lane = tid & 63, wid = tid >> 6;     // wid 0..7
  int wr = wid >> 2, wc = wid & 3;         // 2 row-halves x 4 col-waves (64x96 each)
  f4 acc[4][6];
#pragma unroll
  for (int m = 0; m < 4; ++m)
#pragma unroll
    for (int n = 0; n < 6; ++n)
#pragma unroll
      for (int j = 0; j < 4; ++j) acc[m][n][j] = 0.0f;
  // bijective XCD chunking for N=204: q=25, r=4
  int orig = blockIdx.x;
  int xcd = orig & 7, sub = orig >> 3;
  int lb = (xcd < 4 ? xcd * 26 : 104 + (xcd - 4) * 25) + sub;
  int h = lb / 51;
  int rem = lb % 51, i = 0;
  while (rem >= (i + 3) / 3) { rem -= (i + 3) / 3; ++i; }
  int j0 = rem * 3, j1 = j0 + 1, j2 = j0 + 2;
  bool has1 = (j1 <= i), has2 = (j2 <= i);
  size_t base = (size_t)h * T_ * NN_;
  size_t ao = base + (size_t)i * 128 * NN_;
  size_t bo0 = base + (size_t)j0 * 128 * NN_;
  size_t bo1 = base + (size_t)j1 * 128 * NN_;
  size_t bo2 = base + (size_t)j2 * 128 * NN_;
  {  // prologue: stage k=0 into buf0
    stage_t8(QRH + ao, NN_, smp, wid, lane);
    stage_t8(QRH + bo0, NN_, smp + 8192, wid, lane);
    if (has1) stage_t8(QRH + bo1, NN_, smp + 16384, wid, lane);
    if (has2) stage_t8(QRH + bo2, NN_, smp + 24576, wid, lane);
  }
  int r15 = lane & 15, hi4 = lane >> 4;
  int sw = (r15 & 7) << 3;
  for (int kb = 0; kb < 64; ++kb) {
    short* cur = smp + (kb & 1) * 32768;
    __syncthreads();
    if (kb + 1 < 64) {
      short* nxt = smp + ((kb + 1) & 1) * 32768;
      stage_t8(QRH + ao + (kb + 1) * 64, NN_, nxt, wid, lane);
      stage_t8(QRH + bo0 + (kb + 1) * 64, NN_, nxt + 8192, wid, lane);
      if (has1) stage_t8(QRH + bo1 + (kb + 1) * 64, NN_, nxt + 16384, wid, lane);
      if (has2) stage_t8(QRH + bo2 + (kb + 1) * 64, NN_, nxt + 24576, wid, lane);
    }
#pragma unroll
    for (int kk = 0; kk < 2; ++kk) {
      int ko = (kk * 32 + hi4 * 8) ^ sw;
      bf8 ah[4];
#pragma unroll
      for (int m = 0; m < 4; ++m)
        ah[m] = *(const bf8*)(cur + (wr * 64 + m * 16 + r15) * 64 + ko);
#pragma unroll
      for (int n = 0; n < 6; ++n) {
        int cn = wc * 96 + n * 16;
        int bp = cn >> 7;
        if (bp == 1 && !has1) continue;
        if (bp == 2 && !has2) continue;
        bf8 bh = *(const bf8*)(cur + 8192 + bp * 8192 + ((cn & 127) + r15) * 64 + ko);
#pragma unroll
        for (int m = 0; m < 4; ++m)
          acc[m][n] = __builtin_amdgcn_mfma_f32_16x16x32_bf16(ah[m], bh, acc[m][n], 0, 0, 0);
      }
    }
  }
  __syncthreads();
  // epilogue: per present panel, 2 row-passes through 32KB bounce
  int q4 = lane >> 4;
#pragma unroll
  for (int jb = 0; jb < 3; ++jb) {
    if (jb == 1 && !has1) break;
    if (jb == 2 && !has2) break;
    int j = j0 + jb;
    size_t dblk = ((size_t)h * 136 + (size_t)i * (i + 1) / 2 + j) * 16384;
    bool diag = (i == j);
#pragma unroll
    for (int pass = 0; pass < 2; ++pass) {
      if (wr == pass) {
#pragma unroll
        for (int m = 0; m < 4; ++m)
#pragma unroll
          for (int n = 0; n < 6; ++n) {
            int cn = wc * 96 + n * 16;
            if ((cn >> 7) != jb) continue;
#pragma unroll
            for (int jj = 0; jj < 4; ++jj)
              bounce[(m * 16 + q4 * 4 + jj) * 128 + (cn & 127) + r15] = acc[m][n][jj];
          }
      }
      __syncthreads();
      for (int w = 0; w < 8; ++w) {
        int e = w * 512 + tid;
        int rrel = e >> 6, p = e & 63;
        int row = pass * 64 + rrel;
        float s0 = bounce[rrel * 128 + 2 * p], s1 = bounce[rrel * 128 + 2 * p + 1];
        if (diag) {  // strictly lower: col < row
          if (2 * p >= row) s0 = 0.0f;
          if (2 * p + 1 >= row) s1 = 0.0f;
        }
        u32 hi = (u32)f2b(s0) | ((u32)f2b(s1) << 16);
        ((u32*)SpH)[(dblk >> 1) + row * 64 + p] = hi;
      }
      __syncthreads();
    }
  }
}

// G3: yKV_partial = S_hi @ (xh+xl), split-K x2, double-buffered.
// grid(16,2,8): z = h + 4*ks.  per-b.
__global__ __launch_bounds__(256) void k_g3(const u16* __restrict__ SpH,
                                            const u16* __restrict__ xbTH,
                                            const u16* __restrict__ xbTL,
                                            float* __restrict__ yKV0,
                                            float* __restrict__ yKV1) {
  GEMM_PRE2D
  int i = blockIdx.x, jt = blockIdx.y;
  int h = blockIdx.z & 3, ks = blockIdx.z >> 2;
  size_t tri = (size_t)h * 136 + (size_t)i * (i + 1) / 2;
  size_t bo = (size_t)jt * 128 * T_;
  int k0 = ks * (i + 1), k1 = (ks + 1) * (i + 1);   // half-step range
  {  // prologue
    size_t aoff = (tri + (k0 >> 1)) * 16384 + (k0 & 1) * 64;
    stage_t(SpH + aoff, 128, smd, wid, lane);
    stage_t(xbTH + bo + k0 * 64, T_, smd + 8192, wid, lane);
    stage_t(xbTL + bo + k0 * 64, T_, smd + 16384, wid, lane);
  }
  for (int kb = k0; kb < k1; ++kb) {
    short* cur = smd + ((kb - k0) & 1) * 24576;
    __syncthreads();
    if (kb + 1 < k1) {
      short* nxt = smd + ((kb + 1 - k0) & 1) * 24576;
      size_t aoff = (tri + ((kb + 1) >> 1)) * 16384 + ((kb + 1) & 1) * 64;
      stage_t(SpH + aoff, 128, nxt, wid, lane);
      stage_t(xbTH + bo + (kb + 1) * 64, T_, nxt + 8192, wid, lane);
      stage_t(xbTL + bo + (kb + 1) * 64, T_, nxt + 16384, wid, lane);
    }
    mma64x2b(cur, cur + 8192, cur + 16384, wr, wc, lane, acc);
  }
  __syncthreads();
  float* yout = ks ? yKV1 : yKV0;
#pragma unroll
  for (int pass = 0; pass < 2; ++pass) {
    acc_store_half(bounce, acc, pass, wr, wc, lane, false);
    __syncthreads();
    for (int w = 0; w < 32; ++w) {
      int e = w * 256 + tid;
      int row = e >> 7, col = e & 127;
      yout[((size_t)h * T_ + i * 128 + pass * 64 + row) * 256 + jt * 128 + col] =
          bounce[row * 128 + col];
    }
    __syncthreads();
  }
}

// LN over f32 rows of 256 (sum of 2 partials) -> hi/lo bf16.  2048 blocks, per-b.
__global__ __launch_bounds__(256) void k_ln_f32(const float* __restrict__ in0,
                                                const float* __restrict__ in1,
                                                u16* __restrict__ outH, u16* __restrict__ outL) {
  int lane = threadIdx.x & 63, wid = threadIdx.x >> 6;
  int r = blockIdx.x * 4 + wid;
  float4 a = ((const float4*)(in0 + (size_t)r * 256))[lane];
  float4 b = ((const float4*)(in1 + (size_t)r * 256))[lane];
  float v0 = a.x + b.x, v1 = a.y + b.y, v2 = a.z + b.z, v3 = a.w + b.w;
  float m = wsum(v0 + v1 + v2 + v3) * (1.0f / 256.0f);
  float d0 = v0 - m, d1 = v1 - m, d2 = v2 - m, d3 = v3 - m;
  float var = wsum(d0 * d0 + d1 * d1 + d2 * d2 + d3 * d3) * (1.0f / 256.0f);
  float rs = 1.0f / sqrtf(var + 1e-5f);
  float y0 = d0 * rs, y1 = d1 * rs, y2 = d2 * rs, y3 = d3 * rs;
  ushort4 oh, ol;
  oh.x = f2b(y0); ol.x = f2b(y0 - b2f(oh.x));
  oh.y = f2b(y1); ol.y = f2b(y1 - b2f(oh.y));
  oh.z = f2b(y2); ol.z = f2b(y2 - b2f(oh.z));
  oh.w = f2b(y3); ol.w = f2b(y3 - b2f(oh.w));
  ((ushort4*)(outH + (size_t)r * 256))[lane] = oh;
  ((ushort4*)(outL + (size_t)r * 256))[lane] = ol;
}

// G4a: y_sparse=relu((ykh+ykl)@encv_hi[h]); gate by invrope(QR hi); xy -> QR hi ONLY.
// 2-term. grid(16,32,4), per-b.
__global__ __launch_bounds__(256) void k_g4a(const u16* __restrict__ ykH,
                                             const u16* __restrict__ ykL,
                                             const u16* __restrict__ evH,
                                             const float2* __restrict__ csA,
                                             const float2* __restrict__ csB,
                                             u16* __restrict__ QRH) {
  GEMM_PRE2
  int it = blockIdx.x, jt = blockIdx.y, h = blockIdx.z;
  int t0 = it * 128;
  size_t ao = (size_t)(h * T_ + t0) * 256;
  size_t bo = (size_t)h * NN_ * 256 + (size_t)jt * 128 * 256;
  for (int kb = 0; kb < 4; ++kb) {
    stage_t(ykH + ao + kb * 64, 256, T0, wid, lane);
    stage_t(ykL + ao + kb * 64, 256, T1, wid, lane);
    stage_t(evH + bo + kb * 64, 256, T2, wid, lane);
    __syncthreads();
    mma64x2(T0, T1, T2, wr, wc, lane, acc);
    __syncthreads();
  }
#pragma unroll
  for (int pass = 0; pass < 2; ++pass) {
    acc_store_half(bounce, acc, pass, wr, wc, lane, true);
    __syncthreads();
    for (int w = 0; w < 16; ++w) {
      int e = w * 256 + tid;
      int rrel = e >> 6, p = e & 63;
      float ys0 = bounce[rrel * 128 + 2 * p], ys1 = bounce[rrel * 128 + 2 * p + 1];
      int t = t0 + pass * 64 + rrel, pp = jt * 64 + p;
      size_t u32b = (size_t)(h * T_ + t) * 2048 + pp;
      u32 qh = ((const u32*)QRH)[u32b];
      float qe = b2f((u16)(qh & 0xffff));
      float qo = b2f((u16)(qh >> 16));
      float2 c = trig_ct(csA, csB, t, pp);
      float xe = fmaxf(qe * c.x + qo * c.y, 0.0f);  // inverse rotation from hi; x_sparse >= 0
      float xo = fmaxf(qo * c.x - qe * c.y, 0.0f);
      u32 hi = (u32)f2b(ys0 * xe) | ((u32)f2b(ys1 * xo) << 16);
      ((u32*)QRH)[u32b] = hi;
    }
    __syncthreads();
  }
}

// G4b: part[ks*4+h] = xyH[ks-half] @ dec_hi[h][ks-half].  1-term, 64KB dbuf.
// grid(16,2,8): z = h + 4*ks.  per-b.
__global__ __launch_bounds__(256) void k_g4b(const u16* __restrict__ xyH,
                                             const u16* __restrict__ dtH,
                                             float* __restrict__ part) {
  GEMM_PRE1D
  int it = blockIdx.x, jt = blockIdx.y;
  int h = blockIdx.z & 3, ks = blockIdx.z >> 2;
  int t0 = it * 128;
  size_t ao = (size_t)(h * T_ + t0) * NN_;
  size_t bo = (size_t)h * D_ * NN_ + (size_t)jt * 128 * NN_;
  int k0 = ks * 32, k1 = ks * 32 + 32;
  {  // prologue
    stage_t(xyH + ao + k0 * 64, NN_, smd1, wid, lane);
    stage_t(dtH + bo + k0 * 64, NN_, smd1 + 8192, wid, lane);
  }
  for (int kb = k0; kb < k1; ++kb) {
    short* cur = smd1 + ((kb - k0) & 1) * 16384;
    __syncthreads();
    if (kb + 1 < k1) {
      short* nxt = smd1 + ((kb + 1 - k0) & 1) * 16384;
      stage_t(xyH + ao + (kb + 1) * 64, NN_, nxt, wid, lane);
      stage_t(dtH + bo + (kb + 1) * 64, NN_, nxt + 8192, wid, lane);
    }
    mma64x1(cur, cur + 8192, wr, wc, lane, acc);
  }
  __syncthreads();
#pragma unroll
  for (int pass = 0; pass < 2; ++pass) {
    acc_store_half(bounce, acc, pass, wr, wc, lane, false);
    __syncthreads();
    for (int w = 0; w < 32; ++w) {
      int e = w * 256 + tid;
      int row = e >> 7, col = e & 127;
      part[((size_t)blockIdx.z * T_ + t0 + pass * 64 + row) * 256 + jt * 128 + col] =
          bounce[row * 128 + col];
    }
    __syncthreads();
  }
}

// LN3: yMLP = sum of 8 part slabs; x = ln(x + ln(yMLP)); refresh x, xb hi/lo. 512 blocks.
__global__ __launch_bounds__(256) void k_ln3(const float* __restrict__ part, float* __restrict__ x,
                                             u16* __restrict__ xbH, u16* __restrict__ xbL) {
  int lane = threadIdx.x & 63, wid = threadIdx.x >> 6;
  int r = blockIdx.x * 4 + wid;
  float a0 = 0, a1 = 0, a2 = 0, a3 = 0;
#pragma unroll
  for (int h = 0; h < 8; ++h) {
    float4 u = ((const float4*)(part + ((size_t)h * T_ + r) * 256))[lane];
    a0 += u.x; a1 += u.y; a2 += u.z; a3 += u.w;
  }
  float m = wsum(a0 + a1 + a2 + a3) * (1.0f / 256.0f);
  float d0 = a0 - m, d1 = a1 - m, d2 = a2 - m, d3 = a3 - m;
  float var = wsum(d0 * d0 + d1 * d1 + d2 * d2 + d3 * d3) * (1.0f / 256.0f);
  float rs = 1.0f / sqrtf(var + 1e-5f);
  float4 xv = ((const float4*)(x + (size_t)r * 256))[lane];
  float s0 = xv.x + d0 * rs, s1 = xv.y + d1 * rs, s2 = xv.z + d2 * rs, s3 = xv.w + d3 * rs;
  float m2 = wsum(s0 + s1 + s2 + s3) * (1.0f / 256.0f);
  float e0 = s0 - m2, e1 = s1 - m2, e2 = s2 - m2, e3 = s3 - m2;
  float var2 = wsum(e0 * e0 + e1 * e1 + e2 * e2 + e3 * e3) * (1.0f / 256.0f);
  float rs2 = 1.0f / sqrtf(var2 + 1e-5f);
  float y0 = e0 * rs2, y1 = e1 * rs2, y2 = e2 * rs2, y3 = e3 * rs2;
  ((float4*)(x + (size_t)r * 256))[lane] = make_float4(y0, y1, y2, y3);
  ushort4 oh, ol;
  oh.x = f2b(y0); ol.x = f2b(y0 - b2f(oh.x));
  oh.y = f2b(y1); ol.y = f2b(y1 - b2f(oh.y));
  oh.z = f2b(y2); ol.z = f2b(y2 - b2f(oh.z));
  oh.w = f2b(y3); ol.w = f2b(y3 - b2f(oh.w));
  ((ushort4*)(xbH + (size_t)r * 256))[lane] = oh;
  ((ushort4*)(xbL + (size_t)r * 256))[lane] = ol;
}

// G5: logits = xb @ lm_head (3-term) -> f32 out.  grid(16,2), per-b.
__global__ __launch_bounds__(256) void k_g5(const u16* __restrict__ xbH,
                                            const u16* __restrict__ xbL,
                                            const u16* __restrict__ lmH,
                                            const u16* __restrict__ lmL,
                                            float* __restrict__ out) {
  __shared__ float smf[16384];
  short* AsH = (short*)smf;
  short* AsL = AsH + 8192;
  short* BsH = AsH + 16384;
  short* BsL = AsH + 24576;
  int tid = threadIdx.x;
  int lane = tid & 63, wid = tid >> 6;
  int wr = wid >> 1, wc = wid & 1;
  f4 acc[4][4];
  acc_zero(acc);
  int it = blockIdx.x, jt = blockIdx.y;
  size_t ao = (size_t)it * 128 * 256;
  size_t bo = (size_t)jt * 128 * 256;
  for (int kb = 0; kb < 4; ++kb) {
    stage_t(xbH + ao + kb * 64, 256, AsH, wid, lane);
    stage_t(xbL + ao + kb * 64, 256, AsL, wid, lane);
    stage_t(lmH + bo + kb * 64, 256, BsH, wid, lane);
    stage_t(lmL + bo + kb * 64, 256, BsL, wid, lane);
    __syncthreads();
    mma64x3(AsH, AsL, BsH, BsL, wr, wc, lane, acc);
    __syncthreads();
  }
  acc_store_f32(smf, acc, wr, wc, lane, false);
  __syncthreads();
  for (int w = 0; w < 64; ++w) {
    int e = w * 256 + tid;
    int row = e >> 7, col = e & 127;
    out[(size_t)(it * 128 + row) * 256 + jt * 128 + col] = smf[row * 128 + col];
  }
}

extern "C" void kernel_launch(void* const* d_in, const int* in_sizes, int n_in, void* d_out,
                              int out_size, void* d_ws, size_t ws_size, hipStream_t stream) {
  const int*   idx   = (const int*)d_in[0];
  const float* embed = (const float*)d_in[1];
  const float* enc   = (const float*)d_in[2];
  const float* encv  = (const float*)d_in[3];
  const float* dec   = (const float*)d_in[4];
  const float* lm    = (const float*)d_in[5];

  if (ws_size < WS_NEED) {
    hipMemsetAsync(d_out, 0x46, (size_t)out_size * 4, stream);
    return;
  }

  char* w = (char*)d_ws;
  float2* csA  = (float2*)(w + CSA_OFF);
  float2* csB  = (float2*)(w + CSB_OFF);
  u16*    etH  = (u16*)(w + ETH_OFF);
  u16*    etL  = (u16*)(w + ETL_OFF);
  u16*    evH  = (u16*)(w + EVH_OFF);
  u16*    evL  = (u16*)(w + EVL_OFF);
  u16*    dtH  = (u16*)(w + DTH_OFF);
  u16*    dtL  = (u16*)(w + DTL_OFF);
  u16*    lmH  = (u16*)(w + LMH_OFF);
  u16*    lmL  = (u16*)(w + LML_OFF);
  float*  x    = (float*)(w + X_OFF);
  u16*    xbH  = (u16*)(w + XBH_OFF);
  u16*    xbL  = (u16*)(w + XBL_OFF);
  u16*    xbTH = (u16*)(w + XBTH_OFF);
  u16*    xbTL = (u16*)(w + XBTL_OFF);
  u16*    QRH  = (u16*)(w + QRH_OFF);
  u16*    SpH  = (u16*)(w + SH_OFF);
  float*  part = (float*)(w + SH_OFF);   // overlays S-hi (S dead after G3)
  float*  yKV1 = (float*)(w + SL_OFF);   // freed S-lo region -> g3 partial 1
  float*  yKV0 = (float*)(w + YKV_OFF);
  u16*    ykH  = (u16*)(w + YKBH_OFF);
  u16*    ykL  = (u16*)(w + YKBL_OFF);

  k_costab<<<1152, 256, 0, stream>>>(csA, csB);
  k_tcast2<<<dim3(128, 8, 4), dim3(32, 8), 0, stream>>>(enc, etH, etL, 256, 4096);
  k_tcast2<<<dim3(128, 8, 4), dim3(32, 8), 0, stream>>>(encv, evH, evL, 256, 4096);
  k_tcast2<<<dim3(8, 128, 4), dim3(32, 8), 0, stream>>>(dec, dtH, dtL, 4096, 256);
  k_tcast2<<<dim3(8, 8, 1), dim3(32, 8), 0, stream>>>(lm, lmH, lmL, 256, 256);

  for (int b = 0; b < 2; ++b) {
    k_ln_embed<<<512, 256, 0, stream>>>(idx, embed, b, x, xbH, xbL);
    k_xbt<<<2048, 256, 0, stream>>>(xbH, xbL, xbTH, xbTL);
    for (int l = 0; l < NLAYER; ++l) {
      k_g1<<<dim3(16, 32, 4), 256, 0, stream>>>(xbH, xbL, etH, csA, csB, QRH);
      k_g2<<<204, 512, 0, stream>>>(QRH, SpH);
      k_g3<<<dim3(16, 2, 8), 256, 0, stream>>>(SpH, xbTH, xbTL, yKV0, yKV1);
      k_ln_f32<<<2048, 256, 0, stream>>>(yKV0, yKV1, ykH, ykL);
      k_g4a<<<dim3(16, 32, 4), 256, 0, stream>>>(ykH, ykL, evH, csA, csB, QRH);
      k_g4b<<<dim3(16, 2, 8), 256, 0, stream>>>(QRH, dtH, part);
      k_ln3<<<512, 256, 0, stream>>>(part, x, xbH, xbL);
      k_xbt<<<2048, 256, 0, stream>>>(xbH, xbL, xbTH, xbTL);
    }
    k_g5<<<dim3(16, 2), 256, 0, stream>>>(xbH, xbL, lmH, lmL, (float*)d_out + (size_t)b * T_ * 256);
  }
}

// Round 20
// 3269.559 us; speedup vs baseline: 1.4227x; 1.1251x over previous
//
#include <hip/hip_runtime.h>

// ===== BDH forward on MI355X — R20: 1-term g1/g4a/g3 (pure-hi operands) =====
// R19 (3678us, absmax 0.01367 — 5 rounds bit-identical through activation-lo
// drops). R20: g1 = xbH@encH (1-term), g4a = ykH@evH, g3 = SpH@xbTH; ln_f32
// writes ykH only; xbt writes xbTH only. g5 stays 3-term. g2 unchanged
// (L3-BW floor ~108us).

typedef unsigned short u16;
typedef unsigned int   u32;
typedef __attribute__((ext_vector_type(8))) short bf8;
typedef __attribute__((ext_vector_type(4))) float f4;

#define T_  2048
#define D_  256
#define NH_ 4
#define NN_ 4096
#define NLAYER 6

// ---- workspace layout (bytes); per-b activation buffers ----
#define CSA_OFF  ((size_t)0)                    // float2 [16][2048]  coarse-t trig
#define CSB_OFF  (CSA_OFF  + 262144)            // float2 [128][2048] fine-t trig
#define ETH_OFF  (CSB_OFF  + 2097152)           // bf16 [4][4096][256] enc^T hi
#define ETL_OFF  (ETH_OFF  + 8388608)
#define EVH_OFF  (ETL_OFF  + 8388608)
#define EVL_OFF  (EVH_OFF  + 8388608)
#define DTH_OFF  (EVL_OFF  + 8388608)           // bf16 [4][256][4096] dec^T hi
#define DTL_OFF  (DTH_OFF  + 8388608)
#define LMH_OFF  (DTL_OFF  + 8388608)           // bf16 [256][256] lm^T
#define LML_OFF  (LMH_OFF  + 131072)
#define X_OFF    (LML_OFF  + 131072)            // f32  [2048][256] x (per-b)
#define XBH_OFF  (X_OFF    + 2097152)           // bf16 [2048][256] (per-b)
#define XBL_OFF  (XBH_OFF  + 1048576)
#define XBTH_OFF (XBL_OFF  + 1048576)           // bf16 [256][2048] (per-b)
#define XBTL_OFF (XBTH_OFF + 1048576)           // unused now
#define QRH_OFF  (XBTL_OFF + 1048576)           // bf16 [4][2048][4096] QR/xy hi (per-b)
#define QRL_OFF  (QRH_OFF  + 67108864)          // UNUSED (layout stability)
#define SH_OFF   (QRL_OFF  + 67108864)          // bf16 [4][136][16384] S hi (per-b); part f32 overlays
#define SL_OFF   (SH_OFF   + 17825792)          // FREED -> f32 yKV partial-1
#define YKV_OFF  (SL_OFF   + 17825792)          // f32  [4][2048][256] yKV partial-0 (per-b)
#define YKBH_OFF (YKV_OFF  + 8388608)           // bf16 ln(yKV) hi (per-b)
#define YKBL_OFF (YKBH_OFF + 4194304)           // unused now
#define IDX_END  (YKBL_OFF + 4194304)
#define WS_NEED  (IDX_END  + 16384)             // = 245,907,456 < 253,902,848 proven

// ---------- helpers ----------
__device__ __forceinline__ u16 f2b(float f) {               // RTNE f32->bf16
  u32 u = __builtin_bit_cast(u32, f);
  u32 r = u + 0x7fffu + ((u >> 16) & 1u);
  return (u16)(r >> 16);
}
__device__ __forceinline__ float b2f(u16 h) {
  u32 u = ((u32)h) << 16;
  return __builtin_bit_cast(float, u);
}
__device__ __forceinline__ float wsum(float v) {
#pragma unroll
  for (int o = 32; o; o >>= 1) v += __shfl_xor(v, o, 64);
  return v;
}
// trig from factored tables: pp = pair index [0,2048), t = time [0,2048)
__device__ __forceinline__ float2 trig_ct(const float2* csA, const float2* csB, int t, int pp) {
  float2 a = csA[(t >> 7) * 2048 + pp];
  float2 b = csB[(t & 127) * 2048 + pp];
  return make_float2(a.x * b.x - a.y * b.y, a.x * b.y + a.y * b.x);
}
__device__ __forceinline__ void gld16(const u16* g, short* l) {
  __builtin_amdgcn_global_load_lds(
      (const __attribute__((address_space(1))) u32*)g,
      (__attribute__((address_space(3))) u32*)l, 16, 0, 0);
}
// stage 128x64 bf16 tile into LDS [128][64], XOR-swizzled; 256-thread (4-wave) form
__device__ __forceinline__ void stage_t(const u16* g, int lda, short* s, int wid, int lane) {
  int r8 = lane >> 3;
  int c8 = ((lane & 7) ^ r8) * 8;
#pragma unroll
  for (int j = 0; j < 4; ++j) {
    int row = wid * 32 + j * 8;
    gld16(g + (size_t)(row + r8) * lda + c8, s + row * 64);
  }
}
// 512-thread (8-wave) stage: each wave covers 16 rows
__device__ __forceinline__ void stage_t8(const u16* g, int lda, short* s, int wid, int lane) {
  int r8 = lane >> 3;
  int c8 = ((lane & 7) ^ r8) * 8;
#pragma unroll
  for (int j = 0; j < 2; ++j) {
    int row = wid * 16 + j * 8;
    gld16(g + (size_t)(row + r8) * lda + c8, s + row * 64);
  }
}
// BK=64 step, 3-term split: 96 MFMA — g5 only
__device__ __forceinline__ void mma64x3(const short* AsH, const short* AsL, const short* BsH,
                                        const short* BsL, int wr, int wc, int lane,
                                        f4 acc[4][4]) {
  int r15 = lane & 15, hi = lane >> 4;
  int sw = (r15 & 7) << 3;
#pragma unroll
  for (int kk = 0; kk < 2; ++kk) {
    int ko = (kk * 32 + hi * 8) ^ sw;
    bf8 ah[4], al[4], bh[4], bl[4];
#pragma unroll
    for (int m = 0; m < 4; ++m) {
      int off = (wr * 64 + m * 16 + r15) * 64 + ko;
      ah[m] = *(const bf8*)(AsH + off);
      al[m] = *(const bf8*)(AsL + off);
    }
#pragma unroll
    for (int n = 0; n < 4; ++n) {
      int off = (wc * 64 + n * 16 + r15) * 64 + ko;
      bh[n] = *(const bf8*)(BsH + off);
      bl[n] = *(const bf8*)(BsL + off);
    }
#pragma unroll
    for (int m = 0; m < 4; ++m)
#pragma unroll
      for (int n = 0; n < 4; ++n) {
        acc[m][n] = __builtin_amdgcn_mfma_f32_16x16x32_bf16(ah[m], bh[n], acc[m][n], 0, 0, 0);
        acc[m][n] = __builtin_amdgcn_mfma_f32_16x16x32_bf16(al[m], bh[n], acc[m][n], 0, 0, 0);
        acc[m][n] = __builtin_amdgcn_mfma_f32_16x16x32_bf16(ah[m], bl[n], acc[m][n], 0, 0, 0);
      }
  }
}
// BK=64 step, 1-term: acc += Ah*Bh^T  (32 MFMA) — g1/g3/g4a/g4b
__device__ __forceinline__ void mma64x1(const short* AsH, const short* BsH,
                                        int wr, int wc, int lane, f4 acc[4][4]) {
  int r15 = lane & 15, hi = lane >> 4;
  int sw = (r15 & 7) << 3;
#pragma unroll
  for (int kk = 0; kk < 2; ++kk) {
    int ko = (kk * 32 + hi * 8) ^ sw;
    bf8 ah[4], bh[4];
#pragma unroll
    for (int m = 0; m < 4; ++m)
      ah[m] = *(const bf8*)(AsH + (wr * 64 + m * 16 + r15) * 64 + ko);
#pragma unroll
    for (int n = 0; n < 4; ++n)
      bh[n] = *(const bf8*)(BsH + (wc * 64 + n * 16 + r15) * 64 + ko);
#pragma unroll
    for (int m = 0; m < 4; ++m)
#pragma unroll
      for (int n = 0; n < 4; ++n)
        acc[m][n] = __builtin_amdgcn_mfma_f32_16x16x32_bf16(ah[m], bh[n], acc[m][n], 0, 0, 0);
  }
}
__device__ __forceinline__ void acc_zero(f4 acc[4][4]) {
#pragma unroll
  for (int m = 0; m < 4; ++m)
#pragma unroll
    for (int n = 0; n < 4; ++n)
#pragma unroll
      for (int j = 0; j < 4; ++j) acc[m][n][j] = 0.0f;
}
// C frag -> f32 LDS bounce [128][128] (g5)
__device__ __forceinline__ void acc_store_f32(float* F, f4 acc[4][4], int wr, int wc, int lane,
                                              bool relu) {
  int r15 = lane & 15, q = lane >> 4;
#pragma unroll
  for (int m = 0; m < 4; ++m)
#pragma unroll
    for (int n = 0; n < 4; ++n)
#pragma unroll
      for (int j = 0; j < 4; ++j) {
        float v = acc[m][n][j];
        if (relu) v = fmaxf(v, 0.0f);
        F[(wr * 64 + m * 16 + q * 4 + j) * 128 + wc * 64 + n * 16 + r15] = v;
      }
}
// half-store (pass p writes waves wr==p) into [64][128] f32 bounce
__device__ __forceinline__ void acc_store_half(float* F, f4 acc[4][4], int pass, int wr, int wc,
                                               int lane, bool relu) {
  if (wr != pass) return;
  int r15 = lane & 15, q = lane >> 4;
#pragma unroll
  for (int m = 0; m < 4; ++m)
#pragma unroll
    for (int n = 0; n < 4; ++n)
#pragma unroll
      for (int j = 0; j < 4; ++j) {
        float v = acc[m][n][j];
        if (relu) v = fmaxf(v, 0.0f);
        F[(m * 16 + q * 4 + j) * 128 + wc * 64 + n * 16 + r15] = v;
      }
}

// ---------- prep kernels ----------
__global__ __launch_bounds__(256) void k_costab(float2* csA, float2* csB) {
  int id = blockIdx.x * 256 + threadIdx.x;
  int r = id >> 11, p = id & 2047;
  double freq = exp2(-(double)p / 128.0) * 0.15915494309189533577;
  int t = (r < 16) ? (r * 128) : (r - 16);
  double ph = fmod((double)t * freq, 1.0);
  double ang = ph * 6.2831853071795864769;
  float2 v = make_float2((float)cos(ang), (float)sin(ang));
  if (r < 16) csA[r * 2048 + p] = v;
  else        csB[(r - 16) * 2048 + p] = v;
}

__global__ __launch_bounds__(256) void k_tcast2(const float* __restrict__ in,
                                                u16* __restrict__ outH, u16* __restrict__ outL,
                                                int R, int C) {
  __shared__ float tl[32][33];
  size_t bo = (size_t)blockIdx.z * R * C;
  int tx = threadIdx.x, ty = threadIdx.y;
  int c = blockIdx.x * 32 + tx, r0 = blockIdx.y * 32 + ty;
#pragma unroll
  for (int k = 0; k < 32; k += 8) tl[ty + k][tx] = in[bo + (size_t)(r0 + k) * C + c];
  __syncthreads();
  int rr = blockIdx.y * 32 + tx, cc0 = blockIdx.x * 32 + ty;
#pragma unroll
  for (int k = 0; k < 32; k += 8) {
    float v = tl[tx][ty + k];
    u16 h = f2b(v);
    outH[bo + (size_t)(cc0 + k) * R + rr] = h;
    outL[bo + (size_t)(cc0 + k) * R + rr] = f2b(v - b2f(h));
  }
}

__global__ __launch_bounds__(256) void k_ln_embed(const int* __restrict__ idx,
                                                  const float* __restrict__ embed, int b,
                                                  float* __restrict__ x, u16* __restrict__ xbH,
                                                  u16* __restrict__ xbL) {
  int lane = threadIdx.x & 63, wid = threadIdx.x >> 6;
  int r = blockIdx.x * 4 + wid;
  int id = idx[b * T_ + r] & 255;
  float4 v = ((const float4*)(embed + (size_t)id * 256))[lane];
  float m = wsum(v.x + v.y + v.z + v.w) * (1.0f / 256.0f);
  float d0 = v.x - m, d1 = v.y - m, d2 = v.z - m, d3 = v.w - m;
  float var = wsum(d0 * d0 + d1 * d1 + d2 * d2 + d3 * d3) * (1.0f / 256.0f);
  float rs = 1.0f / sqrtf(var + 1e-5f);
  float y0 = d0 * rs, y1 = d1 * rs, y2 = d2 * rs, y3 = d3 * rs;
  ((float4*)(x + (size_t)r * 256))[lane] = make_float4(y0, y1, y2, y3);
  ushort4 oh, ol;
  oh.x = f2b(y0); ol.x = f2b(y0 - b2f(oh.x));
  oh.y = f2b(y1); ol.y = f2b(y1 - b2f(oh.y));
  oh.z = f2b(y2); ol.z = f2b(y2 - b2f(oh.z));
  oh.w = f2b(y3); ol.w = f2b(y3 - b2f(oh.w));
  ((ushort4*)(xbH + (size_t)r * 256))[lane] = oh;
  ((ushort4*)(xbL + (size_t)r * 256))[lane] = ol;
}

// per-b transpose xbH -> xbTH only. 2048 blocks.
__global__ __launch_bounds__(256) void k_xbt(const u16* __restrict__ xbH,
                                             u16* __restrict__ xbTH) {
  int id = blockIdx.x * 256 + threadIdx.x;
  int t = id & 2047, d = id >> 11;
  xbTH[id] = xbH[(size_t)t * 256 + d];
}

// ---------- GEMM kernels ----------
// 32KB single-buffer preamble (g1/g4a): 2 tiles; bounce aliases same 32KB
#define GEMM_PRE1                                                       \
  __shared__ short sm1[16384];                                          \
  short* T0 = sm1;                                                      \
  short* T1 = sm1 + 8192;                                               \
  float* bounce = (float*)sm1;                                          \
  int tid = threadIdx.x;                                                \
  int lane = tid & 63, wid = tid >> 6;                                  \
  int wr = wid >> 1, wc = wid & 1;                                      \
  f4 acc[4][4];                                                         \
  acc_zero(acc);

// 64KB double-buffer preamble (g3/g4b): 2 x 2 tiles
#define GEMM_PRE1D                                                      \
  __shared__ short smd1[32768];                                         \
  float* bounce = (float*)smd1;                                         \
  int tid = threadIdx.x;                                                \
  int lane = tid & 63, wid = tid >> 6;                                  \
  int wr = wid >> 1, wc = wid & 1;                                      \
  f4 acc[4][4];                                                         \
  acc_zero(acc);

// G1: x_sparse=relu(xbH@enc_hi[h]) -> rope -> QR hi.  1-term. grid(16,32,4), per-b.
__global__ __launch_bounds__(256) void k_g1(const u16* __restrict__ xbH,
                                            const u16* __restrict__ etH,
                                            const float2* __restrict__ csA,
                                            const float2* __restrict__ csB,
                                            u16* __restrict__ QRH) {
  GEMM_PRE1
  int it = blockIdx.x, jt = blockIdx.y, h = blockIdx.z;
  size_t ao = (size_t)it * 128 * 256;
  size_t bo = (size_t)h * NN_ * 256 + (size_t)jt * 128 * 256;
  for (int kb = 0; kb < 4; ++kb) {
    stage_t(xbH + ao + kb * 64, 256, T0, wid, lane);
    stage_t(etH + bo + kb * 64, 256, T1, wid, lane);
    __syncthreads();
    mma64x1(T0, T1, wr, wc, lane, acc);
    __syncthreads();
  }
#pragma unroll
  for (int pass = 0; pass < 2; ++pass) {
    acc_store_half(bounce, acc, pass, wr, wc, lane, true);
    __syncthreads();
    for (int w = 0; w < 16; ++w) {
      int e = w * 256 + tid;
      int rrel = e >> 6, p = e & 63;
      float v0 = bounce[rrel * 128 + 2 * p], v1 = bounce[rrel * 128 + 2 * p + 1];
      int t = it * 128 + pass * 64 + rrel, pp = jt * 64 + p;
      float2 c = trig_ct(csA, csB, t, pp);
      float q0 = v0 * c.x - v1 * c.y;
      float q1 = v1 * c.x + v0 * c.y;
      u32 hi = (u32)f2b(q0) | ((u32)f2b(q1) << 16);
      ((u32*)QRH)[(size_t)(h * T_ + t) * 2048 + pp] = hi;
    }
    __syncthreads();
  }
}

// G2: S = mask(Qh@Qh^T), 1-term, lower-tri, row-triple, 512 threads (8 waves:
// 2r x 4c of 64x96), 128KB dbuf (2 x AsH|B0|B1|B2). grid 204 per b, XCD chunk.
__global__ __launch_bounds__(512) void k_g2(const u16* __restrict__ QRH,
                                            u16* __restrict__ SpH) {
  __shared__ short smp[65536];             // 128KB: 2 x (AsH|B0|B1|B2)
  float* bounce = (float*)smp;             // 32KB [64][128] f32 (epilogue)
  int tid = threadIdx.x;
  int lane = tid & 63, wid = tid >> 6;     // wid 0..7
  int wr = wid >> 2, wc = wid & 3;         // 2 row-halves x 4 col-waves (64x96 each)
  f4 acc[4][6];
#pragma unroll
  for (int m = 0; m < 4; ++m)
#pragma unroll
    for (int n = 0; n < 6; ++n)
#pragma unroll
      for (int j = 0; j < 4; ++j) acc[m][n][j] = 0.0f;
  // bijective XCD chunking for N=204: q=25, r=4
  int orig = blockIdx.x;
  int xcd = orig & 7, sub = orig >> 3;
  int lb = (xcd < 4 ? xcd * 26 : 104 + (xcd - 4) * 25) + sub;
  int h = lb / 51;
  int rem = lb % 51, i = 0;
  while (rem >= (i + 3) / 3) { rem -= (i + 3) / 3; ++i; }
  int j0 = rem * 3, j1 = j0 + 1, j2 = j0 + 2;
  bool has1 = (j1 <= i), has2 = (j2 <= i);
  size_t base = (size_t)h * T_ * NN_;
  size_t ao = base + (size_t)i * 128 * NN_;
  size_t bo0 = base + (size_t)j0 * 128 * NN_;
  size_t bo1 = base + (size_t)j1 * 128 * NN_;
  size_t bo2 = base + (size_t)j2 * 128 * NN_;
  {  // prologue: stage k=0 into buf0
    stage_t8(QRH + ao, NN_, smp, wid, lane);
    stage_t8(QRH + bo0, NN_, smp + 8192, wid, lane);
    if (has1) stage_t8(QRH + bo1, NN_, smp + 16384, wid, lane);
    if (has2) stage_t8(QRH + bo2, NN_, smp + 24576, wid, lane);
  }
  int r15 = lane & 15, hi4 = lane >> 4;
  int sw = (r15 & 7) << 3;
  for (int kb = 0; kb < 64; ++kb) {
    short* cur = smp + (kb & 1) * 32768;
    __syncthreads();
    if (kb + 1 < 64) {
      short* nxt = smp + ((kb + 1) & 1) * 32768;
      stage_t8(QRH + ao + (kb + 1) * 64, NN_, nxt, wid, lane);
      stage_t8(QRH + bo0 + (kb + 1) * 64, NN_, nxt + 8192, wid, lane);
      if (has1) stage_t8(QRH + bo1 + (kb + 1) * 64, NN_, nxt + 16384, wid, lane);
      if (has2) stage_t8(QRH + bo2 + (kb + 1) * 64, NN_, nxt + 24576, wid, lane);
    }
#pragma unroll
    for (int kk = 0; kk < 2; ++kk) {
      int ko = (kk * 32 + hi4 * 8) ^ sw;
      bf8 ah[4];
#pragma unroll
      for (int m = 0; m < 4; ++m)
        ah[m] = *(const bf8*)(cur + (wr * 64 + m * 16 + r15) * 64 + ko);
#pragma unroll
      for (int n = 0; n < 6; ++n) {
        int cn = wc * 96 + n * 16;
        int bp = cn >> 7;
        if (bp == 1 && !has1) continue;
        if (bp == 2 && !has2) continue;
        bf8 bh = *(const bf8*)(cur + 8192 + bp * 8192 + ((cn & 127) + r15) * 64 + ko);
#pragma unroll
        for (int m = 0; m < 4; ++m)
          acc[m][n] = __builtin_amdgcn_mfma_f32_16x16x32_bf16(ah[m], bh, acc[m][n], 0, 0, 0);
      }
    }
  }
  __syncthreads();
  // epilogue: per present panel, 2 row-passes through 32KB bounce
  int q4 = lane >> 4;
#pragma unroll
  for (int jb = 0; jb < 3; ++jb) {
    if (jb == 1 && !has1) break;
    if (jb == 2 && !has2) break;
    int j = j0 + jb;
    size_t dblk = ((size_t)h * 136 + (size_t)i * (i + 1) / 2 + j) * 16384;
    bool diag = (i == j);
#pragma unroll
    for (int pass = 0; pass < 2; ++pass) {
      if (wr == pass) {
#pragma unroll
        for (int m = 0; m < 4; ++m)
#pragma unroll
          for (int n = 0; n < 6; ++n) {
            int cn = wc * 96 + n * 16;
            if ((cn >> 7) != jb) continue;
#pragma unroll
            for (int jj = 0; jj < 4; ++jj)
              bounce[(m * 16 + q4 * 4 + jj) * 128 + (cn & 127) + r15] = acc[m][n][jj];
          }
      }
      __syncthreads();
      for (int w = 0; w < 8; ++w) {
        int e = w * 512 + tid;
        int rrel = e >> 6, p = e & 63;
        int row = pass * 64 + rrel;
        float s0 = bounce[rrel * 128 + 2 * p], s1 = bounce[rrel * 128 + 2 * p + 1];
        if (diag) {  // strictly lower: col < row
          if (2 * p >= row) s0 = 0.0f;
          if (2 * p + 1 >= row) s1 = 0.0f;
        }
        u32 hi = (u32)f2b(s0) | ((u32)f2b(s1) << 16);
        ((u32*)SpH)[(dblk >> 1) + row * 64 + p] = hi;
      }
      __syncthreads();
    }
  }
}

// G3: yKV_partial = S_hi @ xbTH, 1-term, split-K x2, 64KB dbuf.
// grid(16,2,8): z = h + 4*ks.  per-b.
__global__ __launch_bounds__(256) void k_g3(const u16* __restrict__ SpH,
                                            const u16* __restrict__ xbTH,
                                            float* __restrict__ yKV0,
                                            float* __restrict__ yKV1) {
  GEMM_PRE1D
  int i = blockIdx.x, jt = blockIdx.y;
  int h = blockIdx.z & 3, ks = blockIdx.z >> 2;
  size_t tri = (size_t)h * 136 + (size_t)i * (i + 1) / 2;
  size_t bo = (size_t)jt * 128 * T_;
  int k0 = ks * (i + 1), k1 = (ks + 1) * (i + 1);   // half-step range
  {  // prologue
    size_t aoff = (tri + (k0 >> 1)) * 16384 + (k0 & 1) * 64;
    stage_t(SpH + aoff, 128, smd1, wid, lane);
    stage_t(xbTH + bo + k0 * 64, T_, smd1 + 8192, wid, lane);
  }
  for (int kb = k0; kb < k1; ++kb) {
    short* cur = smd1 + ((kb - k0) & 1) * 16384;
    __syncthreads();
    if (kb + 1 < k1) {
      short* nxt = smd1 + ((kb + 1 - k0) & 1) * 16384;
      size_t aoff = (tri + ((kb + 1) >> 1)) * 16384 + ((kb + 1) & 1) * 64;
      stage_t(SpH + aoff, 128, nxt, wid, lane);
      stage_t(xbTH + bo + (kb + 1) * 64, T_, nxt + 8192, wid, lane);
    }
    mma64x1(cur, cur + 8192, wr, wc, lane, acc);
  }
  __syncthreads();
  float* yout = ks ? yKV1 : yKV0;
#pragma unroll
  for (int pass = 0; pass < 2; ++pass) {
    acc_store_half(bounce, acc, pass, wr, wc, lane, false);
    __syncthreads();
    for (int w = 0; w < 32; ++w) {
      int e = w * 256 + tid;
      int row = e >> 7, col = e & 127;
      yout[((size_t)h * T_ + i * 128 + pass * 64 + row) * 256 + jt * 128 + col] =
          bounce[row * 128 + col];
    }
    __syncthreads();
  }
}

// LN over f32 rows of 256 (sum of 2 partials) -> hi bf16 only.  2048 blocks, per-b.
__global__ __launch_bounds__(256) void k_ln_f32(const float* __restrict__ in0,
                                                const float* __restrict__ in1,
                                                u16* __restrict__ outH) {
  int lane = threadIdx.x & 63, wid = threadIdx.x >> 6;
  int r = blockIdx.x * 4 + wid;
  float4 a = ((const float4*)(in0 + (size_t)r * 256))[lane];
  float4 b = ((const float4*)(in1 + (size_t)r * 256))[lane];
  float v0 = a.x + b.x, v1 = a.y + b.y, v2 = a.z + b.z, v3 = a.w + b.w;
  float m = wsum(v0 + v1 + v2 + v3) * (1.0f / 256.0f);
  float d0 = v0 - m, d1 = v1 - m, d2 = v2 - m, d3 = v3 - m;
  float var = wsum(d0 * d0 + d1 * d1 + d2 * d2 + d3 * d3) * (1.0f / 256.0f);
  float rs = 1.0f / sqrtf(var + 1e-5f);
  ushort4 oh;
  oh.x = f2b(d0 * rs); oh.y = f2b(d1 * rs); oh.z = f2b(d2 * rs); oh.w = f2b(d3 * rs);
  ((ushort4*)(outH + (size_t)r * 256))[lane] = oh;
}

// G4a: y_sparse=relu(ykH@encv_hi[h]); gate by invrope(QR hi); xy -> QR hi.
// 1-term. grid(16,32,4), per-b.
__global__ __launch_bounds__(256) void k_g4a(const u16* __restrict__ ykH,
                                             const u16* __restrict__ evH,
                                             const float2* __restrict__ csA,
                                             const float2* __restrict__ csB,
                                             u16* __restrict__ QRH) {
  GEMM_PRE1
  int it = blockIdx.x, jt = blockIdx.y, h = blockIdx.z;
  int t0 = it * 128;
  size_t ao = (size_t)(h * T_ + t0) * 256;
  size_t bo = (size_t)h * NN_ * 256 + (size_t)jt * 128 * 256;
  for (int kb = 0; kb < 4; ++kb) {
    stage_t(ykH + ao + kb * 64, 256, T0, wid, lane);
    stage_t(evH + bo + kb * 64, 256, T1, wid, lane);
    __syncthreads();
    mma64x1(T0, T1, wr, wc, lane, acc);
    __syncthreads();
  }
#pragma unroll
  for (int pass = 0; pass < 2; ++pass) {
    acc_store_half(bounce, acc, pass, wr, wc, lane, true);
    __syncthreads();
    for (int w = 0; w < 16; ++w) {
      int e = w * 256 + tid;
      int rrel = e >> 6, p = e & 63;
      float ys0 = bounce[rrel * 128 + 2 * p], ys1 = bounce[rrel * 128 + 2 * p + 1];
      int t = t0 + pass * 64 + rrel, pp = jt * 64 + p;
      size_t u32b = (size_t)(h * T_ + t) * 2048 + pp;
      u32 qh = ((const u32*)QRH)[u32b];
      float qe = b2f((u16)(qh & 0xffff));
      float qo = b2f((u16)(qh >> 16));
      float2 c = trig_ct(csA, csB, t, pp);
      float xe = fmaxf(qe * c.x + qo * c.y, 0.0f);  // inverse rotation; x_sparse >= 0
      float xo = fmaxf(qo * c.x - qe * c.y, 0.0f);
      u32 hi = (u32)f2b(ys0 * xe) | ((u32)f2b(ys1 * xo) << 16);
      ((u32*)QRH)[u32b] = hi;
    }
    __syncthreads();
  }
}

// G4b: part[ks*4+h] = xyH[ks-half] @ dec_hi[h][ks-half].  1-term, 64KB dbuf.
// grid(16,2,8): z = h + 4*ks.  per-b.
__global__ __launch_bounds__(256) void k_g4b(const u16* __restrict__ xyH,
                                             const u16* __restrict__ dtH,
                                             float* __restrict__ part) {
  GEMM_PRE1D
  int it = blockIdx.x, jt = blockIdx.y;
  int h = blockIdx.z & 3, ks = blockIdx.z >> 2;
  int t0 = it * 128;
  size_t ao = (size_t)(h * T_ + t0) * NN_;
  size_t bo = (size_t)h * D_ * NN_ + (size_t)jt * 128 * NN_;
  int k0 = ks * 32, k1 = ks * 32 + 32;
  {  // prologue
    stage_t(xyH + ao + k0 * 64, NN_, smd1, wid, lane);
    stage_t(dtH + bo + k0 * 64, NN_, smd1 + 8192, wid, lane);
  }
  for (int kb = k0; kb < k1; ++kb) {
    short* cur = smd1 + ((kb - k0) & 1) * 16384;
    __syncthreads();
    if (kb + 1 < k1) {
      short* nxt = smd1 + ((kb + 1 - k0) & 1) * 16384;
      stage_t(xyH + ao + (kb + 1) * 64, NN_, nxt, wid, lane);
      stage_t(dtH + bo + (kb + 1) * 64, NN_, nxt + 8192, wid, lane);
    }
    mma64x1(cur, cur + 8192, wr, wc, lane, acc);
  }
  __syncthreads();
#pragma unroll
  for (int pass = 0; pass < 2; ++pass) {
    acc_store_half(bounce, acc, pass, wr, wc, lane, false);
    __syncthreads();
    for (int w = 0; w < 32; ++w) {
      int e = w * 256 + tid;
      int row = e >> 7, col = e & 127;
      part[((size_t)blockIdx.z * T_ + t0 + pass * 64 + row) * 256 + jt * 128 + col] =
          bounce[row * 128 + col];
    }
    __syncthreads();
  }
}

// LN3: yMLP = sum of 8 part slabs; x = ln(x + ln(yMLP)); refresh x, xb hi/lo. 512 blocks.
__global__ __launch_bounds__(256) void k_ln3(const float* __restrict__ part, float* __restrict__ x,
                                             u16* __restrict__ xbH, u16* __restrict__ xbL) {
  int lane = threadIdx.x & 63, wid = threadIdx.x >> 6;
  int r = blockIdx.x * 4 + wid;
  float a0 = 0, a1 = 0, a2 = 0, a3 = 0;
#pragma unroll
  for (int h = 0; h < 8; ++h) {
    float4 u = ((const float4*)(part + ((size_t)h * T_ + r) * 256))[lane];
    a0 += u.x; a1 += u.y; a2 += u.z; a3 += u.w;
  }
  float m = wsum(a0 + a1 + a2 + a3) * (1.0f / 256.0f);
  float d0 = a0 - m, d1 = a1 - m, d2 = a2 - m, d3 = a3 - m;
  float var = wsum(d0 * d0 + d1 * d1 + d2 * d2 + d3 * d3) * (1.0f / 256.0f);
  float rs = 1.0f / sqrtf(var + 1e-5f);
  float4 xv = ((const float4*)(x + (size_t)r * 256))[lane];
  float s0 = xv.x + d0 * rs, s1 = xv.y + d1 * rs, s2 = xv.z + d2 * rs, s3 = xv.w + d3 * rs;
  float m2 = wsum(s0 + s1 + s2 + s3) * (1.0f / 256.0f);
  float e0 = s0 - m2, e1 = s1 - m2, e2 = s2 - m2, e3 = s3 - m2;
  float var2 = wsum(e0 * e0 + e1 * e1 + e2 * e2 + e3 * e3) * (1.0f / 256.0f);
  float rs2 = 1.0f / sqrtf(var2 + 1e-5f);
  float y0 = e0 * rs2, y1 = e1 * rs2, y2 = e2 * rs2, y3 = e3 * rs2;
  ((float4*)(x + (size_t)r * 256))[lane] = make_float4(y0, y1, y2, y3);
  ushort4 oh, ol;
  oh.x = f2b(y0); ol.x = f2b(y0 - b2f(oh.x));
  oh.y = f2b(y1); ol.y = f2b(y1 - b2f(oh.y));
  oh.z = f2b(y2); ol.z = f2b(y2 - b2f(oh.z));
  oh.w = f2b(y3); ol.w = f2b(y3 - b2f(oh.w));
  ((ushort4*)(xbH + (size_t)r * 256))[lane] = oh;
  ((ushort4*)(xbL + (size_t)r * 256))[lane] = ol;
}

// G5: logits = xb @ lm_head (3-term) -> f32 out.  grid(16,2), per-b.
__global__ __launch_bounds__(256) void k_g5(const u16* __restrict__ xbH,
                                            const u16* __restrict__ xbL,
                                            const u16* __restrict__ lmH,
                                            const u16* __restrict__ lmL,
                                            float* __restrict__ out) {
  __shared__ float smf[16384];
  short* AsH = (short*)smf;
  short* AsL = AsH + 8192;
  short* BsH = AsH + 16384;
  short* BsL = AsH + 24576;
  int tid = threadIdx.x;
  int lane = tid & 63, wid = tid >> 6;
  int wr = wid >> 1, wc = wid & 1;
  f4 acc[4][4];
  acc_zero(acc);
  int it = blockIdx.x, jt = blockIdx.y;
  size_t ao = (size_t)it * 128 * 256;
  size_t bo = (size_t)jt * 128 * 256;
  for (int kb = 0; kb < 4; ++kb) {
    stage_t(xbH + ao + kb * 64, 256, AsH, wid, lane);
    stage_t(xbL + ao + kb * 64, 256, AsL, wid, lane);
    stage_t(lmH + bo + kb * 64, 256, BsH, wid, lane);
    stage_t(lmL + bo + kb * 64, 256, BsL, wid, lane);
    __syncthreads();
    mma64x3(AsH, AsL, BsH, BsL, wr, wc, lane, acc);
    __syncthreads();
  }
  acc_store_f32(smf, acc, wr, wc, lane, false);
  __syncthreads();
  for (int w = 0; w < 64; ++w) {
    int e = w * 256 + tid;
    int row = e >> 7, col = e & 127;
    out[(size_t)(it * 128 + row) * 256 + jt * 128 + col] = smf[row * 128 + col];
  }
}

extern "C" void kernel_launch(void* const* d_in, const int* in_sizes, int n_in, void* d_out,
                              int out_size, void* d_ws, size_t ws_size, hipStream_t stream) {
  const int*   idx   = (const int*)d_in[0];
  const float* embed = (const float*)d_in[1];
  const float* enc   = (const float*)d_in[2];
  const float* encv  = (const float*)d_in[3];
  const float* dec   = (const float*)d_in[4];
  const float* lm    = (const float*)d_in[5];

  if (ws_size < WS_NEED) {
    hipMemsetAsync(d_out, 0x46, (size_t)out_size * 4, stream);
    return;
  }

  char* w = (char*)d_ws;
  float2* csA  = (float2*)(w + CSA_OFF);
  float2* csB  = (float2*)(w + CSB_OFF);
  u16*    etH  = (u16*)(w + ETH_OFF);
  u16*    etL  = (u16*)(w + ETL_OFF);
  u16*    evH  = (u16*)(w + EVH_OFF);
  u16*    evL  = (u16*)(w + EVL_OFF);
  u16*    dtH  = (u16*)(w + DTH_OFF);
  u16*    dtL  = (u16*)(w + DTL_OFF);
  u16*    lmH  = (u16*)(w + LMH_OFF);
  u16*    lmL  = (u16*)(w + LML_OFF);
  float*  x    = (float*)(w + X_OFF);
  u16*    xbH  = (u16*)(w + XBH_OFF);
  u16*    xbL  = (u16*)(w + XBL_OFF);
  u16*    xbTH = (u16*)(w + XBTH_OFF);
  u16*    QRH  = (u16*)(w + QRH_OFF);
  u16*    SpH  = (u16*)(w + SH_OFF);
  float*  part = (float*)(w + SH_OFF);   // overlays S-hi (S dead after G3)
  float*  yKV1 = (float*)(w + SL_OFF);   // freed S-lo region -> g3 partial 1
  float*  yKV0 = (float*)(w + YKV_OFF);
  u16*    ykH  = (u16*)(w + YKBH_OFF);

  k_costab<<<1152, 256, 0, stream>>>(csA, csB);
  k_tcast2<<<dim3(128, 8, 4), dim3(32, 8), 0, stream>>>(enc, etH, etL, 256, 4096);
  k_tcast2<<<dim3(128, 8, 4), dim3(32, 8), 0, stream>>>(encv, evH, evL, 256, 4096);
  k_tcast2<<<dim3(8, 128, 4), dim3(32, 8), 0, stream>>>(dec, dtH, dtL, 4096, 256);
  k_tcast2<<<dim3(8, 8, 1), dim3(32, 8), 0, stream>>>(lm, lmH, lmL, 256, 256);

  for (int b = 0; b < 2; ++b) {
    k_ln_embed<<<512, 256, 0, stream>>>(idx, embed, b, x, xbH, xbL);
    k_xbt<<<2048, 256, 0, stream>>>(xbH, xbTH);
    for (int l = 0; l < NLAYER; ++l) {
      k_g1<<<dim3(16, 32, 4), 256, 0, stream>>>(xbH, etH, csA, csB, QRH);
      k_g2<<<204, 512, 0, stream>>>(QRH, SpH);
      k_g3<<<dim3(16, 2, 8), 256, 0, stream>>>(SpH, xbTH, yKV0, yKV1);
      k_ln_f32<<<2048, 256, 0, stream>>>(yKV0, yKV1, ykH);
      k_g4a<<<dim3(16, 32, 4), 256, 0, stream>>>(ykH, evH, csA, csB, QRH);
      k_g4b<<<dim3(16, 2, 8), 256, 0, stream>>>(QRH, dtH, part);
      k_ln3<<<512, 256, 0, stream>>>(part, x, xbH, xbL);
      k_xbt<<<2048, 256, 0, stream>>>(xbH, xbTH);
    }
    k_g5<<<dim3(16, 2), 256, 0, stream>>>(xbH, xbL, lmH, lmL, (float*)d_out + (size_t)b * T_ * 256);
  }
}

// Round 21
// 3022.282 us; speedup vs baseline: 1.5391x; 1.0818x over previous
//
#include <hip/hip_runtime.h>

// ===== BDH forward on MI355X — R21: batch-parallel (both b concurrent) =====
// R20 (3270us, absmax 0.01367 x6 rounds): dropped weight-lo freed ~100MB ->
// both batches now fit (233MB < 254MB). All per-layer kernels gain batch dim:
// launches 101->56, g3 full-GPU (split-K dropped, single acc), g2 = 408-block
// launches (8x51 XCD chunk). Math identical except g3 f32 regroup.

typedef unsigned short u16;
typedef unsigned int   u32;
typedef __attribute__((ext_vector_type(8))) short bf8;
typedef __attribute__((ext_vector_type(4))) float f4;

#define T_  2048
#define D_  256
#define NH_ 4
#define NN_ 4096
#define NLAYER 6

// per-batch strides (elements)
#define XB_E   524288u      // 2048*256 (u16 or f32 count)
#define QR_E   33554432u    // 4*2048*4096 u16
#define QR_U32 16777216u
#define SP_U16 8912896u     // 4*136*16384 u16
#define SP_U32 4456448u
#define SP_F   4456448u     // part f32 stride (16MB used of 17.8MB)
#define YKV_F  2097152u     // 4*2048*256 f32
#define YKH_E  2097152u     // 4*2048*256 u16

// ---- workspace layout (bytes) ----
#define CSA_OFF  ((size_t)0)                    // float2 [16][2048]
#define CSB_OFF  (CSA_OFF  + 262144)            // float2 [128][2048]
#define ETH_OFF  (CSB_OFF  + 2097152)           // bf16 [4][4096][256] enc^T hi
#define EVH_OFF  (ETH_OFF  + 8388608)           // bf16 encv^T hi
#define DTH_OFF  (EVH_OFF  + 8388608)           // bf16 [4][256][4096] dec^T hi
#define LMH_OFF  (DTH_OFF  + 8388608)           // bf16 [256][256] lm^T hi
#define LML_OFF  (LMH_OFF  + 131072)
#define X_OFF    (LML_OFF  + 131072)            // f32  [2][2048][256]
#define XBH_OFF  (X_OFF    + 4194304)           // bf16 [2][2048][256]
#define XBL_OFF  (XBH_OFF  + 2097152)
#define XBTH_OFF (XBL_OFF  + 2097152)           // bf16 [2][256][2048]
#define QRH_OFF  (XBTH_OFF + 2097152)           // bf16 [2][4][2048][4096]  128MB
#define SH_OFF   (QRH_OFF  + 134217728)         // bf16 [2][4][136][16384]; part f32 overlays per b
#define YKV_OFF  (SH_OFF   + 35651584)          // f32  [2][4][2048][256]
#define YKH_OFF  (YKV_OFF  + 16777216)          // bf16 [2][4][2048][256]
#define WS_NEED  (YKH_OFF  + 8388608)           // = 233,308,160 < 253,902,848 proven

// ---------- helpers ----------
__device__ __forceinline__ u16 f2b(float f) {               // RTNE f32->bf16
  u32 u = __builtin_bit_cast(u32, f);
  u32 r = u + 0x7fffu + ((u >> 16) & 1u);
  return (u16)(r >> 16);
}
__device__ __forceinline__ float b2f(u16 h) {
  u32 u = ((u32)h) << 16;
  return __builtin_bit_cast(float, u);
}
__device__ __forceinline__ float wsum(float v) {
#pragma unroll
  for (int o = 32; o; o >>= 1) v += __shfl_xor(v, o, 64);
  return v;
}
__device__ __forceinline__ float2 trig_ct(const float2* csA, const float2* csB, int t, int pp) {
  float2 a = csA[(t >> 7) * 2048 + pp];
  float2 b = csB[(t & 127) * 2048 + pp];
  return make_float2(a.x * b.x - a.y * b.y, a.x * b.y + a.y * b.x);
}
__device__ __forceinline__ void gld16(const u16* g, short* l) {
  __builtin_amdgcn_global_load_lds(
      (const __attribute__((address_space(1))) u32*)g,
      (__attribute__((address_space(3))) u32*)l, 16, 0, 0);
}
// stage 128x64 bf16 tile into LDS [128][64], XOR-swizzled; 256-thread form
__device__ __forceinline__ void stage_t(const u16* g, int lda, short* s, int wid, int lane) {
  int r8 = lane >> 3;
  int c8 = ((lane & 7) ^ r8) * 8;
#pragma unroll
  for (int j = 0; j < 4; ++j) {
    int row = wid * 32 + j * 8;
    gld16(g + (size_t)(row + r8) * lda + c8, s + row * 64);
  }
}
// 512-thread (8-wave) stage
__device__ __forceinline__ void stage_t8(const u16* g, int lda, short* s, int wid, int lane) {
  int r8 = lane >> 3;
  int c8 = ((lane & 7) ^ r8) * 8;
#pragma unroll
  for (int j = 0; j < 2; ++j) {
    int row = wid * 16 + j * 8;
    gld16(g + (size_t)(row + r8) * lda + c8, s + row * 64);
  }
}
// 3-term split: 96 MFMA — g5 only
__device__ __forceinline__ void mma64x3(const short* AsH, const short* AsL, const short* BsH,
                                        const short* BsL, int wr, int wc, int lane,
                                        f4 acc[4][4]) {
  int r15 = lane & 15, hi = lane >> 4;
  int sw = (r15 & 7) << 3;
#pragma unroll
  for (int kk = 0; kk < 2; ++kk) {
    int ko = (kk * 32 + hi * 8) ^ sw;
    bf8 ah[4], al[4], bh[4], bl[4];
#pragma unroll
    for (int m = 0; m < 4; ++m) {
      int off = (wr * 64 + m * 16 + r15) * 64 + ko;
      ah[m] = *(const bf8*)(AsH + off);
      al[m] = *(const bf8*)(AsL + off);
    }
#pragma unroll
    for (int n = 0; n < 4; ++n) {
      int off = (wc * 64 + n * 16 + r15) * 64 + ko;
      bh[n] = *(const bf8*)(BsH + off);
      bl[n] = *(const bf8*)(BsL + off);
    }
#pragma unroll
    for (int m = 0; m < 4; ++m)
#pragma unroll
      for (int n = 0; n < 4; ++n) {
        acc[m][n] = __builtin_amdgcn_mfma_f32_16x16x32_bf16(ah[m], bh[n], acc[m][n], 0, 0, 0);
        acc[m][n] = __builtin_amdgcn_mfma_f32_16x16x32_bf16(al[m], bh[n], acc[m][n], 0, 0, 0);
        acc[m][n] = __builtin_amdgcn_mfma_f32_16x16x32_bf16(ah[m], bl[n], acc[m][n], 0, 0, 0);
      }
  }
}
// 1-term: 32 MFMA — g1/g3/g4a/g4b
__device__ __forceinline__ void mma64x1(const short* AsH, const short* BsH,
                                        int wr, int wc, int lane, f4 acc[4][4]) {
  int r15 = lane & 15, hi = lane >> 4;
  int sw = (r15 & 7) << 3;
#pragma unroll
  for (int kk = 0; kk < 2; ++kk) {
    int ko = (kk * 32 + hi * 8) ^ sw;
    bf8 ah[4], bh[4];
#pragma unroll
    for (int m = 0; m < 4; ++m)
      ah[m] = *(const bf8*)(AsH + (wr * 64 + m * 16 + r15) * 64 + ko);
#pragma unroll
    for (int n = 0; n < 4; ++n)
      bh[n] = *(const bf8*)(BsH + (wc * 64 + n * 16 + r15) * 64 + ko);
#pragma unroll
    for (int m = 0; m < 4; ++m)
#pragma unroll
      for (int n = 0; n < 4; ++n)
        acc[m][n] = __builtin_amdgcn_mfma_f32_16x16x32_bf16(ah[m], bh[n], acc[m][n], 0, 0, 0);
  }
}
__device__ __forceinline__ void acc_zero(f4 acc[4][4]) {
#pragma unroll
  for (int m = 0; m < 4; ++m)
#pragma unroll
    for (int n = 0; n < 4; ++n)
#pragma unroll
      for (int j = 0; j < 4; ++j) acc[m][n][j] = 0.0f;
}
__device__ __forceinline__ void acc_store_f32(float* F, f4 acc[4][4], int wr, int wc, int lane,
                                              bool relu) {
  int r15 = lane & 15, q = lane >> 4;
#pragma unroll
  for (int m = 0; m < 4; ++m)
#pragma unroll
    for (int n = 0; n < 4; ++n)
#pragma unroll
      for (int j = 0; j < 4; ++j) {
        float v = acc[m][n][j];
        if (relu) v = fmaxf(v, 0.0f);
        F[(wr * 64 + m * 16 + q * 4 + j) * 128 + wc * 64 + n * 16 + r15] = v;
      }
}
__device__ __forceinline__ void acc_store_half(float* F, f4 acc[4][4], int pass, int wr, int wc,
                                               int lane, bool relu) {
  if (wr != pass) return;
  int r15 = lane & 15, q = lane >> 4;
#pragma unroll
  for (int m = 0; m < 4; ++m)
#pragma unroll
    for (int n = 0; n < 4; ++n)
#pragma unroll
      for (int j = 0; j < 4; ++j) {
        float v = acc[m][n][j];
        if (relu) v = fmaxf(v, 0.0f);
        F[(m * 16 + q * 4 + j) * 128 + wc * 64 + n * 16 + r15] = v;
      }
}

// ---------- prep kernels ----------
__global__ __launch_bounds__(256) void k_costab(float2* csA, float2* csB) {
  int id = blockIdx.x * 256 + threadIdx.x;
  int r = id >> 11, p = id & 2047;
  double freq = exp2(-(double)p / 128.0) * 0.15915494309189533577;
  int t = (r < 16) ? (r * 128) : (r - 16);
  double ph = fmod((double)t * freq, 1.0);
  double ang = ph * 6.2831853071795864769;
  float2 v = make_float2((float)cos(ang), (float)sin(ang));
  if (r < 16) csA[r * 2048 + p] = v;
  else        csB[(r - 16) * 2048 + p] = v;
}

// transpose+cast H only: in f32 (R,C) -> out bf16 (C,R)
__global__ __launch_bounds__(256) void k_tcast1(const float* __restrict__ in,
                                                u16* __restrict__ outH, int R, int C) {
  __shared__ float tl[32][33];
  size_t bo = (size_t)blockIdx.z * R * C;
  int tx = threadIdx.x, ty = threadIdx.y;
  int c = blockIdx.x * 32 + tx, r0 = blockIdx.y * 32 + ty;
#pragma unroll
  for (int k = 0; k < 32; k += 8) tl[ty + k][tx] = in[bo + (size_t)(r0 + k) * C + c];
  __syncthreads();
  int rr = blockIdx.y * 32 + tx, cc0 = blockIdx.x * 32 + ty;
#pragma unroll
  for (int k = 0; k < 32; k += 8) outH[bo + (size_t)(cc0 + k) * R + rr] = f2b(tl[tx][ty + k]);
}

// transpose+cast hi/lo (lm only)
__global__ __launch_bounds__(256) void k_tcast2(const float* __restrict__ in,
                                                u16* __restrict__ outH, u16* __restrict__ outL,
                                                int R, int C) {
  __shared__ float tl[32][33];
  int tx = threadIdx.x, ty = threadIdx.y;
  int c = blockIdx.x * 32 + tx, r0 = blockIdx.y * 32 + ty;
#pragma unroll
  for (int k = 0; k < 32; k += 8) tl[ty + k][tx] = in[(size_t)(r0 + k) * C + c];
  __syncthreads();
  int rr = blockIdx.y * 32 + tx, cc0 = blockIdx.x * 32 + ty;
#pragma unroll
  for (int k = 0; k < 32; k += 8) {
    float v = tl[tx][ty + k];
    u16 h = f2b(v);
    outH[(size_t)(cc0 + k) * R + rr] = h;
    outL[(size_t)(cc0 + k) * R + rr] = f2b(v - b2f(h));
  }
}

// ln(embed[idx]) for BOTH b -> x, xb hi/lo. 1024 blocks, r in [0,4096).
__global__ __launch_bounds__(256) void k_ln_embed(const int* __restrict__ idx,
                                                  const float* __restrict__ embed,
                                                  float* __restrict__ x, u16* __restrict__ xbH,
                                                  u16* __restrict__ xbL) {
  int lane = threadIdx.x & 63, wid = threadIdx.x >> 6;
  int r = blockIdx.x * 4 + wid;
  int id = idx[r] & 255;
  float4 v = ((const float4*)(embed + (size_t)id * 256))[lane];
  float m = wsum(v.x + v.y + v.z + v.w) * (1.0f / 256.0f);
  float d0 = v.x - m, d1 = v.y - m, d2 = v.z - m, d3 = v.w - m;
  float var = wsum(d0 * d0 + d1 * d1 + d2 * d2 + d3 * d3) * (1.0f / 256.0f);
  float rs = 1.0f / sqrtf(var + 1e-5f);
  float y0 = d0 * rs, y1 = d1 * rs, y2 = d2 * rs, y3 = d3 * rs;
  ((float4*)(x + (size_t)r * 256))[lane] = make_float4(y0, y1, y2, y3);
  ushort4 oh, ol;
  oh.x = f2b(y0); ol.x = f2b(y0 - b2f(oh.x));
  oh.y = f2b(y1); ol.y = f2b(y1 - b2f(oh.y));
  oh.z = f2b(y2); ol.z = f2b(y2 - b2f(oh.z));
  oh.w = f2b(y3); ol.w = f2b(y3 - b2f(oh.w));
  ((ushort4*)(xbH + (size_t)r * 256))[lane] = oh;
  ((ushort4*)(xbL + (size_t)r * 256))[lane] = ol;
}

// both-b transpose xbH -> xbTH. 4096 blocks.
__global__ __launch_bounds__(256) void k_xbt(const u16* __restrict__ xbH,
                                             u16* __restrict__ xbTH) {
  int id = blockIdx.x * 256 + threadIdx.x;      // [0, 1048576)
  int b = id >> 19;
  int w19 = id & 524287;
  int t = w19 & 2047, d = w19 >> 11;
  xbTH[id] = xbH[(size_t)b * XB_E + (size_t)t * 256 + d];
}

// ---------- GEMM kernels ----------
#define GEMM_PRE1                                                       \
  __shared__ short sm1[16384];                                          \
  short* T0 = sm1;                                                      \
  short* T1 = sm1 + 8192;                                               \
  float* bounce = (float*)sm1;                                          \
  int tid = threadIdx.x;                                                \
  int lane = tid & 63, wid = tid >> 6;                                  \
  int wr = wid >> 1, wc = wid & 1;                                      \
  f4 acc[4][4];                                                         \
  acc_zero(acc);

#define GEMM_PRE1D                                                      \
  __shared__ short smd1[32768];                                         \
  float* bounce = (float*)smd1;                                         \
  int tid = threadIdx.x;                                                \
  int lane = tid & 63, wid = tid >> 6;                                  \
  int wr = wid >> 1, wc = wid & 1;                                      \
  f4 acc[4][4];                                                         \
  acc_zero(acc);

// G1: x_sparse=relu(xbH@enc_hi[h]) -> rope -> QR hi.  grid(16,32,8): z = bb*4+h.
__global__ __launch_bounds__(256) void k_g1(const u16* __restrict__ xbH,
                                            const u16* __restrict__ etH,
                                            const float2* __restrict__ csA,
                                            const float2* __restrict__ csB,
                                            u16* __restrict__ QRH) {
  GEMM_PRE1
  int it = blockIdx.x, jt = blockIdx.y;
  int h = blockIdx.z & 3, bb = blockIdx.z >> 2;
  size_t ao = (size_t)bb * XB_E + (size_t)it * 128 * 256;
  size_t bo = (size_t)h * NN_ * 256 + (size_t)jt * 128 * 256;
  for (int kb = 0; kb < 4; ++kb) {
    stage_t(xbH + ao + kb * 64, 256, T0, wid, lane);
    stage_t(etH + bo + kb * 64, 256, T1, wid, lane);
    __syncthreads();
    mma64x1(T0, T1, wr, wc, lane, acc);
    __syncthreads();
  }
#pragma unroll
  for (int pass = 0; pass < 2; ++pass) {
    acc_store_half(bounce, acc, pass, wr, wc, lane, true);
    __syncthreads();
    for (int w = 0; w < 16; ++w) {
      int e = w * 256 + tid;
      int rrel = e >> 6, p = e & 63;
      float v0 = bounce[rrel * 128 + 2 * p], v1 = bounce[rrel * 128 + 2 * p + 1];
      int t = it * 128 + pass * 64 + rrel, pp = jt * 64 + p;
      float2 c = trig_ct(csA, csB, t, pp);
      float q0 = v0 * c.x - v1 * c.y;
      float q1 = v1 * c.x + v0 * c.y;
      u32 hi = (u32)f2b(q0) | ((u32)f2b(q1) << 16);
      ((u32*)QRH)[(size_t)bb * QR_U32 + (size_t)(h * T_ + t) * 2048 + pp] = hi;
    }
    __syncthreads();
  }
}

// G2: S = mask(Qh@Qh^T), 1-term, row-triple, 512 threads, 128KB dbuf.
// grid 408 = 8 XCDs x 51 (bijective chunk); lb -> (bb, h, triple).
__global__ __launch_bounds__(512) void k_g2(const u16* __restrict__ QRH,
                                            u16* __restrict__ SpH) {
  __shared__ short smp[65536];             // 128KB: 2 x (AsH|B0|B1|B2)
  float* bounce = (float*)smp;
  int tid = threadIdx.x;
  int lane = tid & 63, wid = tid >> 6;
  int wr = wid >> 2, wc = wid & 3;         // 2 row-halves x 4 col-waves (64x96)
  f4 acc[4][6];
#pragma unroll
  for (int m = 0; m < 4; ++m)
#pragma unroll
    for (int n = 0; n < 6; ++n)
#pragma unroll
      for (int j = 0; j < 4; ++j) acc[m][n][j] = 0.0f;
  int orig = blockIdx.x;
  int lb = (orig & 7) * 51 + (orig >> 3);  // 408 = 8*51 exact chunk
  int bb = lb / 204;
  int l2 = lb % 204;
  int h = l2 / 51;
  int rem = l2 % 51, i = 0;
  while (rem >= (i + 3) / 3) { rem -= (i + 3) / 3; ++i; }
  int j0 = rem * 3, j1 = j0 + 1, j2 = j0 + 2;
  bool has1 = (j1 <= i), has2 = (j2 <= i);
  size_t base = (size_t)bb * QR_E + (size_t)h * T_ * NN_;
  size_t ao = base + (size_t)i * 128 * NN_;
  size_t bo0 = base + (size_t)j0 * 128 * NN_;
  size_t bo1 = base + (size_t)j1 * 128 * NN_;
  size_t bo2 = base + (size_t)j2 * 128 * NN_;
  {  // prologue: stage k=0 into buf0
    stage_t8(QRH + ao, NN_, smp, wid, lane);
    stage_t8(QRH + bo0, NN_, smp + 8192, wid, lane);
    if (has1) stage_t8(QRH + bo1, NN_, smp + 16384, wid, lane);
    if (has2) stage_t8(QRH + bo2, NN_, smp + 24576, wid, lane);
  }
  int r15 = lane & 15, hi4 = lane >> 4;
  int sw = (r15 & 7) << 3;
  for (int kb = 0; kb < 64; ++kb) {
    short* cur = smp + (kb & 1) * 32768;
    __syncthreads();
    if (kb + 1 < 64) {
      short* nxt = smp + ((kb + 1) & 1) * 32768;
      stage_t8(QRH + ao + (kb + 1) * 64, NN_, nxt, wid, lane);
      stage_t8(QRH + bo0 + (kb + 1) * 64, NN_, nxt + 8192, wid, lane);
      if (has1) stage_t8(QRH + bo1 + (kb + 1) * 64, NN_, nxt + 16384, wid, lane);
      if (has2) stage_t8(QRH + bo2 + (kb + 1) * 64, NN_, nxt + 24576, wid, lane);
    }
#pragma unroll
    for (int kk = 0; kk < 2; ++kk) {
      int ko = (kk * 32 + hi4 * 8) ^ sw;
      bf8 ah[4];
#pragma unroll
      for (int m = 0; m < 4; ++m)
        ah[m] = *(const bf8*)(cur + (wr * 64 + m * 16 + r15) * 64 + ko);
#pragma unroll
      for (int n = 0; n < 6; ++n) {
        int cn = wc * 96 + n * 16;
        int bp = cn >> 7;
        if (bp == 1 && !has1) continue;
        if (bp == 2 && !has2) continue;
        bf8 bh = *(const bf8*)(cur + 8192 + bp * 8192 + ((cn & 127) + r15) * 64 + ko);
#pragma unroll
        for (int m = 0; m < 4; ++m)
          acc[m][n] = __builtin_amdgcn_mfma_f32_16x16x32_bf16(ah[m], bh, acc[m][n], 0, 0, 0);
      }
    }
  }
  __syncthreads();
  int q4 = lane >> 4;
#pragma unroll
  for (int jb = 0; jb < 3; ++jb) {
    if (jb == 1 && !has1) break;
    if (jb == 2 && !has2) break;
    int j = j0 + jb;
    size_t dblk = ((size_t)h * 136 + (size_t)i * (i + 1) / 2 + j) * 16384;
    bool diag = (i == j);
#pragma unroll
    for (int pass = 0; pass < 2; ++pass) {
      if (wr == pass) {
#pragma unroll
        for (int m = 0; m < 4; ++m)
#pragma unroll
          for (int n = 0; n < 6; ++n) {
            int cn = wc * 96 + n * 16;
            if ((cn >> 7) != jb) continue;
#pragma unroll
            for (int jj = 0; jj < 4; ++jj)
              bounce[(m * 16 + q4 * 4 + jj) * 128 + (cn & 127) + r15] = acc[m][n][jj];
          }
      }
      __syncthreads();
      for (int w = 0; w < 8; ++w) {
        int e = w * 512 + tid;
        int rrel = e >> 6, p = e & 63;
        int row = pass * 64 + rrel;
        float s0 = bounce[rrel * 128 + 2 * p], s1 = bounce[rrel * 128 + 2 * p + 1];
        if (diag) {  // strictly lower: col < row
          if (2 * p >= row) s0 = 0.0f;
          if (2 * p + 1 >= row) s1 = 0.0f;
        }
        u32 hi = (u32)f2b(s0) | ((u32)f2b(s1) << 16);
        ((u32*)SpH)[(size_t)bb * SP_U32 + (dblk >> 1) + row * 64 + p] = hi;
      }
      __syncthreads();
    }
  }
}

// G3: yKV = S_hi @ xbTH, 1-term, FULL K (no split), 64KB dbuf.
// grid(16,2,8): z = bb*4 + h.
__global__ __launch_bounds__(256) void k_g3(const u16* __restrict__ SpH,
                                            const u16* __restrict__ xbTH,
                                            float* __restrict__ yKV) {
  GEMM_PRE1D
  int i = blockIdx.x, jt = blockIdx.y;
  int h = blockIdx.z & 3, bb = blockIdx.z >> 2;
  size_t tri = (size_t)bb * 544 + (size_t)h * 136 + (size_t)i * (i + 1) / 2;
  size_t bo = (size_t)bb * XB_E + (size_t)jt * 128 * T_;
  int nk = 2 * (i + 1);
  {  // prologue
    stage_t(SpH + tri * 16384, 128, smd1, wid, lane);
    stage_t(xbTH + bo, T_, smd1 + 8192, wid, lane);
  }
  for (int kb = 0; kb < nk; ++kb) {
    short* cur = smd1 + (kb & 1) * 16384;
    __syncthreads();
    if (kb + 1 < nk) {
      short* nxt = smd1 + ((kb + 1) & 1) * 16384;
      size_t aoff = (tri + ((kb + 1) >> 1)) * 16384 + ((kb + 1) & 1) * 64;
      stage_t(SpH + aoff, 128, nxt, wid, lane);
      stage_t(xbTH + bo + (kb + 1) * 64, T_, nxt + 8192, wid, lane);
    }
    mma64x1(cur, cur + 8192, wr, wc, lane, acc);
  }
  __syncthreads();
#pragma unroll
  for (int pass = 0; pass < 2; ++pass) {
    acc_store_half(bounce, acc, pass, wr, wc, lane, false);
    __syncthreads();
    for (int w = 0; w < 32; ++w) {
      int e = w * 256 + tid;
      int row = e >> 7, col = e & 127;
      yKV[(size_t)bb * YKV_F + ((size_t)h * T_ + i * 128 + pass * 64 + row) * 256 + jt * 128 + col] =
          bounce[row * 128 + col];
    }
    __syncthreads();
  }
}

// LN over f32 rows of 256 -> hi bf16.  4096 blocks (both b, contiguous).
__global__ __launch_bounds__(256) void k_ln_f32(const float* __restrict__ in,
                                                u16* __restrict__ outH) {
  int lane = threadIdx.x & 63, wid = threadIdx.x >> 6;
  int r = blockIdx.x * 4 + wid;
  float4 v = ((const float4*)(in + (size_t)r * 256))[lane];
  float m = wsum(v.x + v.y + v.z + v.w) * (1.0f / 256.0f);
  float d0 = v.x - m, d1 = v.y - m, d2 = v.z - m, d3 = v.w - m;
  float var = wsum(d0 * d0 + d1 * d1 + d2 * d2 + d3 * d3) * (1.0f / 256.0f);
  float rs = 1.0f / sqrtf(var + 1e-5f);
  ushort4 oh;
  oh.x = f2b(d0 * rs); oh.y = f2b(d1 * rs); oh.z = f2b(d2 * rs); oh.w = f2b(d3 * rs);
  ((ushort4*)(outH + (size_t)r * 256))[lane] = oh;
}

// G4a: y_sparse=relu(ykH@encv_hi[h]); gate by invrope(QR hi); xy -> QR hi.
// grid(16,32,8): z = bb*4+h.
__global__ __launch_bounds__(256) void k_g4a(const u16* __restrict__ ykH,
                                             const u16* __restrict__ evH,
                                             const float2* __restrict__ csA,
                                             const float2* __restrict__ csB,
                                             u16* __restrict__ QRH) {
  GEMM_PRE1
  int it = blockIdx.x, jt = blockIdx.y;
  int h = blockIdx.z & 3, bb = blockIdx.z >> 2;
  int t0 = it * 128;
  size_t ao = (size_t)bb * YKH_E + (size_t)(h * T_ + t0) * 256;
  size_t bo = (size_t)h * NN_ * 256 + (size_t)jt * 128 * 256;
  for (int kb = 0; kb < 4; ++kb) {
    stage_t(ykH + ao + kb * 64, 256, T0, wid, lane);
    stage_t(evH + bo + kb * 64, 256, T1, wid, lane);
    __syncthreads();
    mma64x1(T0, T1, wr, wc, lane, acc);
    __syncthreads();
  }
#pragma unroll
  for (int pass = 0; pass < 2; ++pass) {
    acc_store_half(bounce, acc, pass, wr, wc, lane, true);
    __syncthreads();
    for (int w = 0; w < 16; ++w) {
      int e = w * 256 + tid;
      int rrel = e >> 6, p = e & 63;
      float ys0 = bounce[rrel * 128 + 2 * p], ys1 = bounce[rrel * 128 + 2 * p + 1];
      int t = t0 + pass * 64 + rrel, pp = jt * 64 + p;
      size_t u32b = (size_t)bb * QR_U32 + (size_t)(h * T_ + t) * 2048 + pp;
      u32 qh = ((const u32*)QRH)[u32b];
      float qe = b2f((u16)(qh & 0xffff));
      float qo = b2f((u16)(qh >> 16));
      float2 c = trig_ct(csA, csB, t, pp);
      float xe = fmaxf(qe * c.x + qo * c.y, 0.0f);  // inverse rotation; x_sparse >= 0
      float xo = fmaxf(qo * c.x - qe * c.y, 0.0f);
      u32 hi = (u32)f2b(ys0 * xe) | ((u32)f2b(ys1 * xo) << 16);
      ((u32*)QRH)[u32b] = hi;
    }
    __syncthreads();
  }
}

// G4b: part[bb][h+4*ks] = xyH[ks-half] @ dec_hi[h][ks-half].  1-term, 64KB dbuf.
// grid(16,2,16): z: h = z&3, ks = (z>>2)&1, bb = z>>3.
__global__ __launch_bounds__(256) void k_g4b(const u16* __restrict__ xyH,
                                             const u16* __restrict__ dtH,
                                             float* __restrict__ part) {
  GEMM_PRE1D
  int it = blockIdx.x, jt = blockIdx.y;
  int h = blockIdx.z & 3, ks = (blockIdx.z >> 2) & 1, bb = blockIdx.z >> 3;
  int z8 = h + 4 * ks;
  int t0 = it * 128;
  size_t ao = (size_t)bb * QR_E + (size_t)(h * T_ + t0) * NN_;
  size_t bo = (size_t)h * D_ * NN_ + (size_t)jt * 128 * NN_;
  int k0 = ks * 32, k1 = ks * 32 + 32;
  {  // prologue
    stage_t(xyH + ao + k0 * 64, NN_, smd1, wid, lane);
    stage_t(dtH + bo + k0 * 64, NN_, smd1 + 8192, wid, lane);
  }
  for (int kb = k0; kb < k1; ++kb) {
    short* cur = smd1 + ((kb - k0) & 1) * 16384;
    __syncthreads();
    if (kb + 1 < k1) {
      short* nxt = smd1 + ((kb + 1 - k0) & 1) * 16384;
      stage_t(xyH + ao + (kb + 1) * 64, NN_, nxt, wid, lane);
      stage_t(dtH + bo + (kb + 1) * 64, NN_, nxt + 8192, wid, lane);
    }
    mma64x1(cur, cur + 8192, wr, wc, lane, acc);
  }
  __syncthreads();
#pragma unroll
  for (int pass = 0; pass < 2; ++pass) {
    acc_store_half(bounce, acc, pass, wr, wc, lane, false);
    __syncthreads();
    for (int w = 0; w < 32; ++w) {
      int e = w * 256 + tid;
      int row = e >> 7, col = e & 127;
      part[(size_t)bb * SP_F + ((size_t)z8 * T_ + t0 + pass * 64 + row) * 256 + jt * 128 + col] =
          bounce[row * 128 + col];
    }
    __syncthreads();
  }
}

// LN3: yMLP = sum of 8 part slabs; x = ln(x + ln(yMLP)); refresh x, xb hi/lo.
// 1024 blocks, r in [0,4096): bb = r>>11.
__global__ __launch_bounds__(256) void k_ln3(const float* __restrict__ part, float* __restrict__ x,
                                             u16* __restrict__ xbH, u16* __restrict__ xbL) {
  int lane = threadIdx.x & 63, wid = threadIdx.x >> 6;
  int r = blockIdx.x * 4 + wid;
  int bb = r >> 11, rl = r & 2047;
  const float* P = part + (size_t)bb * SP_F;
  float a0 = 0, a1 = 0, a2 = 0, a3 = 0;
#pragma unroll
  for (int h = 0; h < 8; ++h) {
    float4 u = ((const float4*)(P + ((size_t)h * T_ + rl) * 256))[lane];
    a0 += u.x; a1 += u.y; a2 += u.z; a3 += u.w;
  }
  float m = wsum(a0 + a1 + a2 + a3) * (1.0f / 256.0f);
  float d0 = a0 - m, d1 = a1 - m, d2 = a2 - m, d3 = a3 - m;
  float var = wsum(d0 * d0 + d1 * d1 + d2 * d2 + d3 * d3) * (1.0f / 256.0f);
  float rs = 1.0f / sqrtf(var + 1e-5f);
  float4 xv = ((const float4*)(x + (size_t)r * 256))[lane];
  float s0 = xv.x + d0 * rs, s1 = xv.y + d1 * rs, s2 = xv.z + d2 * rs, s3 = xv.w + d3 * rs;
  float m2 = wsum(s0 + s1 + s2 + s3) * (1.0f / 256.0f);
  float e0 = s0 - m2, e1 = s1 - m2, e2 = s2 - m2, e3 = s3 - m2;
  float var2 = wsum(e0 * e0 + e1 * e1 + e2 * e2 + e3 * e3) * (1.0f / 256.0f);
  float rs2 = 1.0f / sqrtf(var2 + 1e-5f);
  float y0 = e0 * rs2, y1 = e1 * rs2, y2 = e2 * rs2, y3 = e3 * rs2;
  ((float4*)(x + (size_t)r * 256))[lane] = make_float4(y0, y1, y2, y3);
  ushort4 oh, ol;
  oh.x = f2b(y0); ol.x = f2b(y0 - b2f(oh.x));
  oh.y = f2b(y1); ol.y = f2b(y1 - b2f(oh.y));
  oh.z = f2b(y2); ol.z = f2b(y2 - b2f(oh.z));
  oh.w = f2b(y3); ol.w = f2b(y3 - b2f(oh.w));
  ((ushort4*)(xbH + (size_t)r * 256))[lane] = oh;
  ((ushort4*)(xbL + (size_t)r * 256))[lane] = ol;
}

// G5: logits = xb @ lm_head (3-term) -> f32 out.  grid(32,2) — both b contiguous.
__global__ __launch_bounds__(256) void k_g5(const u16* __restrict__ xbH,
                                            const u16* __restrict__ xbL,
                                            const u16* __restrict__ lmH,
                                            const u16* __restrict__ lmL,
                                            float* __restrict__ out) {
  __shared__ float smf[16384];
  short* AsH = (short*)smf;
  short* AsL = AsH + 8192;
  short* BsH = AsH + 16384;
  short* BsL = AsH + 24576;
  int tid = threadIdx.x;
  int lane = tid & 63, wid = tid >> 6;
  int wr = wid >> 1, wc = wid & 1;
  f4 acc[4][4];
  acc_zero(acc);
  int it = blockIdx.x, jt = blockIdx.y;
  size_t ao = (size_t)it * 128 * 256;
  size_t bo = (size_t)jt * 128 * 256;
  for (int kb = 0; kb < 4; ++kb) {
    stage_t(xbH + ao + kb * 64, 256, AsH, wid, lane);
    stage_t(xbL + ao + kb * 64, 256, AsL, wid, lane);
    stage_t(lmH + bo + kb * 64, 256, BsH, wid, lane);
    stage_t(lmL + bo + kb * 64, 256, BsL, wid, lane);
    __syncthreads();
    mma64x3(AsH, AsL, BsH, BsL, wr, wc, lane, acc);
    __syncthreads();
  }
  acc_store_f32(smf, acc, wr, wc, lane, false);
  __syncthreads();
  for (int w = 0; w < 64; ++w) {
    int e = w * 256 + tid;
    int row = e >> 7, col = e & 127;
    out[(size_t)(it * 128 + row) * 256 + jt * 128 + col] = smf[row * 128 + col];
  }
}

extern "C" void kernel_launch(void* const* d_in, const int* in_sizes, int n_in, void* d_out,
                              int out_size, void* d_ws, size_t ws_size, hipStream_t stream) {
  const int*   idx   = (const int*)d_in[0];
  const float* embed = (const float*)d_in[1];
  const float* enc   = (const float*)d_in[2];
  const float* encv  = (const float*)d_in[3];
  const float* dec   = (const float*)d_in[4];
  const float* lm    = (const float*)d_in[5];

  if (ws_size < WS_NEED) {
    hipMemsetAsync(d_out, 0x46, (size_t)out_size * 4, stream);
    return;
  }

  char* w = (char*)d_ws;
  float2* csA  = (float2*)(w + CSA_OFF);
  float2* csB  = (float2*)(w + CSB_OFF);
  u16*    etH  = (u16*)(w + ETH_OFF);
  u16*    evH  = (u16*)(w + EVH_OFF);
  u16*    dtH  = (u16*)(w + DTH_OFF);
  u16*    lmH  = (u16*)(w + LMH_OFF);
  u16*    lmL  = (u16*)(w + LML_OFF);
  float*  x    = (float*)(w + X_OFF);
  u16*    xbH  = (u16*)(w + XBH_OFF);
  u16*    xbL  = (u16*)(w + XBL_OFF);
  u16*    xbTH = (u16*)(w + XBTH_OFF);
  u16*    QRH  = (u16*)(w + QRH_OFF);
  u16*    SpH  = (u16*)(w + SH_OFF);
  float*  part = (float*)(w + SH_OFF);   // overlays SpH per b (S dead after g3)
  float*  yKV  = (float*)(w + YKV_OFF);
  u16*    ykH  = (u16*)(w + YKH_OFF);

  k_costab<<<1152, 256, 0, stream>>>(csA, csB);
  k_tcast1<<<dim3(128, 8, 4), dim3(32, 8), 0, stream>>>(enc, etH, 256, 4096);
  k_tcast1<<<dim3(128, 8, 4), dim3(32, 8), 0, stream>>>(encv, evH, 256, 4096);
  k_tcast1<<<dim3(8, 128, 4), dim3(32, 8), 0, stream>>>(dec, dtH, 4096, 256);
  k_tcast2<<<dim3(8, 8, 1), dim3(32, 8), 0, stream>>>(lm, lmH, lmL, 256, 256);
  k_ln_embed<<<1024, 256, 0, stream>>>(idx, embed, x, xbH, xbL);
  k_xbt<<<4096, 256, 0, stream>>>(xbH, xbTH);

  for (int l = 0; l < NLAYER; ++l) {
    k_g1<<<dim3(16, 32, 8), 256, 0, stream>>>(xbH, etH, csA, csB, QRH);
    k_g2<<<408, 512, 0, stream>>>(QRH, SpH);
    k_g3<<<dim3(16, 2, 8), 256, 0, stream>>>(SpH, xbTH, yKV);
    k_ln_f32<<<4096, 256, 0, stream>>>(yKV, ykH);
    k_g4a<<<dim3(16, 32, 8), 256, 0, stream>>>(ykH, evH, csA, csB, QRH);
    k_g4b<<<dim3(16, 2, 16), 256, 0, stream>>>(QRH, dtH, part);
    k_ln3<<<1024, 256, 0, stream>>>(part, x, xbH, xbL);
    k_xbt<<<4096, 256, 0, stream>>>(xbH, xbTH);
  }
  k_g5<<<dim3(32, 2), 256, 0, stream>>>(xbH, xbL, lmH, lmL, (float*)d_out);
}